// Round 2
// baseline (347.186 us; speedup 1.0000x reference)
//
#include <hip/hip_runtime.h>
#include <hip/hip_bf16.h>
#include <float.h>

#define T_LEN 2048
#define DM    1024
#define NB    128
#define NEGC  (-1e9f)

typedef __attribute__((ext_vector_type(8))) short short8;
typedef __attribute__((ext_vector_type(4))) float floatx4;
typedef _Float16 h2 __attribute__((ext_vector_type(2)));

// ---------------- helpers ----------------
__device__ __forceinline__ float wred_max(float v) {
#pragma unroll
  for (int o = 32; o > 0; o >>= 1) v = fmaxf(v, __shfl_xor(v, o, 64));
  return v;
}
__device__ __forceinline__ float wred_sum(float v) {
#pragma unroll
  for (int o = 32; o > 0; o >>= 1) v += __shfl_xor(v, o, 64);
  return v;
}
__device__ __forceinline__ unsigned short f32_to_bf16(float f) {
  unsigned int b = __float_as_uint(f);
  return (unsigned short)((b + 0x7fffu + ((b >> 16) & 1u)) >> 16);
}
__device__ __forceinline__ float bf16_to_f32(unsigned short u) {
  return __uint_as_float(((unsigned int)u) << 16);
}
__device__ __forceinline__ unsigned int pack_h2(float a, float b) {
  h2 r; r[0] = (_Float16)a; r[1] = (_Float16)b;
  return __builtin_bit_cast(unsigned int, r);
}
__device__ __forceinline__ float fdot2u(unsigned int a, unsigned int b, float c) {
#if __has_builtin(__builtin_amdgcn_fdot2)
  return __builtin_amdgcn_fdot2(__builtin_bit_cast(h2, a), __builtin_bit_cast(h2, b), c, false);
#else
  const h2 av = __builtin_bit_cast(h2, a), bv = __builtin_bit_cast(h2, b);
  return c + (float)av[0] * (float)bv[0] + (float)av[1] * (float)bv[1];
#endif
}
__device__ __forceinline__ void lds_async16(unsigned short* l, const unsigned short* g) {
  __builtin_amdgcn_global_load_lds(
      (const __attribute__((address_space(1))) unsigned int*)g,
      (__attribute__((address_space(3))) unsigned int*)l, 16, 0, 0);
}

// ---------------- zero-fill (split-K partial targets) ----------------
__global__ __launch_bounds__(256) void zero_k(float4* __restrict__ p, int n4) {
  const float4 z = {0.f, 0.f, 0.f, 0.f};
  for (int i = blockIdx.x * 256 + threadIdx.x; i < n4; i += gridDim.x * 256) p[i] = z;
}

// =========== 64x128-tile bf16 MFMA GEMM core (chunk-major swizzled LDS) ======
// 256 thr = 4 waves (2 row-halves x 2 col-halves). BK=32. Round-0 proven
// structure (BK=64 dbuf regressed: barrier vmcnt(0) drain defeats prefetch).
// SPLIT-K: [kbeg, kbeg+klen) slice per block; epilogue atomicAdd into
// pre-zeroed C. Doubles resident blocks/CU (3->6) to overlap the per-iteration
// exposed load latency that limits this 2-barrier structure.
// Staging: lane stages row = w*16+(lane&15), chunk = lane>>4 -> LDS addr is
// lane-contiguous (global_load_lds requirement) AND fragment reads land at
// byte kgrp*256 + mrow*16 -> bank = mrow*4 mod 32 (2-way aliasing = free).
__device__ __forceinline__ void gemm64_core(
    const unsigned short* __restrict__ A, const unsigned short* __restrict__ Bt,
    float* __restrict__ C, int kbeg, int klen, int K, int lda,
    int row0, int bcol0, int ccol0, int ldc,
    unsigned short* As, unsigned short* Bs) {
  const int tid = threadIdx.x;
  const int w = tid >> 6, lane = tid & 63;
  const int wr = w >> 1, wc = w & 1;
  const int mrow = lane & 15, kgrp = lane >> 4;

  const int sr = (w << 4) + mrow;          // staged row 0..63
  const int sc = kgrp;                     // staged chunk 0..3

  floatx4 zero = {0.f, 0.f, 0.f, 0.f};
  floatx4 acc[2][4];
#pragma unroll
  for (int i = 0; i < 2; i++)
#pragma unroll
    for (int j = 0; j < 4; j++) acc[i][j] = zero;

  for (int k0 = kbeg; k0 < kbeg + klen; k0 += 32) {
    lds_async16(&As[w * 512], A + (size_t)(row0 + sr) * lda + k0 + sc * 8);
    lds_async16(&Bs[w * 512], Bt + (size_t)(bcol0 + sr) * K + k0 + sc * 8);
    lds_async16(&Bs[2048 + w * 512], Bt + (size_t)(bcol0 + 64 + sr) * K + k0 + sc * 8);
    __syncthreads();
    short8 af[2], bf[4];
#pragma unroll
    for (int mi = 0; mi < 2; mi++)
      af[mi] = *(const short8*)&As[(wr * 2 + mi) * 512 + kgrp * 128 + mrow * 8];
#pragma unroll
    for (int ni = 0; ni < 4; ni++)
      bf[ni] = *(const short8*)&Bs[(wc * 4 + ni) * 512 + kgrp * 128 + mrow * 8];
#pragma unroll
    for (int mi = 0; mi < 2; mi++)
#pragma unroll
      for (int ni = 0; ni < 4; ni++)
        acc[mi][ni] = __builtin_amdgcn_mfma_f32_16x16x32_bf16(af[mi], bf[ni], acc[mi][ni], 0, 0, 0);
    __syncthreads();
  }
#pragma unroll
  for (int mi = 0; mi < 2; mi++)
#pragma unroll
    for (int ni = 0; ni < 4; ni++) {
      float* Cp = C + (size_t)(row0 + wr * 32 + mi * 16 + kgrp * 4) * ldc
                    + ccol0 + wc * 64 + ni * 16 + mrow;
      atomicAdd(&Cp[0], acc[mi][ni][0]);
      atomicAdd(&Cp[(size_t)ldc], acc[mi][ni][1]);
      atomicAdd(&Cp[(size_t)2 * ldc], acc[mi][ni][2]);
      atomicAdd(&Cp[(size_t)3 * ldc], acc[mi][ni][3]);
    }
}

// merged q|k|v GEMM: grid (24, 32, 2). col-tiles 0..15: Bqkv (K=3072, bf16x3
// split); col-tiles 16..23: Wvt (K=1024, plain hi). z = K-half (split-K).
__global__ __launch_bounds__(256) void qkv_gemm(const unsigned short* __restrict__ Axx,
                                                const unsigned short* __restrict__ Bqkv,
                                                const unsigned short* __restrict__ Wvt,
                                                float* __restrict__ C) {
  __shared__ __align__(16) unsigned short As[64 * 32];
  __shared__ __align__(16) unsigned short Bs[128 * 32];
  const int ct = blockIdx.x, z = blockIdx.z;
  const unsigned short* Bt;
  int K, bcol0, kbeg, klen;
  if (ct < 16) { Bt = Bqkv; K = 3072; bcol0 = ct * 128; klen = 1536; kbeg = z * 1536; }
  else         { Bt = Wvt;  K = 1024; bcol0 = (ct - 16) * 128; klen = 512; kbeg = z * 512; }
  gemm64_core(Axx, Bt, C, kbeg, klen, K, 3072, blockIdx.y * 64, bcol0, ct * 128, 3072, As, Bs);
}

// generic 64x128 GEMM (final output projection), split-K=2 via blockIdx.z
__global__ __launch_bounds__(256) void gemm_bt64(const unsigned short* __restrict__ A,
                                                 const unsigned short* __restrict__ Bt,
                                                 float* __restrict__ C,
                                                 int K, int lda, int ldc) {
  __shared__ __align__(16) unsigned short As[64 * 32];
  __shared__ __align__(16) unsigned short Bs[128 * 32];
  const int half = K >> 1;
  gemm64_core(A, Bt, C, blockIdx.z * half, half, K, lda, blockIdx.y * 64,
              blockIdx.x * 128, blockIdx.x * 128, ldc, As, Bs);
}

// ---------------- cast x -> A'' = [x_hi | x_lo | x_hi] ----------------
__global__ __launch_bounds__(256) void cast_x_k(const float* __restrict__ x,
                                                unsigned short* __restrict__ Axx) {
  const int gid = blockIdx.x * 256 + threadIdx.x;
  float4 xv = ((const float4*)x)[gid];
  const int m = gid >> 8;
  const int c = (gid & 255) * 4;
  float vv[4] = {xv.x, xv.y, xv.z, xv.w};
  unsigned short h[4], l[4];
#pragma unroll
  for (int j = 0; j < 4; j++) {
    h[j] = f32_to_bf16(vv[j]);
    l[j] = f32_to_bf16(vv[j] - bf16_to_f32(h[j]));
  }
  ushort4 hv = make_ushort4(h[0], h[1], h[2], h[3]);
  ushort4 lv = make_ushort4(l[0], l[1], l[2], l[3]);
  *(ushort4*)&Axx[(size_t)m * 3072 + c] = hv;
  *(ushort4*)&Axx[(size_t)m * 3072 + 1024 + c] = lv;
  *(ushort4*)&Axx[(size_t)m * 3072 + 2048 + c] = hv;
}

// ---- transpose-cast Wq/Wk (by blockIdx.z) into Bqkv hi/hi/lo rows (K=3072) ----
__global__ void cast_wt3(const float* __restrict__ Wq, const float* __restrict__ Wk,
                         unsigned short* __restrict__ Bt) {
  __shared__ float tile[32][33];
  const float* W = (blockIdx.z == 0) ? Wq : Wk;
  const int n0 = blockIdx.z * 1024;
  const int kt0 = blockIdx.y * 32, nt0 = blockIdx.x * 32;
  const int tx = threadIdx.x, ty = threadIdx.y;
#pragma unroll
  for (int i = 0; i < 32; i += 8)
    tile[ty + i][tx] = W[(size_t)(kt0 + ty + i) * 1024 + nt0 + tx];
  __syncthreads();
#pragma unroll
  for (int i = 0; i < 32; i += 8) {
    const int n = nt0 + ty + i, kk = kt0 + tx;
    const float f = tile[tx][ty + i];
    const unsigned short hb = f32_to_bf16(f);
    const unsigned short lb = f32_to_bf16(f - bf16_to_f32(hb));
    const size_t base = (size_t)(n0 + n) * 3072;
    Bt[base + kk] = hb;
    Bt[base + 1024 + kk] = hb;
    Bt[base + 2048 + kk] = lb;
  }
}

// ---- transpose-cast 1024x1024 W -> Bt (1024n x 1024k) bf16 ----
__global__ void cast_wt1(const float* __restrict__ W, unsigned short* __restrict__ Bt) {
  __shared__ float tile[32][33];
  const int kt0 = blockIdx.y * 32, nt0 = blockIdx.x * 32;
  const int tx = threadIdx.x, ty = threadIdx.y;
#pragma unroll
  for (int i = 0; i < 32; i += 8)
    tile[ty + i][tx] = W[(size_t)(kt0 + ty + i) * 1024 + nt0 + tx];
  __syncthreads();
#pragma unroll
  for (int i = 0; i < 32; i += 8) {
    const int n = nt0 + ty + i, kk = kt0 + tx;
    Bt[(size_t)n * 1024 + kk] = f32_to_bf16(tile[tx][ty + i]);
  }
}

// ---- transpose-cast Wck/Wcv (1024x64) -> (64,1024) hi/lo bf16 ----
__global__ void cast_wct(const float* __restrict__ Wck, const float* __restrict__ Wcv,
                         unsigned short* __restrict__ KT_hi, unsigned short* __restrict__ KT_lo,
                         unsigned short* __restrict__ VT_hi, unsigned short* __restrict__ VT_lo) {
  __shared__ float tile[32][33];
  const float* W = blockIdx.z ? Wcv : Wck;
  unsigned short* Bh = blockIdx.z ? VT_hi : KT_hi;
  unsigned short* Bl = blockIdx.z ? VT_lo : KT_lo;
  const int kt0 = blockIdx.y * 32, nt0 = blockIdx.x * 32;
  const int tx = threadIdx.x, ty = threadIdx.y;
#pragma unroll
  for (int i = 0; i < 32; i += 8)
    tile[ty + i][tx] = W[(size_t)(kt0 + ty + i) * 64 + nt0 + tx];
  __syncthreads();
#pragma unroll
  for (int i = 0; i < 32; i += 8) {
    const int n = nt0 + ty + i, kk = kt0 + tx;
    const float f = tile[tx][ty + i];
    const unsigned short hb = f32_to_bf16(f);
    Bh[(size_t)n * 1024 + kk] = hb;
    Bl[(size_t)n * 1024 + kk] = f32_to_bf16(f - bf16_to_f32(hb));
  }
}

// ---------------- reorg: C(t,3072) -> qh f32, qhf f16 (T,1024),
//                  khfT f16 (H, 8, T, 8), vhf f16 (H, T, 64) ----------------
__global__ __launch_bounds__(256) void reorg_qkv(const float* __restrict__ C,
                                                 float* __restrict__ qh,
                                                 unsigned short* __restrict__ qhf,
                                                 unsigned short* __restrict__ khfT,
                                                 unsigned short* __restrict__ vhf) {
  const int gid = blockIdx.x * 256 + threadIdx.x;
  const int t = gid / 768;
  const int c = (gid - t * 768) * 4;
  float4 val = *(const float4*)&C[(size_t)t * 3072 + c];
  const unsigned int p0 = pack_h2(val.x, val.y);
  const unsigned int p1 = pack_h2(val.z, val.w);
  if (c < 1024) {
    *(float4*)&qh[(size_t)t * 1024 + c] = val;
    *(uint2*)&qhf[(size_t)t * 1024 + c] = make_uint2(p0, p1);
  } else if (c < 2048) {
    const int h = (c >> 6) & 15, d = c & 63;
    const int dc = d >> 3, j = d & 7;
    *(uint2*)&khfT[((size_t)(h * 8 + dc) * 2048 + t) * 8 + j] = make_uint2(p0, p1);
  } else {
    const int h = (c >> 6) & 15, d = c & 63;
    *(uint2*)&vhf[((size_t)h * 2048 + t) * 64 + d] = make_uint2(p0, p1);
  }
}

// ---------------- compress via MFMA (reads k/v straight from C) ----------------
// v2: 512 thr = 8 waves; each block owns 16 output rows (grid 128x2 = 256
// blocks), waves split K=1024 into 8 chunks of 128, partials reduced through
// padded LDS. (Fixed the round-0 1-wave/SIMD latency-exposed launch.)
__global__ __launch_bounds__(512) void compress_mfma(
    const float* __restrict__ C,
    const unsigned short* __restrict__ KT_hi, const unsigned short* __restrict__ KT_lo,
    const unsigned short* __restrict__ VT_hi, const unsigned short* __restrict__ VT_lo,
    unsigned short* __restrict__ kc_hi, unsigned short* __restrict__ kc_lo,
    unsigned short* __restrict__ vcT) {
  __shared__ float red[8][64][17];
  const int isv = blockIdx.y;
  const unsigned short* Bh = isv ? VT_hi : KT_hi;
  const unsigned short* Bl = isv ? VT_lo : KT_lo;
  const int tid = threadIdx.x, w = tid >> 6, lane = tid & 63;
  const int mrow = lane & 15, kgrp = lane >> 4;
  const int m0 = blockIdx.x * 16;
  const int m = m0 + mrow;
  const int hh = m >> 7, nb = m & 127;
  const int cbase = 1024 + isv * 1024 + hh * 64;

  floatx4 zero = {0.f, 0.f, 0.f, 0.f};
  floatx4 acc[4] = {zero, zero, zero, zero};

  const int kbeg = w << 7;                  // per-wave K chunk of 128
  for (int k0 = kbeg; k0 < kbeg + 128; k0 += 32) {
    const int c = k0 + kgrp * 8;
    const float* ap = &C[(size_t)(nb * 16 + (c >> 6)) * 3072 + cbase + (c & 63)];
    float4 q0 = *(const float4*)ap;
    float4 q1 = *(const float4*)(ap + 4);
    float qq[8] = {q0.x, q0.y, q0.z, q0.w, q1.x, q1.y, q1.z, q1.w};
    short8 a_hi, a_lo;
#pragma unroll
    for (int j = 0; j < 8; j++) {
      unsigned short hb = f32_to_bf16(qq[j]);
      a_hi[j] = (short)hb;
      a_lo[j] = (short)f32_to_bf16(qq[j] - bf16_to_f32(hb));
    }
#pragma unroll
    for (int ni = 0; ni < 4; ni++) {
      const size_t boff = (size_t)(ni * 16 + mrow) * 1024 + k0 + kgrp * 8;
      short8 b_hi = *(const short8*)&Bh[boff];
      short8 b_lo = *(const short8*)&Bl[boff];
      acc[ni] = __builtin_amdgcn_mfma_f32_16x16x32_bf16(a_hi, b_hi, acc[ni], 0, 0, 0);
      acc[ni] = __builtin_amdgcn_mfma_f32_16x16x32_bf16(a_lo, b_hi, acc[ni], 0, 0, 0);
      acc[ni] = __builtin_amdgcn_mfma_f32_16x16x32_bf16(a_hi, b_lo, acc[ni], 0, 0, 0);
    }
  }

  // cross-wave K reduction through LDS (pad 17 -> conflict-free)
#pragma unroll
  for (int ni = 0; ni < 4; ni++)
#pragma unroll
    for (int r = 0; r < 4; r++) red[w][lane][ni * 4 + r] = acc[ni][r];
  __syncthreads();

  if (w < 4) {                              // wave w stores d-columns w*16..w*16+15
#pragma unroll
    for (int r = 0; r < 4; r++) {
      const int j = w * 4 + r;
      float val = 0.f;
#pragma unroll
      for (int ww = 0; ww < 8; ww++) val += red[ww][lane][j];
      const int mo = m0 + kgrp * 4 + r;
      const int d = w * 16 + mrow;
      if (!isv) {
        const unsigned short hb = f32_to_bf16(val);
        kc_hi[(size_t)mo * 64 + d] = hb;
        kc_lo[(size_t)mo * 64 + d] = f32_to_bf16(val - bf16_to_f32(hb));
      } else {
        vcT[(size_t)(mo >> 7) * 8192 + (size_t)d * 128 + (mo & 127)] = f32_to_bf16(val);
      }
    }
  }
}

// ---------------- gates ----------------
__global__ __launch_bounds__(256) void gates_k(const float* __restrict__ C,
                                               const float* __restrict__ Wg,
                                               const float* __restrict__ bg,
                                               float* __restrict__ gates) {
  const int w = threadIdx.x >> 6, lane = threadIdx.x & 63;
  const int t = blockIdx.x * 4 + w;
  float m = 0.f;
#pragma unroll
  for (int h = 0; h < 16; h++) m += C[(size_t)t * 3072 + h * 64 + lane];
  m *= (1.f / 16.f);
  float g0 = wred_sum(m * Wg[lane * 3 + 0]);
  float g1 = wred_sum(m * Wg[lane * 3 + 1]);
  float g2 = wred_sum(m * Wg[lane * 3 + 2]);
  if (lane == 0) {
    g0 += bg[0]; g1 += bg[1]; g2 += bg[2];
    float mx = fmaxf(g0, fmaxf(g1, g2));
    float e0 = __expf(g0 - mx), e1 = __expf(g1 - mx), e2 = __expf(g2 - mx);
    float inv = 1.f / (e0 + e1 + e2);
    gates[t * 3 + 0] = e0 * inv;
    gates[t * 3 + 1] = e1 * inv;
    gates[t * 3 + 2] = e2 * inv;
  }
}

// ---------------- cscore: MFMA scores + softmax + top-4 -> P (bf16), sel ----
__global__ __launch_bounds__(256) void cscore_k(
    const float* __restrict__ qh, const unsigned short* __restrict__ kc_hi,
    const unsigned short* __restrict__ kc_lo, unsigned short* __restrict__ P,
    int4* __restrict__ sel) {
  __shared__ float S_s[16][132];
  const int h = blockIdx.x >> 7, t0 = (blockIdx.x & 127) * 16;
  const int tid = threadIdx.x, w = tid >> 6, lane = tid & 63;
  const int mrow = lane & 15, kgrp = lane >> 4;

  short8 a_hi[2], a_lo[2];
#pragma unroll
  for (int ks = 0; ks < 2; ks++) {
    const float* qp = &qh[(size_t)(t0 + mrow) * 1024 + h * 64 + ks * 32 + kgrp * 8];
    float4 q0 = *(const float4*)qp;
    float4 q1 = *(const float4*)(qp + 4);
    float qq[8] = {q0.x, q0.y, q0.z, q0.w, q1.x, q1.y, q1.z, q1.w};
#pragma unroll
    for (int j = 0; j < 8; j++) {
      unsigned short hb = f32_to_bf16(qq[j]);
      a_hi[ks][j] = (short)hb;
      a_lo[ks][j] = (short)f32_to_bf16(qq[j] - bf16_to_f32(hb));
    }
  }
  floatx4 zero = {0.f, 0.f, 0.f, 0.f};
  floatx4 acc[2] = {zero, zero};
#pragma unroll
  for (int ni = 0; ni < 2; ni++) {
    const int nb = w * 32 + ni * 16 + mrow;
#pragma unroll
    for (int ks = 0; ks < 2; ks++) {
      const size_t off = ((size_t)h * 128 + nb) * 64 + ks * 32 + kgrp * 8;
      short8 b_hi = *(const short8*)&kc_hi[off];
      short8 b_lo = *(const short8*)&kc_lo[off];
      acc[ni] = __builtin_amdgcn_mfma_f32_16x16x32_bf16(a_hi[ks], b_hi, acc[ni], 0, 0, 0);
      acc[ni] = __builtin_amdgcn_mfma_f32_16x16x32_bf16(a_lo[ks], b_hi, acc[ni], 0, 0, 0);
      acc[ni] = __builtin_amdgcn_mfma_f32_16x16x32_bf16(a_hi[ks], b_lo, acc[ni], 0, 0, 0);
    }
  }
#pragma unroll
  for (int ni = 0; ni < 2; ni++) {
    const int n = w * 32 + ni * 16 + mrow;
#pragma unroll
    for (int r = 0; r < 4; r++) {
      const int row = kgrp * 4 + r;
      const int count = (t0 + row) >> 4;
      S_s[row][n] = (n < count) ? acc[ni][r] * 0.125f : NEGC;
    }
  }
  __syncthreads();

  for (int qq = 0; qq < 4; qq++) {
    const int row = w * 4 + qq, t = t0 + row, count = t >> 4;
    const float2 sv = *(const float2*)&S_s[row][2 * lane];
    const float s0 = sv.x, s1 = sv.y;
    const float M = wred_max(fmaxf(s0, s1));
    const float e0 = __expf(s0 - M), e1 = __expf(s1 - M);
    const float inv = 1.f / wred_sum(e0 + e1);
    ushort2 pv;
    pv.x = (count == 0) ? (unsigned short)0 : f32_to_bf16(e0 * inv);
    pv.y = (count == 0) ? (unsigned short)0 : f32_to_bf16(e1 * inv);
    *(ushort2*)&P[(((size_t)h << 11) + t) * 128 + 2 * lane] = pv;

    float c0 = s0, c1 = s1;
    int sel0 = 0, sel1 = 0, sel2 = 0, sel3 = 0;
#pragma unroll
    for (int j = 0; j < 4; j++) {
      float bv; int bi;
      if (c0 >= c1) { bv = c0; bi = 2 * lane; } else { bv = c1; bi = 2 * lane + 1; }
#pragma unroll
      for (int o = 32; o > 0; o >>= 1) {
        const float ov = __shfl_xor(bv, o, 64);
        const int oi = __shfl_xor(bi, o, 64);
        if (ov > bv || (ov == bv && oi < bi)) { bv = ov; bi = oi; }
      }
      if (j == 0) sel0 = bi; else if (j == 1) sel1 = bi;
      else if (j == 2) sel2 = bi; else sel3 = bi;
      if (bi == 2 * lane) c0 = -FLT_MAX;
      if (bi == 2 * lane + 1) c1 = -FLT_MAX;
    }
    if (lane == 0) sel[((size_t)h << 11) + t] = make_int4(sel0, sel1, sel2, sel3);
  }
}

// ---------------- out_c = P @ vc : MFMA, fragment-direct, no LDS ----------------
__global__ __launch_bounds__(256) void outc_k(const unsigned short* __restrict__ P,
                                              const unsigned short* __restrict__ vcT,
                                              float* __restrict__ oc) {
  const int h = blockIdx.x >> 4, t0 = (blockIdx.x & 15) * 128;
  const int tid = threadIdx.x, w = tid >> 6, lane = tid & 63;
  const int mrow = lane & 15, kgrp = lane >> 4;
  floatx4 zero = {0.f, 0.f, 0.f, 0.f};
  floatx4 acc[2][4];
#pragma unroll
  for (int mi = 0; mi < 2; mi++)
#pragma unroll
    for (int ni = 0; ni < 4; ni++) acc[mi][ni] = zero;

#pragma unroll
  for (int ks = 0; ks < 4; ks++) {
    short8 a[2];
#pragma unroll
    for (int mi = 0; mi < 2; mi++) {
      const int t = t0 + w * 32 + mi * 16 + mrow;
      a[mi] = *(const short8*)&P[(((size_t)h << 11) + t) * 128 + ks * 32 + kgrp * 8];
    }
#pragma unroll
    for (int ni = 0; ni < 4; ni++) {
      const int d = ni * 16 + mrow;
      short8 b = *(const short8*)&vcT[((size_t)h * 64 + d) * 128 + ks * 32 + kgrp * 8];
      acc[0][ni] = __builtin_amdgcn_mfma_f32_16x16x32_bf16(a[0], b, acc[0][ni], 0, 0, 0);
      acc[1][ni] = __builtin_amdgcn_mfma_f32_16x16x32_bf16(a[1], b, acc[1][ni], 0, 0, 0);
    }
  }
#pragma unroll
  for (int mi = 0; mi < 2; mi++)
#pragma unroll
    for (int ni = 0; ni < 4; ni++)
#pragma unroll
      for (int r = 0; r < 4; r++)
        oc[(size_t)(t0 + w * 32 + mi * 16 + kgrp * 4 + r) * 1024 + h * 64 + ni * 16 + mrow] =
            acc[mi][ni][r];
}

// ---------------- selected + window branches + gated combine ----------------
__global__ __launch_bounds__(256) void nsa_swl(
    const unsigned short* __restrict__ qhf, const unsigned short* __restrict__ khfT,
    const unsigned short* __restrict__ vhf, const int4* __restrict__ sel,
    const float* __restrict__ oc, const float* __restrict__ gates,
    unsigned short* __restrict__ outf) {
  __shared__ float ps[4][64];
  const int bid = blockIdx.x;
  const int h = ((bid & 7) << 1) | ((bid >> 3) & 1);
  const int w = threadIdx.x >> 6, lane = threadIdx.x & 63;
  const int t = (bid >> 4) * 4 + w;

  const unsigned short* kT = khfT + (size_t)h * 131072;
  const unsigned short* vhh = vhf + (size_t)h * 131072;

  uint4 qr[8];
  {
    const uint4* qp = (const uint4*)(qhf + (size_t)t * 1024 + h * 64);
#pragma unroll
    for (int j = 0; j < 8; j++) qr[j] = qp[j];
  }
  const int4 s4 = sel[((size_t)h << 11) + t];

  const int g16 = lane >> 4;
  const int blk = (g16 == 0) ? s4.x : (g16 == 1) ? s4.y : (g16 == 2) ? s4.z : s4.w;
  const int tok = blk * 16 + (lane & 15);
  {
    float a0 = 0.f, a1 = 0.f, a2 = 0.f, a3 = 0.f;
#pragma unroll
    for (int dc = 0; dc < 8; dc++) {
      const uint4 kk = *(const uint4*)(kT + ((size_t)dc * 2048 + tok) * 8);
      a0 = fdot2u(kk.x, qr[dc].x, a0);
      a1 = fdot2u(kk.y, qr[dc].y, a1);
      a2 = fdot2u(kk.z, qr[dc].z, a2);
      a3 = fdot2u(kk.w, qr[dc].w, a3);
    }
    const float sv_ = (tok <= t) ? ((a0 + a1) + (a2 + a3)) * 0.125f : NEGC;
    const float Ms = wred_max(sv_);
    const float es = __expf(sv_ - Ms);
    ps[w][lane] = es * (1.f / wred_sum(es));
  }

  const int dd = lane & 31, s = lane >> 5;
  const float4* ps4 = (const float4*)ps[w];

  float osx = 0.f, osy = 0.f;
#pragma unroll
  for (int jc = 0; jc < 8; jc++) {
    const float4 p4 = ps4[s * 8 + jc];
    const float pa[4] = {p4.x, p4.y, p4.z, p4.w};
#pragma unroll
    for (int u = 0; u < 4; u++) {
      const int idx = s * 32 + jc * 4 + u;
      const int jb = idx >> 4;
      const int b2 = (jb == 0) ? s4.x : (jb == 1) ? s4.y : (jb == 2) ? s4.z : s4.w;
      const int tok2 = b2 * 16 + (idx & 15);
      const unsigned int vv = *(const unsigned int*)(vhh + (size_t)tok2 * 64 + 2 * dd);
      const h2 v2 = __builtin_bit_cast(h2, vv);
      osx += pa[u] * (float)v2[0];
      osy += pa[u] * (float)v2[1];
    }
  }
  osx += __shfl_xor(osx, 32, 64);
  osy += __shfl_xor(osy, 32, 64);

  {
    const int tw = t - 32 + lane;
    const int twc = min(max(tw, 0), T_LEN - 1);
    float a0 = 0.f, a1 = 0.f, a2 = 0.f, a3 = 0.f;
#pragma unroll
    for (int dc = 0; dc < 8; dc++) {
      const uint4 kk = *(const uint4*)(kT + ((size_t)dc * 2048 + twc) * 8);
      a0 = fdot2u(kk.x, qr[dc].x, a0);
      a1 = fdot2u(kk.y, qr[dc].y, a1);
      a2 = fdot2u(kk.z, qr[dc].z, a2);
      a3 = fdot2u(kk.w, qr[dc].w, a3);
    }
    const float swv = (tw >= 0 && lane <= 32) ? ((a0 + a1) + (a2 + a3)) * 0.125f : NEGC;
    const float Mw = wred_max(swv);
    const float ew = __expf(swv - Mw);
    ps[w][lane] = ew * (1.f / wred_sum(ew));
  }

  float olx = 0.f, oly = 0.f;
#pragma unroll
  for (int j = 0; j < 17; j++) {
    const int idx = s * 17 + j;
    const int idc = min(idx, 32);
    const float p = (idx <= 32) ? ps[w][idc] : 0.f;
    const int tk = min(max(t - 32 + idx, 0), T_LEN - 1);
    const unsigned int vv = *(const unsigned int*)(vhh + (size_t)tk * 64 + 2 * dd);
    const h2 v2 = __builtin_bit_cast(h2, vv);
    olx += p * (float)v2[0];
    oly += p * (float)v2[1];
  }
  olx += __shfl_xor(olx, 32, 64);
  oly += __shfl_xor(oly, 32, 64);

  if (lane < 32) {
    const float2 ocv = *(const float2*)&oc[(size_t)t * 1024 + h * 64 + 2 * dd];
    const float g0 = gates[t * 3 + 0], g1 = gates[t * 3 + 1], g2 = gates[t * 3 + 2];
    const float r0 = g0 * ocv.x + g1 * osx + g2 * olx;
    const float r1 = g0 * ocv.y + g1 * osy + g2 * oly;
    const unsigned int pk = (unsigned int)f32_to_bf16(r0) | ((unsigned int)f32_to_bf16(r1) << 16);
    *(unsigned int*)&outf[(size_t)t * DM + h * 64 + 2 * dd] = pk;
  }
}

// ---------------- launch ----------------
extern "C" void kernel_launch(void* const* d_in, const int* in_sizes, int n_in,
                              void* d_out, int out_size, void* d_ws, size_t ws_size,
                              hipStream_t stream) {
  const float* x   = (const float*)d_in[0];
  const float* Wq  = (const float*)d_in[1];
  const float* Wk  = (const float*)d_in[2];
  const float* Wv  = (const float*)d_in[3];
  const float* Wo  = (const float*)d_in[4];
  const float* Wck = (const float*)d_in[5];
  const float* Wcv = (const float*)d_in[6];
  const float* Wg  = (const float*)d_in[7];
  const float* bg  = (const float*)d_in[8];
  float* out = (float*)d_out;

  float* ws = (float*)d_ws;
  // region A [0,24 MB): C until compress_mfma; then P/oc/outf
  float*          C    = ws;
  unsigned short* P    = (unsigned short*)ws;               // [0,8 MB)
  float*          oc   = ws + 2097152;                      // [8,16 MB)
  unsigned short* outf = (unsigned short*)(ws + 4194304);   // [16,20 MB)
  // region B [24,36 MB): Axx until qkv GEMM; then qh + smalls
  unsigned short* Axx   = (unsigned short*)(ws + 6291456);
  float*          qh    = ws + 6291456;                     // [24,32 MB)
  unsigned short* Wot   = (unsigned short*)(ws + 8388608);  // [32,34 MB)
  unsigned short* kc_hi = (unsigned short*)(ws + 8912896);
  unsigned short* kc_lo = (unsigned short*)(ws + 8978432);
  unsigned short* vcT   = (unsigned short*)(ws + 9043968);
  int4*           sel   = (int4*)(ws + 9109504);
  unsigned short* WckT_hi = (unsigned short*)(ws + 9240576);
  unsigned short* WckT_lo = (unsigned short*)(ws + 9273344);
  unsigned short* WcvT_hi = (unsigned short*)(ws + 9306112);
  unsigned short* WcvT_lo = (unsigned short*)(ws + 9338880);
  float*          gates   = ws + 9371648;
  // region C [36,48 MB): Bqkv until qkv GEMM; then qhf/khfT/vhf f16
  unsigned short* Bqkv = (unsigned short*)(ws + 9437184);   // 2048x3072 bf16, 12 MB
  unsigned short* qhf  = (unsigned short*)(ws + 9437184);   // [36,40 MB)
  unsigned short* khfT = (unsigned short*)(ws + 10485760);  // [40,44 MB)
  unsigned short* vhf  = (unsigned short*)(ws + 11534336);  // [44,48 MB)
  // Wvt scratch lives in d_out (consumed by qkv_gemm before final GEMM writes out)
  unsigned short* Wvt = (unsigned short*)d_out;             // 1024x1024 bf16, 2 MB

  // 1. operand preparation (+ zero C for split-K atomics)
  zero_k<<<1536, 256, 0, stream>>>((float4*)C, 1572864);
  cast_x_k<<<2048, 256, 0, stream>>>(x, Axx);
  cast_wt3<<<dim3(32, 32, 2), dim3(32, 8), 0, stream>>>(Wq, Wk, Bqkv);
  cast_wt1<<<dim3(32, 32), dim3(32, 8), 0, stream>>>(Wv, Wvt);

  // 2. merged q|k|v GEMM: split-K=2 -> 1536 blocks (6/CU), atomicAdd epilogue
  qkv_gemm<<<dim3(24, 32, 2), 256, 0, stream>>>(Axx, Bqkv, Wvt, C);

  // 3. zero out (Wvt dead now) + reorg + gates; late weight casts
  zero_k<<<1024, 256, 0, stream>>>((float4*)out, 524288);
  reorg_qkv<<<6144, 256, 0, stream>>>(C, qh, qhf, khfT, vhf);
  gates_k<<<512, 256, 0, stream>>>(C, Wg, bg, gates);
  cast_wt1<<<dim3(32, 32), dim3(32, 8), 0, stream>>>(Wo, Wot);
  cast_wct<<<dim3(2, 32, 2), dim3(32, 8), 0, stream>>>(Wck, Wcv, WckT_hi, WckT_lo, WcvT_hi, WcvT_lo);

  // 4. compression (MFMA, reads C) + compressed-branch pipeline (C dead after)
  compress_mfma<<<dim3(128, 2), 512, 0, stream>>>(C, WckT_hi, WckT_lo, WcvT_hi, WcvT_lo,
                                                  kc_hi, kc_lo, vcT);
  cscore_k<<<2048, 256, 0, stream>>>(qh, kc_hi, kc_lo, P, sel);
  outc_k<<<256, 256, 0, stream>>>(P, vcT, oc);

  // 5. selected + window + gated combine
  nsa_swl<<<8192, 256, 0, stream>>>(qhf, khfT, vhf, sel, oc, gates, outf);

  // 6. output projection: split-K=2 -> 512 blocks, atomicAdd into zeroed out
  gemm_bt64<<<dim3(8, 32, 2), 256, 0, stream>>>(outf, Wot, out, 1024, 1024, 1024);
}

// Round 3
// 334.304 us; speedup vs baseline: 1.0385x; 1.0385x over previous
//
#include <hip/hip_runtime.h>
#include <hip/hip_bf16.h>
#include <float.h>

#define T_LEN 2048
#define DM    1024
#define NB    128
#define NEGC  (-1e9f)

typedef __attribute__((ext_vector_type(8))) short short8;
typedef __attribute__((ext_vector_type(4))) float floatx4;
typedef _Float16 h2 __attribute__((ext_vector_type(2)));

// ---------------- helpers ----------------
__device__ __forceinline__ float wred_max(float v) {
#pragma unroll
  for (int o = 32; o > 0; o >>= 1) v = fmaxf(v, __shfl_xor(v, o, 64));
  return v;
}
__device__ __forceinline__ float wred_sum(float v) {
#pragma unroll
  for (int o = 32; o > 0; o >>= 1) v += __shfl_xor(v, o, 64);
  return v;
}
__device__ __forceinline__ unsigned short f32_to_bf16(float f) {
  unsigned int b = __float_as_uint(f);
  return (unsigned short)((b + 0x7fffu + ((b >> 16) & 1u)) >> 16);
}
__device__ __forceinline__ float bf16_to_f32(unsigned short u) {
  return __uint_as_float(((unsigned int)u) << 16);
}
__device__ __forceinline__ unsigned int pack_h2(float a, float b) {
  h2 r; r[0] = (_Float16)a; r[1] = (_Float16)b;
  return __builtin_bit_cast(unsigned int, r);
}
__device__ __forceinline__ float fdot2u(unsigned int a, unsigned int b, float c) {
#if __has_builtin(__builtin_amdgcn_fdot2)
  return __builtin_amdgcn_fdot2(__builtin_bit_cast(h2, a), __builtin_bit_cast(h2, b), c, false);
#else
  const h2 av = __builtin_bit_cast(h2, a), bv = __builtin_bit_cast(h2, b);
  return c + (float)av[0] * (float)bv[0] + (float)av[1] * (float)bv[1];
#endif
}
__device__ __forceinline__ void lds_async16(unsigned short* l, const unsigned short* g) {
  __builtin_amdgcn_global_load_lds(
      (const __attribute__((address_space(1))) unsigned int*)g,
      (__attribute__((address_space(3))) unsigned int*)l, 16, 0, 0);
}

// =========== 64x128-tile bf16 MFMA GEMM core (chunk-major swizzled LDS) ======
// 256 thr = 4 waves (2 row-halves x 2 col-halves). BK=32. Round-0 proven
// structure: BK=64 dbuf (r1) and split-K atomics (r2) both regressed — this
// 2-barrier loop is latency-bound and concurrency knobs are null here.
// Staging: lane stages row = w*16+(lane&15), chunk = lane>>4 -> LDS addr is
// lane-contiguous (global_load_lds requirement) AND fragment reads land at
// byte kgrp*256 + mrow*16 -> bank = mrow*4 mod 32 (2-way aliasing = free).
__device__ __forceinline__ void gemm64_core(
    const unsigned short* __restrict__ A, const unsigned short* __restrict__ Bt,
    float* __restrict__ C, int K, int lda, int row0, int bcol0, int ccol0, int ldc,
    unsigned short* As, unsigned short* Bs) {
  const int tid = threadIdx.x;
  const int w = tid >> 6, lane = tid & 63;
  const int wr = w >> 1, wc = w & 1;
  const int mrow = lane & 15, kgrp = lane >> 4;

  const int sr = (w << 4) + mrow;          // staged row 0..63
  const int sc = kgrp;                     // staged chunk 0..3

  floatx4 zero = {0.f, 0.f, 0.f, 0.f};
  floatx4 acc[2][4];
#pragma unroll
  for (int i = 0; i < 2; i++)
#pragma unroll
    for (int j = 0; j < 4; j++) acc[i][j] = zero;

  for (int k0 = 0; k0 < K; k0 += 32) {
    lds_async16(&As[w * 512], A + (size_t)(row0 + sr) * lda + k0 + sc * 8);
    lds_async16(&Bs[w * 512], Bt + (size_t)(bcol0 + sr) * K + k0 + sc * 8);
    lds_async16(&Bs[2048 + w * 512], Bt + (size_t)(bcol0 + 64 + sr) * K + k0 + sc * 8);
    __syncthreads();
    short8 af[2], bf[4];
#pragma unroll
    for (int mi = 0; mi < 2; mi++)
      af[mi] = *(const short8*)&As[(wr * 2 + mi) * 512 + kgrp * 128 + mrow * 8];
#pragma unroll
    for (int ni = 0; ni < 4; ni++)
      bf[ni] = *(const short8*)&Bs[(wc * 4 + ni) * 512 + kgrp * 128 + mrow * 8];
#pragma unroll
    for (int mi = 0; mi < 2; mi++)
#pragma unroll
      for (int ni = 0; ni < 4; ni++)
        acc[mi][ni] = __builtin_amdgcn_mfma_f32_16x16x32_bf16(af[mi], bf[ni], acc[mi][ni], 0, 0, 0);
    __syncthreads();
  }
#pragma unroll
  for (int mi = 0; mi < 2; mi++)
#pragma unroll
    for (int ni = 0; ni < 4; ni++) {
      float* Cp = C + (size_t)(row0 + wr * 32 + mi * 16 + kgrp * 4) * ldc
                    + ccol0 + wc * 64 + ni * 16 + mrow;
      Cp[0] = acc[mi][ni][0];
      Cp[(size_t)ldc] = acc[mi][ni][1];
      Cp[(size_t)2 * ldc] = acc[mi][ni][2];
      Cp[(size_t)3 * ldc] = acc[mi][ni][3];
    }
}

// merged q|k|v GEMM: 768 blocks, 1D grid with XCD-aware col-major remap.
// task = (bid%8)*96 + bid/8 (bijective, 768%8==0): each XCD owns 3 consecutive
// col-panels x all 32 row-tiles -> B panel (768 KB) L2-hot (reuse distance 1
// block on same XCD; was 24 blocks -> 18 MB working set -> L2 thrash, 56 MB
// FETCH vs 26 MB unique). col-tiles 0..15: Bqkv (K=3072); 16..23: Wvt (K=1024).
__global__ __launch_bounds__(256) void qkv_gemm(const unsigned short* __restrict__ Axx,
                                                const unsigned short* __restrict__ Bqkv,
                                                const unsigned short* __restrict__ Wvt,
                                                float* __restrict__ C) {
  __shared__ __align__(16) unsigned short As[64 * 32];
  __shared__ __align__(16) unsigned short Bs[128 * 32];
  const int bid = blockIdx.x;
  const int task = (bid & 7) * 96 + (bid >> 3);
  const int ct = task >> 5, row = task & 31;
  const unsigned short* Bt;
  int K, bcol0;
  if (ct < 16) { Bt = Bqkv; K = 3072; bcol0 = ct * 128; }
  else         { Bt = Wvt;  K = 1024; bcol0 = (ct - 16) * 128; }
  gemm64_core(Axx, Bt, C, K, 3072, row * 64, bcol0, ct * 128, 3072, As, Bs);
}

// final output projection: 256 blocks, same XCD-aware remap (256%8==0):
// each XCD owns 1 col-panel (256 KB, L2-hot) x 32 row-tiles.
__global__ __launch_bounds__(256) void gemm_bt64(const unsigned short* __restrict__ A,
                                                 const unsigned short* __restrict__ Bt,
                                                 float* __restrict__ C,
                                                 int K, int lda, int ldc) {
  __shared__ __align__(16) unsigned short As[64 * 32];
  __shared__ __align__(16) unsigned short Bs[128 * 32];
  const int bid = blockIdx.x;
  const int task = (bid & 7) * 32 + (bid >> 3);
  const int ct = task >> 5, row = task & 31;
  gemm64_core(A, Bt, C, K, lda, row * 64, ct * 128, ct * 128, ldc, As, Bs);
}

// ---------------- cast x -> A'' = [x_hi | x_lo | x_hi] ----------------
__global__ __launch_bounds__(256) void cast_x_k(const float* __restrict__ x,
                                                unsigned short* __restrict__ Axx) {
  const int gid = blockIdx.x * 256 + threadIdx.x;
  float4 xv = ((const float4*)x)[gid];
  const int m = gid >> 8;
  const int c = (gid & 255) * 4;
  float vv[4] = {xv.x, xv.y, xv.z, xv.w};
  unsigned short h[4], l[4];
#pragma unroll
  for (int j = 0; j < 4; j++) {
    h[j] = f32_to_bf16(vv[j]);
    l[j] = f32_to_bf16(vv[j] - bf16_to_f32(h[j]));
  }
  ushort4 hv = make_ushort4(h[0], h[1], h[2], h[3]);
  ushort4 lv = make_ushort4(l[0], l[1], l[2], l[3]);
  *(ushort4*)&Axx[(size_t)m * 3072 + c] = hv;
  *(ushort4*)&Axx[(size_t)m * 3072 + 1024 + c] = lv;
  *(ushort4*)&Axx[(size_t)m * 3072 + 2048 + c] = hv;
}

// ---- transpose-cast Wq/Wk (by blockIdx.z) into Bqkv hi/hi/lo rows (K=3072) ----
__global__ void cast_wt3(const float* __restrict__ Wq, const float* __restrict__ Wk,
                         unsigned short* __restrict__ Bt) {
  __shared__ float tile[32][33];
  const float* W = (blockIdx.z == 0) ? Wq : Wk;
  const int n0 = blockIdx.z * 1024;
  const int kt0 = blockIdx.y * 32, nt0 = blockIdx.x * 32;
  const int tx = threadIdx.x, ty = threadIdx.y;
#pragma unroll
  for (int i = 0; i < 32; i += 8)
    tile[ty + i][tx] = W[(size_t)(kt0 + ty + i) * 1024 + nt0 + tx];
  __syncthreads();
#pragma unroll
  for (int i = 0; i < 32; i += 8) {
    const int n = nt0 + ty + i, kk = kt0 + tx;
    const float f = tile[tx][ty + i];
    const unsigned short hb = f32_to_bf16(f);
    const unsigned short lb = f32_to_bf16(f - bf16_to_f32(hb));
    const size_t base = (size_t)(n0 + n) * 3072;
    Bt[base + kk] = hb;
    Bt[base + 1024 + kk] = hb;
    Bt[base + 2048 + kk] = lb;
  }
}

// ---- transpose-cast 1024x1024 W -> Bt (1024n x 1024k) bf16 ----
__global__ void cast_wt1(const float* __restrict__ W, unsigned short* __restrict__ Bt) {
  __shared__ float tile[32][33];
  const int kt0 = blockIdx.y * 32, nt0 = blockIdx.x * 32;
  const int tx = threadIdx.x, ty = threadIdx.y;
#pragma unroll
  for (int i = 0; i < 32; i += 8)
    tile[ty + i][tx] = W[(size_t)(kt0 + ty + i) * 1024 + nt0 + tx];
  __syncthreads();
#pragma unroll
  for (int i = 0; i < 32; i += 8) {
    const int n = nt0 + ty + i, kk = kt0 + tx;
    Bt[(size_t)n * 1024 + kk] = f32_to_bf16(tile[tx][ty + i]);
  }
}

// ---- transpose-cast Wck/Wcv (1024x64) -> (64,1024) hi/lo bf16 ----
__global__ void cast_wct(const float* __restrict__ Wck, const float* __restrict__ Wcv,
                         unsigned short* __restrict__ KT_hi, unsigned short* __restrict__ KT_lo,
                         unsigned short* __restrict__ VT_hi, unsigned short* __restrict__ VT_lo) {
  __shared__ float tile[32][33];
  const float* W = blockIdx.z ? Wcv : Wck;
  unsigned short* Bh = blockIdx.z ? VT_hi : KT_hi;
  unsigned short* Bl = blockIdx.z ? VT_lo : KT_lo;
  const int kt0 = blockIdx.y * 32, nt0 = blockIdx.x * 32;
  const int tx = threadIdx.x, ty = threadIdx.y;
#pragma unroll
  for (int i = 0; i < 32; i += 8)
    tile[ty + i][tx] = W[(size_t)(kt0 + ty + i) * 64 + nt0 + tx];
  __syncthreads();
#pragma unroll
  for (int i = 0; i < 32; i += 8) {
    const int n = nt0 + ty + i, kk = kt0 + tx;
    const float f = tile[tx][ty + i];
    const unsigned short hb = f32_to_bf16(f);
    Bh[(size_t)n * 1024 + kk] = hb;
    Bl[(size_t)n * 1024 + kk] = f32_to_bf16(f - bf16_to_f32(hb));
  }
}

// ---------------- reorg: C(t,3072) -> qh f32, qhf f16 (T,1024),
//                  khfT f16 (H, 8, T, 8), vhf f16 (H, T, 64) ----------------
__global__ __launch_bounds__(256) void reorg_qkv(const float* __restrict__ C,
                                                 float* __restrict__ qh,
                                                 unsigned short* __restrict__ qhf,
                                                 unsigned short* __restrict__ khfT,
                                                 unsigned short* __restrict__ vhf) {
  const int gid = blockIdx.x * 256 + threadIdx.x;
  const int t = gid / 768;
  const int c = (gid - t * 768) * 4;
  float4 val = *(const float4*)&C[(size_t)t * 3072 + c];
  const unsigned int p0 = pack_h2(val.x, val.y);
  const unsigned int p1 = pack_h2(val.z, val.w);
  if (c < 1024) {
    *(float4*)&qh[(size_t)t * 1024 + c] = val;
    *(uint2*)&qhf[(size_t)t * 1024 + c] = make_uint2(p0, p1);
  } else if (c < 2048) {
    const int h = (c >> 6) & 15, d = c & 63;
    const int dc = d >> 3, j = d & 7;
    *(uint2*)&khfT[((size_t)(h * 8 + dc) * 2048 + t) * 8 + j] = make_uint2(p0, p1);
  } else {
    const int h = (c >> 6) & 15, d = c & 63;
    *(uint2*)&vhf[((size_t)h * 2048 + t) * 64 + d] = make_uint2(p0, p1);
  }
}

// ---------------- compress via MFMA (reads k/v straight from C) ----------------
// v2: 512 thr = 8 waves; each block owns 16 output rows (grid 128x2 = 256
// blocks), waves split K=1024 into 8 chunks of 128, partials reduced through
// padded LDS. (Fixed the round-0 1-wave/SIMD latency-exposed launch.)
__global__ __launch_bounds__(512) void compress_mfma(
    const float* __restrict__ C,
    const unsigned short* __restrict__ KT_hi, const unsigned short* __restrict__ KT_lo,
    const unsigned short* __restrict__ VT_hi, const unsigned short* __restrict__ VT_lo,
    unsigned short* __restrict__ kc_hi, unsigned short* __restrict__ kc_lo,
    unsigned short* __restrict__ vcT) {
  __shared__ float red[8][64][17];
  const int isv = blockIdx.y;
  const unsigned short* Bh = isv ? VT_hi : KT_hi;
  const unsigned short* Bl = isv ? VT_lo : KT_lo;
  const int tid = threadIdx.x, w = tid >> 6, lane = tid & 63;
  const int mrow = lane & 15, kgrp = lane >> 4;
  const int m0 = blockIdx.x * 16;
  const int m = m0 + mrow;
  const int hh = m >> 7, nb = m & 127;
  const int cbase = 1024 + isv * 1024 + hh * 64;

  floatx4 zero = {0.f, 0.f, 0.f, 0.f};
  floatx4 acc[4] = {zero, zero, zero, zero};

  const int kbeg = w << 7;                  // per-wave K chunk of 128
  for (int k0 = kbeg; k0 < kbeg + 128; k0 += 32) {
    const int c = k0 + kgrp * 8;
    const float* ap = &C[(size_t)(nb * 16 + (c >> 6)) * 3072 + cbase + (c & 63)];
    float4 q0 = *(const float4*)ap;
    float4 q1 = *(const float4*)(ap + 4);
    float qq[8] = {q0.x, q0.y, q0.z, q0.w, q1.x, q1.y, q1.z, q1.w};
    short8 a_hi, a_lo;
#pragma unroll
    for (int j = 0; j < 8; j++) {
      unsigned short hb = f32_to_bf16(qq[j]);
      a_hi[j] = (short)hb;
      a_lo[j] = (short)f32_to_bf16(qq[j] - bf16_to_f32(hb));
    }
#pragma unroll
    for (int ni = 0; ni < 4; ni++) {
      const size_t boff = (size_t)(ni * 16 + mrow) * 1024 + k0 + kgrp * 8;
      short8 b_hi = *(const short8*)&Bh[boff];
      short8 b_lo = *(const short8*)&Bl[boff];
      acc[ni] = __builtin_amdgcn_mfma_f32_16x16x32_bf16(a_hi, b_hi, acc[ni], 0, 0, 0);
      acc[ni] = __builtin_amdgcn_mfma_f32_16x16x32_bf16(a_lo, b_hi, acc[ni], 0, 0, 0);
      acc[ni] = __builtin_amdgcn_mfma_f32_16x16x32_bf16(a_hi, b_lo, acc[ni], 0, 0, 0);
    }
  }

  // cross-wave K reduction through LDS (pad 17 -> conflict-free)
#pragma unroll
  for (int ni = 0; ni < 4; ni++)
#pragma unroll
    for (int r = 0; r < 4; r++) red[w][lane][ni * 4 + r] = acc[ni][r];
  __syncthreads();

  if (w < 4) {                              // wave w stores d-columns w*16..w*16+15
#pragma unroll
    for (int r = 0; r < 4; r++) {
      const int j = w * 4 + r;
      float val = 0.f;
#pragma unroll
      for (int ww = 0; ww < 8; ww++) val += red[ww][lane][j];
      const int mo = m0 + kgrp * 4 + r;
      const int d = w * 16 + mrow;
      if (!isv) {
        const unsigned short hb = f32_to_bf16(val);
        kc_hi[(size_t)mo * 64 + d] = hb;
        kc_lo[(size_t)mo * 64 + d] = f32_to_bf16(val - bf16_to_f32(hb));
      } else {
        vcT[(size_t)(mo >> 7) * 8192 + (size_t)d * 128 + (mo & 127)] = f32_to_bf16(val);
      }
    }
  }
}

// ---------------- gates ----------------
__global__ __launch_bounds__(256) void gates_k(const float* __restrict__ C,
                                               const float* __restrict__ Wg,
                                               const float* __restrict__ bg,
                                               float* __restrict__ gates) {
  const int w = threadIdx.x >> 6, lane = threadIdx.x & 63;
  const int t = blockIdx.x * 4 + w;
  float m = 0.f;
#pragma unroll
  for (int h = 0; h < 16; h++) m += C[(size_t)t * 3072 + h * 64 + lane];
  m *= (1.f / 16.f);
  float g0 = wred_sum(m * Wg[lane * 3 + 0]);
  float g1 = wred_sum(m * Wg[lane * 3 + 1]);
  float g2 = wred_sum(m * Wg[lane * 3 + 2]);
  if (lane == 0) {
    g0 += bg[0]; g1 += bg[1]; g2 += bg[2];
    float mx = fmaxf(g0, fmaxf(g1, g2));
    float e0 = __expf(g0 - mx), e1 = __expf(g1 - mx), e2 = __expf(g2 - mx);
    float inv = 1.f / (e0 + e1 + e2);
    gates[t * 3 + 0] = e0 * inv;
    gates[t * 3 + 1] = e1 * inv;
    gates[t * 3 + 2] = e2 * inv;
  }
}

// ---------------- cscore: MFMA scores + softmax + top-4 -> P (bf16), sel ----
__global__ __launch_bounds__(256) void cscore_k(
    const float* __restrict__ qh, const unsigned short* __restrict__ kc_hi,
    const unsigned short* __restrict__ kc_lo, unsigned short* __restrict__ P,
    int4* __restrict__ sel) {
  __shared__ float S_s[16][132];
  const int h = blockIdx.x >> 7, t0 = (blockIdx.x & 127) * 16;
  const int tid = threadIdx.x, w = tid >> 6, lane = tid & 63;
  const int mrow = lane & 15, kgrp = lane >> 4;

  short8 a_hi[2], a_lo[2];
#pragma unroll
  for (int ks = 0; ks < 2; ks++) {
    const float* qp = &qh[(size_t)(t0 + mrow) * 1024 + h * 64 + ks * 32 + kgrp * 8];
    float4 q0 = *(const float4*)qp;
    float4 q1 = *(const float4*)(qp + 4);
    float qq[8] = {q0.x, q0.y, q0.z, q0.w, q1.x, q1.y, q1.z, q1.w};
#pragma unroll
    for (int j = 0; j < 8; j++) {
      unsigned short hb = f32_to_bf16(qq[j]);
      a_hi[ks][j] = (short)hb;
      a_lo[ks][j] = (short)f32_to_bf16(qq[j] - bf16_to_f32(hb));
    }
  }
  floatx4 zero = {0.f, 0.f, 0.f, 0.f};
  floatx4 acc[2] = {zero, zero};
#pragma unroll
  for (int ni = 0; ni < 2; ni++) {
    const int nb = w * 32 + ni * 16 + mrow;
#pragma unroll
    for (int ks = 0; ks < 2; ks++) {
      const size_t off = ((size_t)h * 128 + nb) * 64 + ks * 32 + kgrp * 8;
      short8 b_hi = *(const short8*)&kc_hi[off];
      short8 b_lo = *(const short8*)&kc_lo[off];
      acc[ni] = __builtin_amdgcn_mfma_f32_16x16x32_bf16(a_hi[ks], b_hi, acc[ni], 0, 0, 0);
      acc[ni] = __builtin_amdgcn_mfma_f32_16x16x32_bf16(a_lo[ks], b_hi, acc[ni], 0, 0, 0);
      acc[ni] = __builtin_amdgcn_mfma_f32_16x16x32_bf16(a_hi[ks], b_lo, acc[ni], 0, 0, 0);
    }
  }
#pragma unroll
  for (int ni = 0; ni < 2; ni++) {
    const int n = w * 32 + ni * 16 + mrow;
#pragma unroll
    for (int r = 0; r < 4; r++) {
      const int row = kgrp * 4 + r;
      const int count = (t0 + row) >> 4;
      S_s[row][n] = (n < count) ? acc[ni][r] * 0.125f : NEGC;
    }
  }
  __syncthreads();

  for (int qq = 0; qq < 4; qq++) {
    const int row = w * 4 + qq, t = t0 + row, count = t >> 4;
    const float2 sv = *(const float2*)&S_s[row][2 * lane];
    const float s0 = sv.x, s1 = sv.y;
    const float M = wred_max(fmaxf(s0, s1));
    const float e0 = __expf(s0 - M), e1 = __expf(s1 - M);
    const float inv = 1.f / wred_sum(e0 + e1);
    ushort2 pv;
    pv.x = (count == 0) ? (unsigned short)0 : f32_to_bf16(e0 * inv);
    pv.y = (count == 0) ? (unsigned short)0 : f32_to_bf16(e1 * inv);
    *(ushort2*)&P[(((size_t)h << 11) + t) * 128 + 2 * lane] = pv;

    float c0 = s0, c1 = s1;
    int sel0 = 0, sel1 = 0, sel2 = 0, sel3 = 0;
#pragma unroll
    for (int j = 0; j < 4; j++) {
      float bv; int bi;
      if (c0 >= c1) { bv = c0; bi = 2 * lane; } else { bv = c1; bi = 2 * lane + 1; }
#pragma unroll
      for (int o = 32; o > 0; o >>= 1) {
        const float ov = __shfl_xor(bv, o, 64);
        const int oi = __shfl_xor(bi, o, 64);
        if (ov > bv || (ov == bv && oi < bi)) { bv = ov; bi = oi; }
      }
      if (j == 0) sel0 = bi; else if (j == 1) sel1 = bi;
      else if (j == 2) sel2 = bi; else sel3 = bi;
      if (bi == 2 * lane) c0 = -FLT_MAX;
      if (bi == 2 * lane + 1) c1 = -FLT_MAX;
    }
    if (lane == 0) sel[((size_t)h << 11) + t] = make_int4(sel0, sel1, sel2, sel3);
  }
}

// ---------------- out_c = P @ vc : MFMA, fragment-direct, no LDS ----------------
__global__ __launch_bounds__(256) void outc_k(const unsigned short* __restrict__ P,
                                              const unsigned short* __restrict__ vcT,
                                              float* __restrict__ oc) {
  const int h = blockIdx.x >> 4, t0 = (blockIdx.x & 15) * 128;
  const int tid = threadIdx.x, w = tid >> 6, lane = tid & 63;
  const int mrow = lane & 15, kgrp = lane >> 4;
  floatx4 zero = {0.f, 0.f, 0.f, 0.f};
  floatx4 acc[2][4];
#pragma unroll
  for (int mi = 0; mi < 2; mi++)
#pragma unroll
    for (int ni = 0; ni < 4; ni++) acc[mi][ni] = zero;

#pragma unroll
  for (int ks = 0; ks < 4; ks++) {
    short8 a[2];
#pragma unroll
    for (int mi = 0; mi < 2; mi++) {
      const int t = t0 + w * 32 + mi * 16 + mrow;
      a[mi] = *(const short8*)&P[(((size_t)h << 11) + t) * 128 + ks * 32 + kgrp * 8];
    }
#pragma unroll
    for (int ni = 0; ni < 4; ni++) {
      const int d = ni * 16 + mrow;
      short8 b = *(const short8*)&vcT[((size_t)h * 64 + d) * 128 + ks * 32 + kgrp * 8];
      acc[0][ni] = __builtin_amdgcn_mfma_f32_16x16x32_bf16(a[0], b, acc[0][ni], 0, 0, 0);
      acc[1][ni] = __builtin_amdgcn_mfma_f32_16x16x32_bf16(a[1], b, acc[1][ni], 0, 0, 0);
    }
  }
#pragma unroll
  for (int mi = 0; mi < 2; mi++)
#pragma unroll
    for (int ni = 0; ni < 4; ni++)
#pragma unroll
      for (int r = 0; r < 4; r++)
        oc[(size_t)(t0 + w * 32 + mi * 16 + kgrp * 4 + r) * 1024 + h * 64 + ni * 16 + mrow] =
            acc[mi][ni][r];
}

// ---------------- selected + window branches + gated combine ----------------
__global__ __launch_bounds__(256) void nsa_swl(
    const unsigned short* __restrict__ qhf, const unsigned short* __restrict__ khfT,
    const unsigned short* __restrict__ vhf, const int4* __restrict__ sel,
    const float* __restrict__ oc, const float* __restrict__ gates,
    unsigned short* __restrict__ outf) {
  __shared__ float ps[4][64];
  const int bid = blockIdx.x;
  const int h = ((bid & 7) << 1) | ((bid >> 3) & 1);
  const int w = threadIdx.x >> 6, lane = threadIdx.x & 63;
  const int t = (bid >> 4) * 4 + w;

  const unsigned short* kT = khfT + (size_t)h * 131072;
  const unsigned short* vhh = vhf + (size_t)h * 131072;

  uint4 qr[8];
  {
    const uint4* qp = (const uint4*)(qhf + (size_t)t * 1024 + h * 64);
#pragma unroll
    for (int j = 0; j < 8; j++) qr[j] = qp[j];
  }
  const int4 s4 = sel[((size_t)h << 11) + t];

  const int g16 = lane >> 4;
  const int blk = (g16 == 0) ? s4.x : (g16 == 1) ? s4.y : (g16 == 2) ? s4.z : s4.w;
  const int tok = blk * 16 + (lane & 15);
  {
    float a0 = 0.f, a1 = 0.f, a2 = 0.f, a3 = 0.f;
#pragma unroll
    for (int dc = 0; dc < 8; dc++) {
      const uint4 kk = *(const uint4*)(kT + ((size_t)dc * 2048 + tok) * 8);
      a0 = fdot2u(kk.x, qr[dc].x, a0);
      a1 = fdot2u(kk.y, qr[dc].y, a1);
      a2 = fdot2u(kk.z, qr[dc].z, a2);
      a3 = fdot2u(kk.w, qr[dc].w, a3);
    }
    const float sv_ = (tok <= t) ? ((a0 + a1) + (a2 + a3)) * 0.125f : NEGC;
    const float Ms = wred_max(sv_);
    const float es = __expf(sv_ - Ms);
    ps[w][lane] = es * (1.f / wred_sum(es));
  }

  const int dd = lane & 31, s = lane >> 5;
  const float4* ps4 = (const float4*)ps[w];

  float osx = 0.f, osy = 0.f;
#pragma unroll
  for (int jc = 0; jc < 8; jc++) {
    const float4 p4 = ps4[s * 8 + jc];
    const float pa[4] = {p4.x, p4.y, p4.z, p4.w};
#pragma unroll
    for (int u = 0; u < 4; u++) {
      const int idx = s * 32 + jc * 4 + u;
      const int jb = idx >> 4;
      const int b2 = (jb == 0) ? s4.x : (jb == 1) ? s4.y : (jb == 2) ? s4.z : s4.w;
      const int tok2 = b2 * 16 + (idx & 15);
      const unsigned int vv = *(const unsigned int*)(vhh + (size_t)tok2 * 64 + 2 * dd);
      const h2 v2 = __builtin_bit_cast(h2, vv);
      osx += pa[u] * (float)v2[0];
      osy += pa[u] * (float)v2[1];
    }
  }
  osx += __shfl_xor(osx, 32, 64);
  osy += __shfl_xor(osy, 32, 64);

  {
    const int tw = t - 32 + lane;
    const int twc = min(max(tw, 0), T_LEN - 1);
    float a0 = 0.f, a1 = 0.f, a2 = 0.f, a3 = 0.f;
#pragma unroll
    for (int dc = 0; dc < 8; dc++) {
      const uint4 kk = *(const uint4*)(kT + ((size_t)dc * 2048 + twc) * 8);
      a0 = fdot2u(kk.x, qr[dc].x, a0);
      a1 = fdot2u(kk.y, qr[dc].y, a1);
      a2 = fdot2u(kk.z, qr[dc].z, a2);
      a3 = fdot2u(kk.w, qr[dc].w, a3);
    }
    const float swv = (tw >= 0 && lane <= 32) ? ((a0 + a1) + (a2 + a3)) * 0.125f : NEGC;
    const float Mw = wred_max(swv);
    const float ew = __expf(swv - Mw);
    ps[w][lane] = ew * (1.f / wred_sum(ew));
  }

  float olx = 0.f, oly = 0.f;
#pragma unroll
  for (int j = 0; j < 17; j++) {
    const int idx = s * 17 + j;
    const int idc = min(idx, 32);
    const float p = (idx <= 32) ? ps[w][idc] : 0.f;
    const int tk = min(max(t - 32 + idx, 0), T_LEN - 1);
    const unsigned int vv = *(const unsigned int*)(vhh + (size_t)tk * 64 + 2 * dd);
    const h2 v2 = __builtin_bit_cast(h2, vv);
    olx += p * (float)v2[0];
    oly += p * (float)v2[1];
  }
  olx += __shfl_xor(olx, 32, 64);
  oly += __shfl_xor(oly, 32, 64);

  if (lane < 32) {
    const float2 ocv = *(const float2*)&oc[(size_t)t * 1024 + h * 64 + 2 * dd];
    const float g0 = gates[t * 3 + 0], g1 = gates[t * 3 + 1], g2 = gates[t * 3 + 2];
    const float r0 = g0 * ocv.x + g1 * osx + g2 * olx;
    const float r1 = g0 * ocv.y + g1 * osy + g2 * oly;
    const unsigned int pk = (unsigned int)f32_to_bf16(r0) | ((unsigned int)f32_to_bf16(r1) << 16);
    *(unsigned int*)&outf[(size_t)t * DM + h * 64 + 2 * dd] = pk;
  }
}

// ---------------- launch ----------------
extern "C" void kernel_launch(void* const* d_in, const int* in_sizes, int n_in,
                              void* d_out, int out_size, void* d_ws, size_t ws_size,
                              hipStream_t stream) {
  const float* x   = (const float*)d_in[0];
  const float* Wq  = (const float*)d_in[1];
  const float* Wk  = (const float*)d_in[2];
  const float* Wv  = (const float*)d_in[3];
  const float* Wo  = (const float*)d_in[4];
  const float* Wck = (const float*)d_in[5];
  const float* Wcv = (const float*)d_in[6];
  const float* Wg  = (const float*)d_in[7];
  const float* bg  = (const float*)d_in[8];
  float* out = (float*)d_out;

  float* ws = (float*)d_ws;
  // region A [0,24 MB): C until compress_mfma; then P/oc/outf
  float*          C    = ws;
  unsigned short* P    = (unsigned short*)ws;               // [0,8 MB)
  float*          oc   = ws + 2097152;                      // [8,16 MB)
  unsigned short* outf = (unsigned short*)(ws + 4194304);   // [16,20 MB)
  // region B [24,36 MB): Axx until qkv GEMM; then qh + smalls
  unsigned short* Axx   = (unsigned short*)(ws + 6291456);
  float*          qh    = ws + 6291456;                     // [24,32 MB)
  unsigned short* Wot   = (unsigned short*)(ws + 8388608);  // [32,34 MB)
  unsigned short* kc_hi = (unsigned short*)(ws + 8912896);
  unsigned short* kc_lo = (unsigned short*)(ws + 8978432);
  unsigned short* vcT   = (unsigned short*)(ws + 9043968);
  int4*           sel   = (int4*)(ws + 9109504);
  unsigned short* WckT_hi = (unsigned short*)(ws + 9240576);
  unsigned short* WckT_lo = (unsigned short*)(ws + 9273344);
  unsigned short* WcvT_hi = (unsigned short*)(ws + 9306112);
  unsigned short* WcvT_lo = (unsigned short*)(ws + 9338880);
  float*          gates   = ws + 9371648;
  // region C [36,48 MB): Bqkv until qkv GEMM; then qhf/khfT/vhf f16
  unsigned short* Bqkv = (unsigned short*)(ws + 9437184);   // 2048x3072 bf16, 12 MB
  unsigned short* qhf  = (unsigned short*)(ws + 9437184);   // [36,40 MB)
  unsigned short* khfT = (unsigned short*)(ws + 10485760);  // [40,44 MB)
  unsigned short* vhf  = (unsigned short*)(ws + 11534336);  // [44,48 MB)
  // Wvt scratch lives in d_out (consumed by qkv_gemm before final GEMM writes out)
  unsigned short* Wvt = (unsigned short*)d_out;             // 1024x1024 bf16, 2 MB

  // 1. operand preparation
  cast_x_k<<<2048, 256, 0, stream>>>(x, Axx);
  cast_wt3<<<dim3(32, 32, 2), dim3(32, 8), 0, stream>>>(Wq, Wk, Bqkv);
  cast_wt1<<<dim3(32, 32), dim3(32, 8), 0, stream>>>(Wv, Wvt);

  // 2. merged q|k|v GEMM: 768 blocks (3/CU), XCD-aware col-major remap
  qkv_gemm<<<768, 256, 0, stream>>>(Axx, Bqkv, Wvt, C);

  // 3. reorg + gates (C stays alive for compress); late weight casts
  reorg_qkv<<<6144, 256, 0, stream>>>(C, qh, qhf, khfT, vhf);
  gates_k<<<512, 256, 0, stream>>>(C, Wg, bg, gates);
  cast_wt1<<<dim3(32, 32), dim3(32, 8), 0, stream>>>(Wo, Wot);
  cast_wct<<<dim3(2, 32, 2), dim3(32, 8), 0, stream>>>(Wck, Wcv, WckT_hi, WckT_lo, WcvT_hi, WcvT_lo);

  // 4. compression (MFMA, reads C) + compressed-branch pipeline (C dead after)
  compress_mfma<<<dim3(128, 2), 512, 0, stream>>>(C, WckT_hi, WckT_lo, WcvT_hi, WcvT_lo,
                                                  kc_hi, kc_lo, vcT);
  cscore_k<<<2048, 256, 0, stream>>>(qh, kc_hi, kc_lo, P, sel);
  outc_k<<<256, 256, 0, stream>>>(P, vcT, oc);

  // 5. selected + window + gated combine
  nsa_swl<<<8192, 256, 0, stream>>>(qhf, khfT, vhf, sel, oc, gates, outf);

  // 6. output projection (64x128 tiles, 256 blocks, XCD-aware remap)
  gemm_bt64<<<256, 256, 0, stream>>>(outf, Wot, out, 1024, 1024, 1024);
}

// Round 4
// 262.528 us; speedup vs baseline: 1.3225x; 1.2734x over previous
//
#include <hip/hip_runtime.h>
#include <hip/hip_bf16.h>
#include <float.h>

#define T_LEN 2048
#define DM    1024
#define NB    128
#define NEGC  (-1e9f)

typedef __attribute__((ext_vector_type(8))) short short8;
typedef __attribute__((ext_vector_type(4))) float floatx4;
typedef _Float16 h2 __attribute__((ext_vector_type(2)));
typedef _Float16 h8 __attribute__((ext_vector_type(8)));

// ---------------- helpers ----------------
__device__ __forceinline__ float wred_max(float v) {
#pragma unroll
  for (int o = 32; o > 0; o >>= 1) v = fmaxf(v, __shfl_xor(v, o, 64));
  return v;
}
__device__ __forceinline__ float wred_sum(float v) {
#pragma unroll
  for (int o = 32; o > 0; o >>= 1) v += __shfl_xor(v, o, 64);
  return v;
}
__device__ __forceinline__ unsigned short f32_to_bf16(float f) {
  unsigned int b = __float_as_uint(f);
  return (unsigned short)((b + 0x7fffu + ((b >> 16) & 1u)) >> 16);
}
__device__ __forceinline__ float bf16_to_f32(unsigned short u) {
  return __uint_as_float(((unsigned int)u) << 16);
}
__device__ __forceinline__ unsigned int pack_h2(float a, float b) {
  h2 r; r[0] = (_Float16)a; r[1] = (_Float16)b;
  return __builtin_bit_cast(unsigned int, r);
}
__device__ __forceinline__ float fdot2u(unsigned int a, unsigned int b, float c) {
#if __has_builtin(__builtin_amdgcn_fdot2)
  return __builtin_amdgcn_fdot2(__builtin_bit_cast(h2, a), __builtin_bit_cast(h2, b), c, false);
#else
  const h2 av = __builtin_bit_cast(h2, a), bv = __builtin_bit_cast(h2, b);
  return c + (float)av[0] * (float)bv[0] + (float)av[1] * (float)bv[1];
#endif
}
__device__ __forceinline__ void lds_async16(unsigned short* l, const unsigned short* g) {
  __builtin_amdgcn_global_load_lds(
      (const __attribute__((address_space(1))) unsigned int*)g,
      (__attribute__((address_space(3))) unsigned int*)l, 16, 0, 0);
}

// =========== 64x128-tile MFMA GEMM core (chunk-major swizzled LDS) ======
// 256 thr = 4 waves (2 row-halves x 2 col-halves). BK=32. Round-0 proven
// structure: BK=64 dbuf (r1), split-K atomics (r2), XCD remap (r3) all
// regressed — per-step time is first-touch-latency-bound (~1 us/step), so the
// lever is FEWER STEPS (round 4: f16 single-pass, K 3072->1024), not how the
// bytes move. F16 selects v_mfma f16 (11-bit mantissa) vs bf16.
// Staging: lane stages row = w*16+(lane&15), chunk = lane>>4 -> LDS addr is
// lane-contiguous (global_load_lds requirement) AND fragment reads land at
// byte kgrp*256 + mrow*16 -> bank = mrow*4 mod 32 (2-way aliasing = free).
template <bool F16>
__device__ __forceinline__ void gemm64_core(
    const unsigned short* __restrict__ A, const unsigned short* __restrict__ Bt,
    float* __restrict__ C, int K, int lda, int row0, int bcol0, int ccol0, int ldc,
    unsigned short* As, unsigned short* Bs) {
  const int tid = threadIdx.x;
  const int w = tid >> 6, lane = tid & 63;
  const int wr = w >> 1, wc = w & 1;
  const int mrow = lane & 15, kgrp = lane >> 4;

  const int sr = (w << 4) + mrow;          // staged row 0..63
  const int sc = kgrp;                     // staged chunk 0..3

  floatx4 zero = {0.f, 0.f, 0.f, 0.f};
  floatx4 acc[2][4];
#pragma unroll
  for (int i = 0; i < 2; i++)
#pragma unroll
    for (int j = 0; j < 4; j++) acc[i][j] = zero;

  for (int k0 = 0; k0 < K; k0 += 32) {
    lds_async16(&As[w * 512], A + (size_t)(row0 + sr) * lda + k0 + sc * 8);
    lds_async16(&Bs[w * 512], Bt + (size_t)(bcol0 + sr) * K + k0 + sc * 8);
    lds_async16(&Bs[2048 + w * 512], Bt + (size_t)(bcol0 + 64 + sr) * K + k0 + sc * 8);
    __syncthreads();
    short8 af[2], bf[4];
#pragma unroll
    for (int mi = 0; mi < 2; mi++)
      af[mi] = *(const short8*)&As[(wr * 2 + mi) * 512 + kgrp * 128 + mrow * 8];
#pragma unroll
    for (int ni = 0; ni < 4; ni++)
      bf[ni] = *(const short8*)&Bs[(wc * 4 + ni) * 512 + kgrp * 128 + mrow * 8];
#pragma unroll
    for (int mi = 0; mi < 2; mi++)
#pragma unroll
      for (int ni = 0; ni < 4; ni++) {
        if constexpr (F16)
          acc[mi][ni] = __builtin_amdgcn_mfma_f32_16x16x32_f16(
              __builtin_bit_cast(h8, af[mi]), __builtin_bit_cast(h8, bf[ni]),
              acc[mi][ni], 0, 0, 0);
        else
          acc[mi][ni] = __builtin_amdgcn_mfma_f32_16x16x32_bf16(af[mi], bf[ni],
                                                                acc[mi][ni], 0, 0, 0);
      }
    __syncthreads();
  }
#pragma unroll
  for (int mi = 0; mi < 2; mi++)
#pragma unroll
    for (int ni = 0; ni < 4; ni++) {
      float* Cp = C + (size_t)(row0 + wr * 32 + mi * 16 + kgrp * 4) * ldc
                    + ccol0 + wc * 64 + ni * 16 + mrow;
      Cp[0] = acc[mi][ni][0];
      Cp[(size_t)ldc] = acc[mi][ni][1];
      Cp[(size_t)2 * ldc] = acc[mi][ni][2];
      Cp[(size_t)3 * ldc] = acc[mi][ni][3];
    }
}

// merged q|k|v GEMM: grid (24, 32) — round-0 mapping (x fastest: each XCD gets
// ct%8, CU-co-resident blocks share the A row-panel; r3 remap regressed).
// Single f16 pass, K=1024: Bqkv rows 0..1023 = Wq^T, 1024..2047 = Wk^T,
// 2048..3071 = Wv^T. C cols land [q|k|v] as reorg expects.
__global__ __launch_bounds__(256) void qkv_gemm(const unsigned short* __restrict__ Axf,
                                                const unsigned short* __restrict__ Bqkv,
                                                float* __restrict__ C) {
  __shared__ __align__(16) unsigned short As[64 * 32];
  __shared__ __align__(16) unsigned short Bs[128 * 32];
  gemm64_core<true>(Axf, Bqkv, C, 1024, 1024, blockIdx.y * 64,
                    blockIdx.x * 128, blockIdx.x * 128, 3072, As, Bs);
}

// final output projection (bf16 inputs), round-0 2D grid
__global__ __launch_bounds__(256) void gemm_bt64(const unsigned short* __restrict__ A,
                                                 const unsigned short* __restrict__ Bt,
                                                 float* __restrict__ C,
                                                 int K, int lda, int ldc) {
  __shared__ __align__(16) unsigned short As[64 * 32];
  __shared__ __align__(16) unsigned short Bs[128 * 32];
  gemm64_core<false>(A, Bt, C, K, lda, blockIdx.y * 64,
                     blockIdx.x * 128, blockIdx.x * 128, ldc, As, Bs);
}

// ---------------- cast x -> f16 (2048 x 1024) ----------------
__global__ __launch_bounds__(256) void cast_x_k(const float* __restrict__ x,
                                                unsigned short* __restrict__ Axf) {
  const int gid = blockIdx.x * 256 + threadIdx.x;
  float4 xv = ((const float4*)x)[gid];
  const unsigned int p0 = pack_h2(xv.x, xv.y);
  const unsigned int p1 = pack_h2(xv.z, xv.w);
  *(uint2*)&Axf[(size_t)gid * 4] = make_uint2(p0, p1);
}

// ---- transpose-cast Wq/Wk/Wv (by blockIdx.z) into Bqkv f16 (3072n x 1024k) ----
__global__ void cast_wqkv(const float* __restrict__ Wq, const float* __restrict__ Wk,
                          const float* __restrict__ Wv, unsigned short* __restrict__ Bt) {
  __shared__ float tile[32][33];
  const float* W = (blockIdx.z == 0) ? Wq : (blockIdx.z == 1) ? Wk : Wv;
  const int n0 = blockIdx.z * 1024;
  const int kt0 = blockIdx.y * 32, nt0 = blockIdx.x * 32;
  const int tx = threadIdx.x, ty = threadIdx.y;
#pragma unroll
  for (int i = 0; i < 32; i += 8)
    tile[ty + i][tx] = W[(size_t)(kt0 + ty + i) * 1024 + nt0 + tx];
  __syncthreads();
#pragma unroll
  for (int i = 0; i < 32; i += 8) {
    const int n = nt0 + ty + i, kk = kt0 + tx;
    h2 r; r[0] = (_Float16)tile[tx][ty + i]; r[1] = (_Float16)0.f;
    Bt[(size_t)(n0 + n) * 1024 + kk] = (unsigned short)(__builtin_bit_cast(unsigned int, r) & 0xffffu);
  }
}

// ---- transpose-cast 1024x1024 W -> Bt (1024n x 1024k) bf16 ----
__global__ void cast_wt1(const float* __restrict__ W, unsigned short* __restrict__ Bt) {
  __shared__ float tile[32][33];
  const int kt0 = blockIdx.y * 32, nt0 = blockIdx.x * 32;
  const int tx = threadIdx.x, ty = threadIdx.y;
#pragma unroll
  for (int i = 0; i < 32; i += 8)
    tile[ty + i][tx] = W[(size_t)(kt0 + ty + i) * 1024 + nt0 + tx];
  __syncthreads();
#pragma unroll
  for (int i = 0; i < 32; i += 8) {
    const int n = nt0 + ty + i, kk = kt0 + tx;
    Bt[(size_t)n * 1024 + kk] = f32_to_bf16(tile[tx][ty + i]);
  }
}

// ---- transpose-cast Wck/Wcv (1024x64) -> (64,1024) hi/lo bf16 ----
__global__ void cast_wct(const float* __restrict__ Wck, const float* __restrict__ Wcv,
                         unsigned short* __restrict__ KT_hi, unsigned short* __restrict__ KT_lo,
                         unsigned short* __restrict__ VT_hi, unsigned short* __restrict__ VT_lo) {
  __shared__ float tile[32][33];
  const float* W = blockIdx.z ? Wcv : Wck;
  unsigned short* Bh = blockIdx.z ? VT_hi : KT_hi;
  unsigned short* Bl = blockIdx.z ? VT_lo : KT_lo;
  const int kt0 = blockIdx.y * 32, nt0 = blockIdx.x * 32;
  const int tx = threadIdx.x, ty = threadIdx.y;
#pragma unroll
  for (int i = 0; i < 32; i += 8)
    tile[ty + i][tx] = W[(size_t)(kt0 + ty + i) * 64 + nt0 + tx];
  __syncthreads();
#pragma unroll
  for (int i = 0; i < 32; i += 8) {
    const int n = nt0 + ty + i, kk = kt0 + tx;
    const float f = tile[tx][ty + i];
    const unsigned short hb = f32_to_bf16(f);
    Bh[(size_t)n * 1024 + kk] = hb;
    Bl[(size_t)n * 1024 + kk] = f32_to_bf16(f - bf16_to_f32(hb));
  }
}

// ---------------- reorg: C(t,3072) -> qh f32, qhf f16 (T,1024),
//                  khfT f16 (H, 8, T, 8), vhf f16 (H, T, 64) ----------------
__global__ __launch_bounds__(256) void reorg_qkv(const float* __restrict__ C,
                                                 float* __restrict__ qh,
                                                 unsigned short* __restrict__ qhf,
                                                 unsigned short* __restrict__ khfT,
                                                 unsigned short* __restrict__ vhf) {
  const int gid = blockIdx.x * 256 + threadIdx.x;
  const int t = gid / 768;
  const int c = (gid - t * 768) * 4;
  float4 val = *(const float4*)&C[(size_t)t * 3072 + c];
  const unsigned int p0 = pack_h2(val.x, val.y);
  const unsigned int p1 = pack_h2(val.z, val.w);
  if (c < 1024) {
    *(float4*)&qh[(size_t)t * 1024 + c] = val;
    *(uint2*)&qhf[(size_t)t * 1024 + c] = make_uint2(p0, p1);
  } else if (c < 2048) {
    const int h = (c >> 6) & 15, d = c & 63;
    const int dc = d >> 3, j = d & 7;
    *(uint2*)&khfT[((size_t)(h * 8 + dc) * 2048 + t) * 8 + j] = make_uint2(p0, p1);
  } else {
    const int h = (c >> 6) & 15, d = c & 63;
    *(uint2*)&vhf[((size_t)h * 2048 + t) * 64 + d] = make_uint2(p0, p1);
  }
}

// ---------------- compress via MFMA (reads k/v straight from C) ----------------
// v2: 512 thr = 8 waves; each block owns 16 output rows (grid 128x2 = 256
// blocks), waves split K=1024 into 8 chunks of 128, partials reduced through
// padded LDS. (Fixed the round-0 1-wave/SIMD latency-exposed launch.)
__global__ __launch_bounds__(512) void compress_mfma(
    const float* __restrict__ C,
    const unsigned short* __restrict__ KT_hi, const unsigned short* __restrict__ KT_lo,
    const unsigned short* __restrict__ VT_hi, const unsigned short* __restrict__ VT_lo,
    unsigned short* __restrict__ kc_hi, unsigned short* __restrict__ kc_lo,
    unsigned short* __restrict__ vcT) {
  __shared__ float red[8][64][17];
  const int isv = blockIdx.y;
  const unsigned short* Bh = isv ? VT_hi : KT_hi;
  const unsigned short* Bl = isv ? VT_lo : KT_lo;
  const int tid = threadIdx.x, w = tid >> 6, lane = tid & 63;
  const int mrow = lane & 15, kgrp = lane >> 4;
  const int m0 = blockIdx.x * 16;
  const int m = m0 + mrow;
  const int hh = m >> 7, nb = m & 127;
  const int cbase = 1024 + isv * 1024 + hh * 64;

  floatx4 zero = {0.f, 0.f, 0.f, 0.f};
  floatx4 acc[4] = {zero, zero, zero, zero};

  const int kbeg = w << 7;                  // per-wave K chunk of 128
  for (int k0 = kbeg; k0 < kbeg + 128; k0 += 32) {
    const int c = k0 + kgrp * 8;
    const float* ap = &C[(size_t)(nb * 16 + (c >> 6)) * 3072 + cbase + (c & 63)];
    float4 q0 = *(const float4*)ap;
    float4 q1 = *(const float4*)(ap + 4);
    float qq[8] = {q0.x, q0.y, q0.z, q0.w, q1.x, q1.y, q1.z, q1.w};
    short8 a_hi, a_lo;
#pragma unroll
    for (int j = 0; j < 8; j++) {
      unsigned short hb = f32_to_bf16(qq[j]);
      a_hi[j] = (short)hb;
      a_lo[j] = (short)f32_to_bf16(qq[j] - bf16_to_f32(hb));
    }
#pragma unroll
    for (int ni = 0; ni < 4; ni++) {
      const size_t boff = (size_t)(ni * 16 + mrow) * 1024 + k0 + kgrp * 8;
      short8 b_hi = *(const short8*)&Bh[boff];
      short8 b_lo = *(const short8*)&Bl[boff];
      acc[ni] = __builtin_amdgcn_mfma_f32_16x16x32_bf16(a_hi, b_hi, acc[ni], 0, 0, 0);
      acc[ni] = __builtin_amdgcn_mfma_f32_16x16x32_bf16(a_lo, b_hi, acc[ni], 0, 0, 0);
      acc[ni] = __builtin_amdgcn_mfma_f32_16x16x32_bf16(a_hi, b_lo, acc[ni], 0, 0, 0);
    }
  }

  // cross-wave K reduction through LDS (pad 17 -> conflict-free)
#pragma unroll
  for (int ni = 0; ni < 4; ni++)
#pragma unroll
    for (int r = 0; r < 4; r++) red[w][lane][ni * 4 + r] = acc[ni][r];
  __syncthreads();

  if (w < 4) {                              // wave w stores d-columns w*16..w*16+15
#pragma unroll
    for (int r = 0; r < 4; r++) {
      const int j = w * 4 + r;
      float val = 0.f;
#pragma unroll
      for (int ww = 0; ww < 8; ww++) val += red[ww][lane][j];
      const int mo = m0 + kgrp * 4 + r;
      const int d = w * 16 + mrow;
      if (!isv) {
        const unsigned short hb = f32_to_bf16(val);
        kc_hi[(size_t)mo * 64 + d] = hb;
        kc_lo[(size_t)mo * 64 + d] = f32_to_bf16(val - bf16_to_f32(hb));
      } else {
        vcT[(size_t)(mo >> 7) * 8192 + (size_t)d * 128 + (mo & 127)] = f32_to_bf16(val);
      }
    }
  }
}

// ---------------- gates ----------------
__global__ __launch_bounds__(256) void gates_k(const float* __restrict__ C,
                                               const float* __restrict__ Wg,
                                               const float* __restrict__ bg,
                                               float* __restrict__ gates) {
  const int w = threadIdx.x >> 6, lane = threadIdx.x & 63;
  const int t = blockIdx.x * 4 + w;
  float m = 0.f;
#pragma unroll
  for (int h = 0; h < 16; h++) m += C[(size_t)t * 3072 + h * 64 + lane];
  m *= (1.f / 16.f);
  float g0 = wred_sum(m * Wg[lane * 3 + 0]);
  float g1 = wred_sum(m * Wg[lane * 3 + 1]);
  float g2 = wred_sum(m * Wg[lane * 3 + 2]);
  if (lane == 0) {
    g0 += bg[0]; g1 += bg[1]; g2 += bg[2];
    float mx = fmaxf(g0, fmaxf(g1, g2));
    float e0 = __expf(g0 - mx), e1 = __expf(g1 - mx), e2 = __expf(g2 - mx);
    float inv = 1.f / (e0 + e1 + e2);
    gates[t * 3 + 0] = e0 * inv;
    gates[t * 3 + 1] = e1 * inv;
    gates[t * 3 + 2] = e2 * inv;
  }
}

// ---------------- cscore: MFMA scores + softmax + top-4 -> P (bf16), sel ----
__global__ __launch_bounds__(256) void cscore_k(
    const float* __restrict__ qh, const unsigned short* __restrict__ kc_hi,
    const unsigned short* __restrict__ kc_lo, unsigned short* __restrict__ P,
    int4* __restrict__ sel) {
  __shared__ float S_s[16][132];
  const int h = blockIdx.x >> 7, t0 = (blockIdx.x & 127) * 16;
  const int tid = threadIdx.x, w = tid >> 6, lane = tid & 63;
  const int mrow = lane & 15, kgrp = lane >> 4;

  short8 a_hi[2], a_lo[2];
#pragma unroll
  for (int ks = 0; ks < 2; ks++) {
    const float* qp = &qh[(size_t)(t0 + mrow) * 1024 + h * 64 + ks * 32 + kgrp * 8];
    float4 q0 = *(const float4*)qp;
    float4 q1 = *(const float4*)(qp + 4);
    float qq[8] = {q0.x, q0.y, q0.z, q0.w, q1.x, q1.y, q1.z, q1.w};
#pragma unroll
    for (int j = 0; j < 8; j++) {
      unsigned short hb = f32_to_bf16(qq[j]);
      a_hi[ks][j] = (short)hb;
      a_lo[ks][j] = (short)f32_to_bf16(qq[j] - bf16_to_f32(hb));
    }
  }
  floatx4 zero = {0.f, 0.f, 0.f, 0.f};
  floatx4 acc[2] = {zero, zero};
#pragma unroll
  for (int ni = 0; ni < 2; ni++) {
    const int nb = w * 32 + ni * 16 + mrow;
#pragma unroll
    for (int ks = 0; ks < 2; ks++) {
      const size_t off = ((size_t)h * 128 + nb) * 64 + ks * 32 + kgrp * 8;
      short8 b_hi = *(const short8*)&kc_hi[off];
      short8 b_lo = *(const short8*)&kc_lo[off];
      acc[ni] = __builtin_amdgcn_mfma_f32_16x16x32_bf16(a_hi[ks], b_hi, acc[ni], 0, 0, 0);
      acc[ni] = __builtin_amdgcn_mfma_f32_16x16x32_bf16(a_lo[ks], b_hi, acc[ni], 0, 0, 0);
      acc[ni] = __builtin_amdgcn_mfma_f32_16x16x32_bf16(a_hi[ks], b_lo, acc[ni], 0, 0, 0);
    }
  }
#pragma unroll
  for (int ni = 0; ni < 2; ni++) {
    const int n = w * 32 + ni * 16 + mrow;
#pragma unroll
    for (int r = 0; r < 4; r++) {
      const int row = kgrp * 4 + r;
      const int count = (t0 + row) >> 4;
      S_s[row][n] = (n < count) ? acc[ni][r] * 0.125f : NEGC;
    }
  }
  __syncthreads();

  for (int qq = 0; qq < 4; qq++) {
    const int row = w * 4 + qq, t = t0 + row, count = t >> 4;
    const float2 sv = *(const float2*)&S_s[row][2 * lane];
    const float s0 = sv.x, s1 = sv.y;
    const float M = wred_max(fmaxf(s0, s1));
    const float e0 = __expf(s0 - M), e1 = __expf(s1 - M);
    const float inv = 1.f / wred_sum(e0 + e1);
    ushort2 pv;
    pv.x = (count == 0) ? (unsigned short)0 : f32_to_bf16(e0 * inv);
    pv.y = (count == 0) ? (unsigned short)0 : f32_to_bf16(e1 * inv);
    *(ushort2*)&P[(((size_t)h << 11) + t) * 128 + 2 * lane] = pv;

    float c0 = s0, c1 = s1;
    int sel0 = 0, sel1 = 0, sel2 = 0, sel3 = 0;
#pragma unroll
    for (int j = 0; j < 4; j++) {
      float bv; int bi;
      if (c0 >= c1) { bv = c0; bi = 2 * lane; } else { bv = c1; bi = 2 * lane + 1; }
#pragma unroll
      for (int o = 32; o > 0; o >>= 1) {
        const float ov = __shfl_xor(bv, o, 64);
        const int oi = __shfl_xor(bi, o, 64);
        if (ov > bv || (ov == bv && oi < bi)) { bv = ov; bi = oi; }
      }
      if (j == 0) sel0 = bi; else if (j == 1) sel1 = bi;
      else if (j == 2) sel2 = bi; else sel3 = bi;
      if (bi == 2 * lane) c0 = -FLT_MAX;
      if (bi == 2 * lane + 1) c1 = -FLT_MAX;
    }
    if (lane == 0) sel[((size_t)h << 11) + t] = make_int4(sel0, sel1, sel2, sel3);
  }
}

// ---------------- out_c = P @ vc : MFMA, fragment-direct, no LDS ----------------
__global__ __launch_bounds__(256) void outc_k(const unsigned short* __restrict__ P,
                                              const unsigned short* __restrict__ vcT,
                                              float* __restrict__ oc) {
  const int h = blockIdx.x >> 4, t0 = (blockIdx.x & 15) * 128;
  const int tid = threadIdx.x, w = tid >> 6, lane = tid & 63;
  const int mrow = lane & 15, kgrp = lane >> 4;
  floatx4 zero = {0.f, 0.f, 0.f, 0.f};
  floatx4 acc[2][4];
#pragma unroll
  for (int mi = 0; mi < 2; mi++)
#pragma unroll
    for (int ni = 0; ni < 4; ni++) acc[mi][ni] = zero;

#pragma unroll
  for (int ks = 0; ks < 4; ks++) {
    short8 a[2];
#pragma unroll
    for (int mi = 0; mi < 2; mi++) {
      const int t = t0 + w * 32 + mi * 16 + mrow;
      a[mi] = *(const short8*)&P[(((size_t)h << 11) + t) * 128 + ks * 32 + kgrp * 8];
    }
#pragma unroll
    for (int ni = 0; ni < 4; ni++) {
      const int d = ni * 16 + mrow;
      short8 b = *(const short8*)&vcT[((size_t)h * 64 + d) * 128 + ks * 32 + kgrp * 8];
      acc[0][ni] = __builtin_amdgcn_mfma_f32_16x16x32_bf16(a[0], b, acc[0][ni], 0, 0, 0);
      acc[1][ni] = __builtin_amdgcn_mfma_f32_16x16x32_bf16(a[1], b, acc[1][ni], 0, 0, 0);
    }
  }
#pragma unroll
  for (int mi = 0; mi < 2; mi++)
#pragma unroll
    for (int ni = 0; ni < 4; ni++)
#pragma unroll
      for (int r = 0; r < 4; r++)
        oc[(size_t)(t0 + w * 32 + mi * 16 + kgrp * 4 + r) * 1024 + h * 64 + ni * 16 + mrow] =
            acc[mi][ni][r];
}

// ---------------- selected + window branches + gated combine ----------------
__global__ __launch_bounds__(256) void nsa_swl(
    const unsigned short* __restrict__ qhf, const unsigned short* __restrict__ khfT,
    const unsigned short* __restrict__ vhf, const int4* __restrict__ sel,
    const float* __restrict__ oc, const float* __restrict__ gates,
    unsigned short* __restrict__ outf) {
  __shared__ float ps[4][64];
  const int bid = blockIdx.x;
  const int h = ((bid & 7) << 1) | ((bid >> 3) & 1);
  const int w = threadIdx.x >> 6, lane = threadIdx.x & 63;
  const int t = (bid >> 4) * 4 + w;

  const unsigned short* kT = khfT + (size_t)h * 131072;
  const unsigned short* vhh = vhf + (size_t)h * 131072;

  uint4 qr[8];
  {
    const uint4* qp = (const uint4*)(qhf + (size_t)t * 1024 + h * 64);
#pragma unroll
    for (int j = 0; j < 8; j++) qr[j] = qp[j];
  }
  const int4 s4 = sel[((size_t)h << 11) + t];

  const int g16 = lane >> 4;
  const int blk = (g16 == 0) ? s4.x : (g16 == 1) ? s4.y : (g16 == 2) ? s4.z : s4.w;
  const int tok = blk * 16 + (lane & 15);
  {
    float a0 = 0.f, a1 = 0.f, a2 = 0.f, a3 = 0.f;
#pragma unroll
    for (int dc = 0; dc < 8; dc++) {
      const uint4 kk = *(const uint4*)(kT + ((size_t)dc * 2048 + tok) * 8);
      a0 = fdot2u(kk.x, qr[dc].x, a0);
      a1 = fdot2u(kk.y, qr[dc].y, a1);
      a2 = fdot2u(kk.z, qr[dc].z, a2);
      a3 = fdot2u(kk.w, qr[dc].w, a3);
    }
    const float sv_ = (tok <= t) ? ((a0 + a1) + (a2 + a3)) * 0.125f : NEGC;
    const float Ms = wred_max(sv_);
    const float es = __expf(sv_ - Ms);
    ps[w][lane] = es * (1.f / wred_sum(es));
  }

  const int dd = lane & 31, s = lane >> 5;
  const float4* ps4 = (const float4*)ps[w];

  float osx = 0.f, osy = 0.f;
#pragma unroll
  for (int jc = 0; jc < 8; jc++) {
    const float4 p4 = ps4[s * 8 + jc];
    const float pa[4] = {p4.x, p4.y, p4.z, p4.w};
#pragma unroll
    for (int u = 0; u < 4; u++) {
      const int idx = s * 32 + jc * 4 + u;
      const int jb = idx >> 4;
      const int b2 = (jb == 0) ? s4.x : (jb == 1) ? s4.y : (jb == 2) ? s4.z : s4.w;
      const int tok2 = b2 * 16 + (idx & 15);
      const unsigned int vv = *(const unsigned int*)(vhh + (size_t)tok2 * 64 + 2 * dd);
      const h2 v2 = __builtin_bit_cast(h2, vv);
      osx += pa[u] * (float)v2[0];
      osy += pa[u] * (float)v2[1];
    }
  }
  osx += __shfl_xor(osx, 32, 64);
  osy += __shfl_xor(osy, 32, 64);

  {
    const int tw = t - 32 + lane;
    const int twc = min(max(tw, 0), T_LEN - 1);
    float a0 = 0.f, a1 = 0.f, a2 = 0.f, a3 = 0.f;
#pragma unroll
    for (int dc = 0; dc < 8; dc++) {
      const uint4 kk = *(const uint4*)(kT + ((size_t)dc * 2048 + twc) * 8);
      a0 = fdot2u(kk.x, qr[dc].x, a0);
      a1 = fdot2u(kk.y, qr[dc].y, a1);
      a2 = fdot2u(kk.z, qr[dc].z, a2);
      a3 = fdot2u(kk.w, qr[dc].w, a3);
    }
    const float swv = (tw >= 0 && lane <= 32) ? ((a0 + a1) + (a2 + a3)) * 0.125f : NEGC;
    const float Mw = wred_max(swv);
    const float ew = __expf(swv - Mw);
    ps[w][lane] = ew * (1.f / wred_sum(ew));
  }

  float olx = 0.f, oly = 0.f;
#pragma unroll
  for (int j = 0; j < 17; j++) {
    const int idx = s * 17 + j;
    const int idc = min(idx, 32);
    const float p = (idx <= 32) ? ps[w][idc] : 0.f;
    const int tk = min(max(t - 32 + idx, 0), T_LEN - 1);
    const unsigned int vv = *(const unsigned int*)(vhh + (size_t)tk * 64 + 2 * dd);
    const h2 v2 = __builtin_bit_cast(h2, vv);
    olx += p * (float)v2[0];
    oly += p * (float)v2[1];
  }
  olx += __shfl_xor(olx, 32, 64);
  oly += __shfl_xor(oly, 32, 64);

  if (lane < 32) {
    const float2 ocv = *(const float2*)&oc[(size_t)t * 1024 + h * 64 + 2 * dd];
    const float g0 = gates[t * 3 + 0], g1 = gates[t * 3 + 1], g2 = gates[t * 3 + 2];
    const float r0 = g0 * ocv.x + g1 * osx + g2 * olx;
    const float r1 = g0 * ocv.y + g1 * osy + g2 * oly;
    const unsigned int pk = (unsigned int)f32_to_bf16(r0) | ((unsigned int)f32_to_bf16(r1) << 16);
    *(unsigned int*)&outf[(size_t)t * DM + h * 64 + 2 * dd] = pk;
  }
}

// ---------------- launch ----------------
extern "C" void kernel_launch(void* const* d_in, const int* in_sizes, int n_in,
                              void* d_out, int out_size, void* d_ws, size_t ws_size,
                              hipStream_t stream) {
  const float* x   = (const float*)d_in[0];
  const float* Wq  = (const float*)d_in[1];
  const float* Wk  = (const float*)d_in[2];
  const float* Wv  = (const float*)d_in[3];
  const float* Wo  = (const float*)d_in[4];
  const float* Wck = (const float*)d_in[5];
  const float* Wcv = (const float*)d_in[6];
  const float* Wg  = (const float*)d_in[7];
  const float* bg  = (const float*)d_in[8];
  float* out = (float*)d_out;

  float* ws = (float*)d_ws;
  // region A [0,24 MB): C until compress_mfma; then P/oc/outf
  float*          C    = ws;
  unsigned short* P    = (unsigned short*)ws;               // [0,8 MB)
  float*          oc   = ws + 2097152;                      // [8,16 MB)
  unsigned short* outf = (unsigned short*)(ws + 4194304);   // [16,20 MB)
  // region B [24,36 MB): Axf (4 MB) until qkv GEMM; then qh + smalls
  unsigned short* Axf   = (unsigned short*)(ws + 6291456);
  float*          qh    = ws + 6291456;                     // [24,32 MB)
  unsigned short* Wot   = (unsigned short*)(ws + 8388608);  // [32,34 MB)
  unsigned short* kc_hi = (unsigned short*)(ws + 8912896);
  unsigned short* kc_lo = (unsigned short*)(ws + 8978432);
  unsigned short* vcT   = (unsigned short*)(ws + 9043968);
  int4*           sel   = (int4*)(ws + 9109504);
  unsigned short* WckT_hi = (unsigned short*)(ws + 9240576);
  unsigned short* WckT_lo = (unsigned short*)(ws + 9273344);
  unsigned short* WcvT_hi = (unsigned short*)(ws + 9306112);
  unsigned short* WcvT_lo = (unsigned short*)(ws + 9338880);
  float*          gates   = ws + 9371648;
  // region C [36,48 MB): Bqkv f16 (6 MB) until qkv GEMM; then qhf/khfT/vhf f16
  unsigned short* Bqkv = (unsigned short*)(ws + 9437184);   // 3072x1024 f16, 6 MB
  unsigned short* qhf  = (unsigned short*)(ws + 9437184);   // [36,40 MB)
  unsigned short* khfT = (unsigned short*)(ws + 10485760);  // [40,44 MB)
  unsigned short* vhf  = (unsigned short*)(ws + 11534336);  // [44,48 MB)

  // 1. operand preparation (f16 single-pass QKV operands)
  cast_x_k<<<2048, 256, 0, stream>>>(x, Axf);
  cast_wqkv<<<dim3(32, 32, 3), dim3(32, 8), 0, stream>>>(Wq, Wk, Wv, Bqkv);

  // 2. merged q|k|v GEMM: K=1024 f16, grid (24,32) round-0 mapping
  qkv_gemm<<<dim3(24, 32), 256, 0, stream>>>(Axf, Bqkv, C);

  // 3. reorg + gates (C stays alive for compress); late weight casts
  reorg_qkv<<<6144, 256, 0, stream>>>(C, qh, qhf, khfT, vhf);
  gates_k<<<512, 256, 0, stream>>>(C, Wg, bg, gates);
  cast_wt1<<<dim3(32, 32), dim3(32, 8), 0, stream>>>(Wo, Wot);
  cast_wct<<<dim3(2, 32, 2), dim3(32, 8), 0, stream>>>(Wck, Wcv, WckT_hi, WckT_lo, WcvT_hi, WcvT_lo);

  // 4. compression (MFMA, reads C) + compressed-branch pipeline (C dead after)
  compress_mfma<<<dim3(128, 2), 512, 0, stream>>>(C, WckT_hi, WckT_lo, WcvT_hi, WcvT_lo,
                                                  kc_hi, kc_lo, vcT);
  cscore_k<<<2048, 256, 0, stream>>>(qh, kc_hi, kc_lo, P, sel);
  outc_k<<<256, 256, 0, stream>>>(P, vcT, oc);

  // 5. selected + window + gated combine
  nsa_swl<<<8192, 256, 0, stream>>>(qhf, khfT, vhf, sel, oc, gates, outf);

  // 6. output projection (64x128 tiles, grid (8,32))
  gemm_bt64<<<dim3(8, 32), 256, 0, stream>>>(outf, Wot, out, 1024, 1024, 1024);
}

// Round 5
// 256.470 us; speedup vs baseline: 1.3537x; 1.0236x over previous
//
#include <hip/hip_runtime.h>
#include <hip/hip_bf16.h>
#include <float.h>

#define T_LEN 2048
#define DM    1024
#define NB    128
#define NEGC  (-1e9f)

typedef __attribute__((ext_vector_type(8))) short short8;
typedef __attribute__((ext_vector_type(4))) float floatx4;
typedef _Float16 h2 __attribute__((ext_vector_type(2)));
typedef _Float16 h8 __attribute__((ext_vector_type(8)));

// ---------------- helpers ----------------
__device__ __forceinline__ float wred_max(float v) {
#pragma unroll
  for (int o = 32; o > 0; o >>= 1) v = fmaxf(v, __shfl_xor(v, o, 64));
  return v;
}
__device__ __forceinline__ float wred_sum(float v) {
#pragma unroll
  for (int o = 32; o > 0; o >>= 1) v += __shfl_xor(v, o, 64);
  return v;
}
__device__ __forceinline__ unsigned short f32_to_bf16(float f) {
  unsigned int b = __float_as_uint(f);
  return (unsigned short)((b + 0x7fffu + ((b >> 16) & 1u)) >> 16);
}
__device__ __forceinline__ float bf16_to_f32(unsigned short u) {
  return __uint_as_float(((unsigned int)u) << 16);
}
__device__ __forceinline__ unsigned int pack_h2(float a, float b) {
  h2 r; r[0] = (_Float16)a; r[1] = (_Float16)b;
  return __builtin_bit_cast(unsigned int, r);
}
__device__ __forceinline__ float fdot2u(unsigned int a, unsigned int b, float c) {
#if __has_builtin(__builtin_amdgcn_fdot2)
  return __builtin_amdgcn_fdot2(__builtin_bit_cast(h2, a), __builtin_bit_cast(h2, b), c, false);
#else
  const h2 av = __builtin_bit_cast(h2, a), bv = __builtin_bit_cast(h2, b);
  return c + (float)av[0] * (float)bv[0] + (float)av[1] * (float)bv[1];
#endif
}
__device__ __forceinline__ void lds_async16(unsigned short* l, const unsigned short* g) {
  __builtin_amdgcn_global_load_lds(
      (const __attribute__((address_space(1))) unsigned int*)g,
      (__attribute__((address_space(3))) unsigned int*)l, 16, 0, 0);
}

// =========== 64x128-tile MFMA GEMM core — 2-phase counted-vmcnt pipeline ====
// 256 thr = 4 waves. BK=32, double-buffered LDS. THE fix for the ~1 us/step
// latency floor seen r0-r4: r1's __syncthreads dbuf drained vmcnt(0) at every
// barrier (prefetch completed AT the barrier -> zero overlap). Here: raw
// s_barrier + counted vmcnt(3) -> the 3 prefetch loads for tile t+1 stay IN
// FLIGHT across the barrier while tile t computes (catalog T3/T4 minimum
// 2-phase recipe). Each wave issues exactly 3 global_load_lds per stage, no
// other vmem in the loop, so vmcnt(3) == "my previous tile landed"; barrier
// joins all waves' guarantees. Closing barrier keeps stage(t+2) from
// overwriting buf while others still read it; "memory" clobbers fence
// compiler motion of LDS/global ops across the waits.
template <bool F16>
__device__ __forceinline__ void gemm64_core(
    const unsigned short* __restrict__ A, const unsigned short* __restrict__ Bt,
    float* __restrict__ C, int K, int lda, int row0, int bcol0, int ccol0, int ldc,
    unsigned short* As, unsigned short* Bs) {
  const int tid = threadIdx.x;
  const int w = tid >> 6, lane = tid & 63;
  const int wr = w >> 1, wc = w & 1;
  const int mrow = lane & 15, kgrp = lane >> 4;

  const int sr = (w << 4) + mrow;          // staged row 0..63
  const int sc = kgrp;                     // staged chunk 0..3

  floatx4 zero = {0.f, 0.f, 0.f, 0.f};
  floatx4 acc[2][4];
#pragma unroll
  for (int i = 0; i < 2; i++)
#pragma unroll
    for (int j = 0; j < 4; j++) acc[i][j] = zero;

  const int nt = K >> 5;
  const unsigned short* Ap  = A  + (size_t)(row0 + sr) * lda + sc * 8;
  const unsigned short* Bp0 = Bt + (size_t)(bcol0 + sr) * K + sc * 8;
  const unsigned short* Bp1 = Bt + (size_t)(bcol0 + 64 + sr) * K + sc * 8;

  auto stage = [&](int t, int b) {
    lds_async16(&As[b * 2048 + w * 512], Ap + t * 32);
    lds_async16(&Bs[b * 4096 + w * 512], Bp0 + t * 32);
    lds_async16(&Bs[b * 4096 + 2048 + w * 512], Bp1 + t * 32);
  };

  stage(0, 0);
  int cur = 0;
  for (int t = 0; t < nt; t++) {
    if (t + 1 < nt) {
      stage(t + 1, cur ^ 1);                              // outstanding: 6
      asm volatile("s_waitcnt vmcnt(3)" ::: "memory");    // buf[t] landed; t+1 in flight
    } else {
      asm volatile("s_waitcnt vmcnt(0)" ::: "memory");    // final tile: drain
    }
    __builtin_amdgcn_s_barrier();
    const unsigned short* as = As + cur * 2048;
    const unsigned short* bs = Bs + cur * 4096;
    short8 af[2], bf4[4];
#pragma unroll
    for (int mi = 0; mi < 2; mi++)
      af[mi] = *(const short8*)&as[(wr * 2 + mi) * 512 + kgrp * 128 + mrow * 8];
#pragma unroll
    for (int ni = 0; ni < 4; ni++)
      bf4[ni] = *(const short8*)&bs[(wc * 4 + ni) * 512 + kgrp * 128 + mrow * 8];
#pragma unroll
    for (int mi = 0; mi < 2; mi++)
#pragma unroll
      for (int ni = 0; ni < 4; ni++) {
        if constexpr (F16)
          acc[mi][ni] = __builtin_amdgcn_mfma_f32_16x16x32_f16(
              __builtin_bit_cast(h8, af[mi]), __builtin_bit_cast(h8, bf4[ni]),
              acc[mi][ni], 0, 0, 0);
        else
          acc[mi][ni] = __builtin_amdgcn_mfma_f32_16x16x32_bf16(af[mi], bf4[ni],
                                                                acc[mi][ni], 0, 0, 0);
      }
    asm volatile("" ::: "memory");
    __builtin_amdgcn_s_barrier();       // all reads of buf[cur] done before overwrite
    cur ^= 1;
  }
#pragma unroll
  for (int mi = 0; mi < 2; mi++)
#pragma unroll
    for (int ni = 0; ni < 4; ni++) {
      float* Cp = C + (size_t)(row0 + wr * 32 + mi * 16 + kgrp * 4) * ldc
                    + ccol0 + wc * 64 + ni * 16 + mrow;
      Cp[0] = acc[mi][ni][0];
      Cp[(size_t)ldc] = acc[mi][ni][1];
      Cp[(size_t)2 * ldc] = acc[mi][ni][2];
      Cp[(size_t)3 * ldc] = acc[mi][ni][3];
    }
}

// merged q|k|v GEMM: grid (24, 32), f16 single pass K=1024 (r4 win).
// Bqkv rows 0..1023 = Wq^T, 1024..2047 = Wk^T, 2048..3071 = Wv^T.
__global__ __launch_bounds__(256) void qkv_gemm(const unsigned short* __restrict__ Axf,
                                                const unsigned short* __restrict__ Bqkv,
                                                float* __restrict__ C) {
  __shared__ __align__(16) unsigned short As[2 * 64 * 32];
  __shared__ __align__(16) unsigned short Bs[2 * 128 * 32];
  gemm64_core<true>(Axf, Bqkv, C, 1024, 1024, blockIdx.y * 64,
                    blockIdx.x * 128, blockIdx.x * 128, 3072, As, Bs);
}

// final output projection (bf16 inputs)
__global__ __launch_bounds__(256) void gemm_bt64(const unsigned short* __restrict__ A,
                                                 const unsigned short* __restrict__ Bt,
                                                 float* __restrict__ C,
                                                 int K, int lda, int ldc) {
  __shared__ __align__(16) unsigned short As[2 * 64 * 32];
  __shared__ __align__(16) unsigned short Bs[2 * 128 * 32];
  gemm64_core<false>(A, Bt, C, K, lda, blockIdx.y * 64,
                     blockIdx.x * 128, blockIdx.x * 128, ldc, As, Bs);
}

// ---------------- cast x -> f16 (2048 x 1024) ----------------
__global__ __launch_bounds__(256) void cast_x_k(const float* __restrict__ x,
                                                unsigned short* __restrict__ Axf) {
  const int gid = blockIdx.x * 256 + threadIdx.x;
  float4 xv = ((const float4*)x)[gid];
  const unsigned int p0 = pack_h2(xv.x, xv.y);
  const unsigned int p1 = pack_h2(xv.z, xv.w);
  *(uint2*)&Axf[(size_t)gid * 4] = make_uint2(p0, p1);
}

// ---- transpose-cast Wq/Wk/Wv (by blockIdx.z) into Bqkv f16 (3072n x 1024k) ----
__global__ void cast_wqkv(const float* __restrict__ Wq, const float* __restrict__ Wk,
                          const float* __restrict__ Wv, unsigned short* __restrict__ Bt) {
  __shared__ float tile[32][33];
  const float* W = (blockIdx.z == 0) ? Wq : (blockIdx.z == 1) ? Wk : Wv;
  const int n0 = blockIdx.z * 1024;
  const int kt0 = blockIdx.y * 32, nt0 = blockIdx.x * 32;
  const int tx = threadIdx.x, ty = threadIdx.y;
#pragma unroll
  for (int i = 0; i < 32; i += 8)
    tile[ty + i][tx] = W[(size_t)(kt0 + ty + i) * 1024 + nt0 + tx];
  __syncthreads();
#pragma unroll
  for (int i = 0; i < 32; i += 8) {
    const int n = nt0 + ty + i, kk = kt0 + tx;
    h2 r; r[0] = (_Float16)tile[tx][ty + i]; r[1] = (_Float16)0.f;
    Bt[(size_t)(n0 + n) * 1024 + kk] = (unsigned short)(__builtin_bit_cast(unsigned int, r) & 0xffffu);
  }
}

// ---- transpose-cast 1024x1024 W -> Bt (1024n x 1024k) bf16 ----
__global__ void cast_wt1(const float* __restrict__ W, unsigned short* __restrict__ Bt) {
  __shared__ float tile[32][33];
  const int kt0 = blockIdx.y * 32, nt0 = blockIdx.x * 32;
  const int tx = threadIdx.x, ty = threadIdx.y;
#pragma unroll
  for (int i = 0; i < 32; i += 8)
    tile[ty + i][tx] = W[(size_t)(kt0 + ty + i) * 1024 + nt0 + tx];
  __syncthreads();
#pragma unroll
  for (int i = 0; i < 32; i += 8) {
    const int n = nt0 + ty + i, kk = kt0 + tx;
    Bt[(size_t)n * 1024 + kk] = f32_to_bf16(tile[tx][ty + i]);
  }
}

// ---- transpose-cast Wck/Wcv (1024x64) -> (64,1024) hi/lo bf16 ----
__global__ void cast_wct(const float* __restrict__ Wck, const float* __restrict__ Wcv,
                         unsigned short* __restrict__ KT_hi, unsigned short* __restrict__ KT_lo,
                         unsigned short* __restrict__ VT_hi, unsigned short* __restrict__ VT_lo) {
  __shared__ float tile[32][33];
  const float* W = blockIdx.z ? Wcv : Wck;
  unsigned short* Bh = blockIdx.z ? VT_hi : KT_hi;
  unsigned short* Bl = blockIdx.z ? VT_lo : KT_lo;
  const int kt0 = blockIdx.y * 32, nt0 = blockIdx.x * 32;
  const int tx = threadIdx.x, ty = threadIdx.y;
#pragma unroll
  for (int i = 0; i < 32; i += 8)
    tile[ty + i][tx] = W[(size_t)(kt0 + ty + i) * 64 + nt0 + tx];
  __syncthreads();
#pragma unroll
  for (int i = 0; i < 32; i += 8) {
    const int n = nt0 + ty + i, kk = kt0 + tx;
    const float f = tile[tx][ty + i];
    const unsigned short hb = f32_to_bf16(f);
    Bh[(size_t)n * 1024 + kk] = hb;
    Bl[(size_t)n * 1024 + kk] = f32_to_bf16(f - bf16_to_f32(hb));
  }
}

// ---------------- reorg: C(t,3072) -> qh f32, qhf f16 (T,1024),
//                  khfT f16 (H, 8, T, 8), vhf f16 (H, T, 64) ----------------
__global__ __launch_bounds__(256) void reorg_qkv(const float* __restrict__ C,
                                                 float* __restrict__ qh,
                                                 unsigned short* __restrict__ qhf,
                                                 unsigned short* __restrict__ khfT,
                                                 unsigned short* __restrict__ vhf) {
  const int gid = blockIdx.x * 256 + threadIdx.x;
  const int t = gid / 768;
  const int c = (gid - t * 768) * 4;
  float4 val = *(const float4*)&C[(size_t)t * 3072 + c];
  const unsigned int p0 = pack_h2(val.x, val.y);
  const unsigned int p1 = pack_h2(val.z, val.w);
  if (c < 1024) {
    *(float4*)&qh[(size_t)t * 1024 + c] = val;
    *(uint2*)&qhf[(size_t)t * 1024 + c] = make_uint2(p0, p1);
  } else if (c < 2048) {
    const int h = (c >> 6) & 15, d = c & 63;
    const int dc = d >> 3, j = d & 7;
    *(uint2*)&khfT[((size_t)(h * 8 + dc) * 2048 + t) * 8 + j] = make_uint2(p0, p1);
  } else {
    const int h = (c >> 6) & 15, d = c & 63;
    *(uint2*)&vhf[((size_t)h * 2048 + t) * 64 + d] = make_uint2(p0, p1);
  }
}

// ---------------- compress via MFMA (reads k/v straight from C) ----------------
__global__ __launch_bounds__(512) void compress_mfma(
    const float* __restrict__ C,
    const unsigned short* __restrict__ KT_hi, const unsigned short* __restrict__ KT_lo,
    const unsigned short* __restrict__ VT_hi, const unsigned short* __restrict__ VT_lo,
    unsigned short* __restrict__ kc_hi, unsigned short* __restrict__ kc_lo,
    unsigned short* __restrict__ vcT) {
  __shared__ float red[8][64][17];
  const int isv = blockIdx.y;
  const unsigned short* Bh = isv ? VT_hi : KT_hi;
  const unsigned short* Bl = isv ? VT_lo : KT_lo;
  const int tid = threadIdx.x, w = tid >> 6, lane = tid & 63;
  const int mrow = lane & 15, kgrp = lane >> 4;
  const int m0 = blockIdx.x * 16;
  const int m = m0 + mrow;
  const int hh = m >> 7, nb = m & 127;
  const int cbase = 1024 + isv * 1024 + hh * 64;

  floatx4 zero = {0.f, 0.f, 0.f, 0.f};
  floatx4 acc[4] = {zero, zero, zero, zero};

  const int kbeg = w << 7;                  // per-wave K chunk of 128
  for (int k0 = kbeg; k0 < kbeg + 128; k0 += 32) {
    const int c = k0 + kgrp * 8;
    const float* ap = &C[(size_t)(nb * 16 + (c >> 6)) * 3072 + cbase + (c & 63)];
    float4 q0 = *(const float4*)ap;
    float4 q1 = *(const float4*)(ap + 4);
    float qq[8] = {q0.x, q0.y, q0.z, q0.w, q1.x, q1.y, q1.z, q1.w};
    short8 a_hi, a_lo;
#pragma unroll
    for (int j = 0; j < 8; j++) {
      unsigned short hb = f32_to_bf16(qq[j]);
      a_hi[j] = (short)hb;
      a_lo[j] = (short)f32_to_bf16(qq[j] - bf16_to_f32(hb));
    }
#pragma unroll
    for (int ni = 0; ni < 4; ni++) {
      const size_t boff = (size_t)(ni * 16 + mrow) * 1024 + k0 + kgrp * 8;
      short8 b_hi = *(const short8*)&Bh[boff];
      short8 b_lo = *(const short8*)&Bl[boff];
      acc[ni] = __builtin_amdgcn_mfma_f32_16x16x32_bf16(a_hi, b_hi, acc[ni], 0, 0, 0);
      acc[ni] = __builtin_amdgcn_mfma_f32_16x16x32_bf16(a_lo, b_hi, acc[ni], 0, 0, 0);
      acc[ni] = __builtin_amdgcn_mfma_f32_16x16x32_bf16(a_hi, b_lo, acc[ni], 0, 0, 0);
    }
  }

  // cross-wave K reduction through LDS (pad 17 -> conflict-free)
#pragma unroll
  for (int ni = 0; ni < 4; ni++)
#pragma unroll
    for (int r = 0; r < 4; r++) red[w][lane][ni * 4 + r] = acc[ni][r];
  __syncthreads();

  if (w < 4) {                              // wave w stores d-columns w*16..w*16+15
#pragma unroll
    for (int r = 0; r < 4; r++) {
      const int j = w * 4 + r;
      float val = 0.f;
#pragma unroll
      for (int ww = 0; ww < 8; ww++) val += red[ww][lane][j];
      const int mo = m0 + kgrp * 4 + r;
      const int d = w * 16 + mrow;
      if (!isv) {
        const unsigned short hb = f32_to_bf16(val);
        kc_hi[(size_t)mo * 64 + d] = hb;
        kc_lo[(size_t)mo * 64 + d] = f32_to_bf16(val - bf16_to_f32(hb));
      } else {
        vcT[(size_t)(mo >> 7) * 8192 + (size_t)d * 128 + (mo & 127)] = f32_to_bf16(val);
      }
    }
  }
}

// ---------------- gates ----------------
__global__ __launch_bounds__(256) void gates_k(const float* __restrict__ C,
                                               const float* __restrict__ Wg,
                                               const float* __restrict__ bg,
                                               float* __restrict__ gates) {
  const int w = threadIdx.x >> 6, lane = threadIdx.x & 63;
  const int t = blockIdx.x * 4 + w;
  float m = 0.f;
#pragma unroll
  for (int h = 0; h < 16; h++) m += C[(size_t)t * 3072 + h * 64 + lane];
  m *= (1.f / 16.f);
  float g0 = wred_sum(m * Wg[lane * 3 + 0]);
  float g1 = wred_sum(m * Wg[lane * 3 + 1]);
  float g2 = wred_sum(m * Wg[lane * 3 + 2]);
  if (lane == 0) {
    g0 += bg[0]; g1 += bg[1]; g2 += bg[2];
    float mx = fmaxf(g0, fmaxf(g1, g2));
    float e0 = __expf(g0 - mx), e1 = __expf(g1 - mx), e2 = __expf(g2 - mx);
    float inv = 1.f / (e0 + e1 + e2);
    gates[t * 3 + 0] = e0 * inv;
    gates[t * 3 + 1] = e1 * inv;
    gates[t * 3 + 2] = e2 * inv;
  }
}

// ------- cscore: MFMA scores + softmax + top-4 + FUSED PV (was outc_k) -------
// After softmax, normalized probs live in S_s (LDS); PV = P(16x128)@vc(128x64)
// via 4 MFMA per wave (wave w owns d-tile w*16..w*16+15), B-fragments straight
// from vcT [h][d][nb]. Kills the P bf16 global round-trip (16 MB) + one launch.
__global__ __launch_bounds__(256) void cscore_k(
    const float* __restrict__ qh, const unsigned short* __restrict__ kc_hi,
    const unsigned short* __restrict__ kc_lo, const unsigned short* __restrict__ vcT,
    float* __restrict__ oc, int4* __restrict__ sel) {
  __shared__ float S_s[16][132];
  const int h = blockIdx.x >> 7, t0 = (blockIdx.x & 127) * 16;
  const int tid = threadIdx.x, w = tid >> 6, lane = tid & 63;
  const int mrow = lane & 15, kgrp = lane >> 4;

  short8 a_hi[2], a_lo[2];
#pragma unroll
  for (int ks = 0; ks < 2; ks++) {
    const float* qp = &qh[(size_t)(t0 + mrow) * 1024 + h * 64 + ks * 32 + kgrp * 8];
    float4 q0 = *(const float4*)qp;
    float4 q1 = *(const float4*)(qp + 4);
    float qq[8] = {q0.x, q0.y, q0.z, q0.w, q1.x, q1.y, q1.z, q1.w};
#pragma unroll
    for (int j = 0; j < 8; j++) {
      unsigned short hb = f32_to_bf16(qq[j]);
      a_hi[ks][j] = (short)hb;
      a_lo[ks][j] = (short)f32_to_bf16(qq[j] - bf16_to_f32(hb));
    }
  }
  floatx4 zero = {0.f, 0.f, 0.f, 0.f};
  floatx4 acc[2] = {zero, zero};
#pragma unroll
  for (int ni = 0; ni < 2; ni++) {
    const int nb = w * 32 + ni * 16 + mrow;
#pragma unroll
    for (int ks = 0; ks < 2; ks++) {
      const size_t off = ((size_t)h * 128 + nb) * 64 + ks * 32 + kgrp * 8;
      short8 b_hi = *(const short8*)&kc_hi[off];
      short8 b_lo = *(const short8*)&kc_lo[off];
      acc[ni] = __builtin_amdgcn_mfma_f32_16x16x32_bf16(a_hi[ks], b_hi, acc[ni], 0, 0, 0);
      acc[ni] = __builtin_amdgcn_mfma_f32_16x16x32_bf16(a_lo[ks], b_hi, acc[ni], 0, 0, 0);
      acc[ni] = __builtin_amdgcn_mfma_f32_16x16x32_bf16(a_hi[ks], b_lo, acc[ni], 0, 0, 0);
    }
  }
#pragma unroll
  for (int ni = 0; ni < 2; ni++) {
    const int n = w * 32 + ni * 16 + mrow;
#pragma unroll
    for (int r = 0; r < 4; r++) {
      const int row = kgrp * 4 + r;
      const int count = (t0 + row) >> 4;
      S_s[row][n] = (n < count) ? acc[ni][r] * 0.125f : NEGC;
    }
  }
  __syncthreads();

  for (int qq = 0; qq < 4; qq++) {
    const int row = w * 4 + qq, t = t0 + row, count = t >> 4;
    const float2 sv = *(const float2*)&S_s[row][2 * lane];
    const float s0 = sv.x, s1 = sv.y;
    const float M = wred_max(fmaxf(s0, s1));
    const float e0 = __expf(s0 - M), e1 = __expf(s1 - M);
    const float inv = 1.f / wred_sum(e0 + e1);
    // write normalized probs back to S_s (0 if no valid block) for fused PV
    S_s[row][2 * lane]     = (count == 0) ? 0.f : e0 * inv;
    S_s[row][2 * lane + 1] = (count == 0) ? 0.f : e1 * inv;

    float c0 = s0, c1 = s1;
    int sel0 = 0, sel1 = 0, sel2 = 0, sel3 = 0;
#pragma unroll
    for (int j = 0; j < 4; j++) {
      float bv; int bi;
      if (c0 >= c1) { bv = c0; bi = 2 * lane; } else { bv = c1; bi = 2 * lane + 1; }
#pragma unroll
      for (int o = 32; o > 0; o >>= 1) {
        const float ov = __shfl_xor(bv, o, 64);
        const int oi = __shfl_xor(bi, o, 64);
        if (ov > bv || (ov == bv && oi < bi)) { bv = ov; bi = oi; }
      }
      if (j == 0) sel0 = bi; else if (j == 1) sel1 = bi;
      else if (j == 2) sel2 = bi; else sel3 = bi;
      if (bi == 2 * lane) c0 = -FLT_MAX;
      if (bi == 2 * lane + 1) c1 = -FLT_MAX;
    }
    if (lane == 0) sel[((size_t)h << 11) + t] = make_int4(sel0, sel1, sel2, sel3);
  }
  __syncthreads();

  // fused PV: wave w -> d-tile [w*16, w*16+16)
  const int d = w * 16 + mrow;
  floatx4 accp = zero;
#pragma unroll
  for (int ks = 0; ks < 4; ks++) {
    const float4 p0 = *(const float4*)&S_s[mrow][ks * 32 + kgrp * 8];
    const float4 p1 = *(const float4*)&S_s[mrow][ks * 32 + kgrp * 8 + 4];
    short8 a;
    a[0] = (short)f32_to_bf16(p0.x); a[1] = (short)f32_to_bf16(p0.y);
    a[2] = (short)f32_to_bf16(p0.z); a[3] = (short)f32_to_bf16(p0.w);
    a[4] = (short)f32_to_bf16(p1.x); a[5] = (short)f32_to_bf16(p1.y);
    a[6] = (short)f32_to_bf16(p1.z); a[7] = (short)f32_to_bf16(p1.w);
    const short8 b = *(const short8*)&vcT[((size_t)h * 64 + d) * 128 + ks * 32 + kgrp * 8];
    accp = __builtin_amdgcn_mfma_f32_16x16x32_bf16(a, b, accp, 0, 0, 0);
  }
#pragma unroll
  for (int r = 0; r < 4; r++)
    oc[(size_t)(t0 + kgrp * 4 + r) * 1024 + h * 64 + d] = accp[r];
}

// ---------------- selected + window branches + gated combine ----------------
__global__ __launch_bounds__(256) void nsa_swl(
    const unsigned short* __restrict__ qhf, const unsigned short* __restrict__ khfT,
    const unsigned short* __restrict__ vhf, const int4* __restrict__ sel,
    const float* __restrict__ oc, const float* __restrict__ gates,
    unsigned short* __restrict__ outf) {
  __shared__ float ps[4][64];
  const int bid = blockIdx.x;
  const int h = ((bid & 7) << 1) | ((bid >> 3) & 1);
  const int w = threadIdx.x >> 6, lane = threadIdx.x & 63;
  const int t = (bid >> 4) * 4 + w;

  const unsigned short* kT = khfT + (size_t)h * 131072;
  const unsigned short* vhh = vhf + (size_t)h * 131072;

  uint4 qr[8];
  {
    const uint4* qp = (const uint4*)(qhf + (size_t)t * 1024 + h * 64);
#pragma unroll
    for (int j = 0; j < 8; j++) qr[j] = qp[j];
  }
  const int4 s4 = sel[((size_t)h << 11) + t];

  const int g16 = lane >> 4;
  const int blk = (g16 == 0) ? s4.x : (g16 == 1) ? s4.y : (g16 == 2) ? s4.z : s4.w;
  const int tok = blk * 16 + (lane & 15);
  {
    float a0 = 0.f, a1 = 0.f, a2 = 0.f, a3 = 0.f;
#pragma unroll
    for (int dc = 0; dc < 8; dc++) {
      const uint4 kk = *(const uint4*)(kT + ((size_t)dc * 2048 + tok) * 8);
      a0 = fdot2u(kk.x, qr[dc].x, a0);
      a1 = fdot2u(kk.y, qr[dc].y, a1);
      a2 = fdot2u(kk.z, qr[dc].z, a2);
      a3 = fdot2u(kk.w, qr[dc].w, a3);
    }
    const float sv_ = (tok <= t) ? ((a0 + a1) + (a2 + a3)) * 0.125f : NEGC;
    const float Ms = wred_max(sv_);
    const float es = __expf(sv_ - Ms);
    ps[w][lane] = es * (1.f / wred_sum(es));
  }

  const int dd = lane & 31, s = lane >> 5;
  const float4* ps4 = (const float4*)ps[w];

  float osx = 0.f, osy = 0.f;
#pragma unroll
  for (int jc = 0; jc < 8; jc++) {
    const float4 p4 = ps4[s * 8 + jc];
    const float pa[4] = {p4.x, p4.y, p4.z, p4.w};
#pragma unroll
    for (int u = 0; u < 4; u++) {
      const int idx = s * 32 + jc * 4 + u;
      const int jb = idx >> 4;
      const int b2 = (jb == 0) ? s4.x : (jb == 1) ? s4.y : (jb == 2) ? s4.z : s4.w;
      const int tok2 = b2 * 16 + (idx & 15);
      const unsigned int vv = *(const unsigned int*)(vhh + (size_t)tok2 * 64 + 2 * dd);
      const h2 v2 = __builtin_bit_cast(h2, vv);
      osx += pa[u] * (float)v2[0];
      osy += pa[u] * (float)v2[1];
    }
  }
  osx += __shfl_xor(osx, 32, 64);
  osy += __shfl_xor(osy, 32, 64);

  {
    const int tw = t - 32 + lane;
    const int twc = min(max(tw, 0), T_LEN - 1);
    float a0 = 0.f, a1 = 0.f, a2 = 0.f, a3 = 0.f;
#pragma unroll
    for (int dc = 0; dc < 8; dc++) {
      const uint4 kk = *(const uint4*)(kT + ((size_t)dc * 2048 + twc) * 8);
      a0 = fdot2u(kk.x, qr[dc].x, a0);
      a1 = fdot2u(kk.y, qr[dc].y, a1);
      a2 = fdot2u(kk.z, qr[dc].z, a2);
      a3 = fdot2u(kk.w, qr[dc].w, a3);
    }
    const float swv = (tw >= 0 && lane <= 32) ? ((a0 + a1) + (a2 + a3)) * 0.125f : NEGC;
    const float Mw = wred_max(swv);
    const float ew = __expf(swv - Mw);
    ps[w][lane] = ew * (1.f / wred_sum(ew));
  }

  float olx = 0.f, oly = 0.f;
#pragma unroll
  for (int j = 0; j < 17; j++) {
    const int idx = s * 17 + j;
    const int idc = min(idx, 32);
    const float p = (idx <= 32) ? ps[w][idc] : 0.f;
    const int tk = min(max(t - 32 + idx, 0), T_LEN - 1);
    const unsigned int vv = *(const unsigned int*)(vhh + (size_t)tk * 64 + 2 * dd);
    const h2 v2 = __builtin_bit_cast(h2, vv);
    olx += p * (float)v2[0];
    oly += p * (float)v2[1];
  }
  olx += __shfl_xor(olx, 32, 64);
  oly += __shfl_xor(oly, 32, 64);

  if (lane < 32) {
    const float2 ocv = *(const float2*)&oc[(size_t)t * 1024 + h * 64 + 2 * dd];
    const float g0 = gates[t * 3 + 0], g1 = gates[t * 3 + 1], g2 = gates[t * 3 + 2];
    const float r0 = g0 * ocv.x + g1 * osx + g2 * olx;
    const float r1 = g0 * ocv.y + g1 * osy + g2 * oly;
    const unsigned int pk = (unsigned int)f32_to_bf16(r0) | ((unsigned int)f32_to_bf16(r1) << 16);
    *(unsigned int*)&outf[(size_t)t * DM + h * 64 + 2 * dd] = pk;
  }
}

// ---------------- launch ----------------
extern "C" void kernel_launch(void* const* d_in, const int* in_sizes, int n_in,
                              void* d_out, int out_size, void* d_ws, size_t ws_size,
                              hipStream_t stream) {
  const float* x   = (const float*)d_in[0];
  const float* Wq  = (const float*)d_in[1];
  const float* Wk  = (const float*)d_in[2];
  const float* Wv  = (const float*)d_in[3];
  const float* Wo  = (const float*)d_in[4];
  const float* Wck = (const float*)d_in[5];
  const float* Wcv = (const float*)d_in[6];
  const float* Wg  = (const float*)d_in[7];
  const float* bg  = (const float*)d_in[8];
  float* out = (float*)d_out;

  float* ws = (float*)d_ws;
  // region A [0,24 MB): C until compress_mfma; then oc/outf
  float*          C    = ws;
  float*          oc   = ws + 2097152;                      // [8,16 MB)
  unsigned short* outf = (unsigned short*)(ws + 4194304);   // [16,20 MB)
  // region B [24,36 MB): Axf (4 MB) until qkv GEMM; then qh + smalls
  unsigned short* Axf   = (unsigned short*)(ws + 6291456);
  float*          qh    = ws + 6291456;                     // [24,32 MB)
  unsigned short* Wot   = (unsigned short*)(ws + 8388608);  // [32,34 MB)
  unsigned short* kc_hi = (unsigned short*)(ws + 8912896);
  unsigned short* kc_lo = (unsigned short*)(ws + 8978432);
  unsigned short* vcT   = (unsigned short*)(ws + 9043968);
  int4*           sel   = (int4*)(ws + 9109504);
  unsigned short* WckT_hi = (unsigned short*)(ws + 9240576);
  unsigned short* WckT_lo = (unsigned short*)(ws + 9273344);
  unsigned short* WcvT_hi = (unsigned short*)(ws + 9306112);
  unsigned short* WcvT_lo = (unsigned short*)(ws + 9338880);
  float*          gates   = ws + 9371648;
  // region C [36,48 MB): Bqkv f16 (6 MB) until qkv GEMM; then qhf/khfT/vhf f16
  unsigned short* Bqkv = (unsigned short*)(ws + 9437184);   // 3072x1024 f16, 6 MB
  unsigned short* qhf  = (unsigned short*)(ws + 9437184);   // [36,40 MB)
  unsigned short* khfT = (unsigned short*)(ws + 10485760);  // [40,44 MB)
  unsigned short* vhf  = (unsigned short*)(ws + 11534336);  // [44,48 MB)

  // 1. operand preparation (f16 single-pass QKV operands)
  cast_x_k<<<2048, 256, 0, stream>>>(x, Axf);
  cast_wqkv<<<dim3(32, 32, 3), dim3(32, 8), 0, stream>>>(Wq, Wk, Wv, Bqkv);

  // 2. merged q|k|v GEMM: K=1024 f16, 2-phase counted-vmcnt pipeline
  qkv_gemm<<<dim3(24, 32), 256, 0, stream>>>(Axf, Bqkv, C);

  // 3. reorg + gates (C stays alive for compress); late weight casts
  reorg_qkv<<<6144, 256, 0, stream>>>(C, qh, qhf, khfT, vhf);
  gates_k<<<512, 256, 0, stream>>>(C, Wg, bg, gates);
  cast_wt1<<<dim3(32, 32), dim3(32, 8), 0, stream>>>(Wo, Wot);
  cast_wct<<<dim3(2, 32, 2), dim3(32, 8), 0, stream>>>(Wck, Wcv, WckT_hi, WckT_lo, WcvT_hi, WcvT_lo);

  // 4. compression (MFMA, reads C) + compressed branch (C dead after compress;
  //    cscore writes oc which aliases C — ordering: compress -> cscore)
  compress_mfma<<<dim3(128, 2), 512, 0, stream>>>(C, WckT_hi, WckT_lo, WcvT_hi, WcvT_lo,
                                                  kc_hi, kc_lo, vcT);
  cscore_k<<<2048, 256, 0, stream>>>(qh, kc_hi, kc_lo, vcT, oc, sel);

  // 5. selected + window + gated combine
  nsa_swl<<<8192, 256, 0, stream>>>(qhf, khfT, vhf, sel, oc, gates, outf);

  // 6. output projection (2-phase counted-vmcnt pipeline)
  gemm_bt64<<<dim3(8, 32), 256, 0, stream>>>(outf, Wot, out, 1024, 1024, 1024);
}

// Round 6
// 252.997 us; speedup vs baseline: 1.3723x; 1.0137x over previous
//
#include <hip/hip_runtime.h>
#include <hip/hip_bf16.h>
#include <float.h>

#define T_LEN 2048
#define DM    1024
#define NB    128
#define NEGC  (-1e9f)

typedef __attribute__((ext_vector_type(8))) short short8;
typedef __attribute__((ext_vector_type(4))) float floatx4;
typedef _Float16 h2 __attribute__((ext_vector_type(2)));
typedef _Float16 h8 __attribute__((ext_vector_type(8)));

// ---------------- helpers ----------------
__device__ __forceinline__ float wred_max(float v) {
#pragma unroll
  for (int o = 32; o > 0; o >>= 1) v = fmaxf(v, __shfl_xor(v, o, 64));
  return v;
}
__device__ __forceinline__ float wred_sum(float v) {
#pragma unroll
  for (int o = 32; o > 0; o >>= 1) v += __shfl_xor(v, o, 64);
  return v;
}
__device__ __forceinline__ unsigned short f32_to_bf16(float f) {
  unsigned int b = __float_as_uint(f);
  return (unsigned short)((b + 0x7fffu + ((b >> 16) & 1u)) >> 16);
}
__device__ __forceinline__ float bf16_to_f32(unsigned short u) {
  return __uint_as_float(((unsigned int)u) << 16);
}
__device__ __forceinline__ unsigned int pack_h2(float a, float b) {
  h2 r; r[0] = (_Float16)a; r[1] = (_Float16)b;
  return __builtin_bit_cast(unsigned int, r);
}
__device__ __forceinline__ unsigned short f32_to_f16u(float f) {
  h2 r; r[0] = (_Float16)f; r[1] = (_Float16)0.f;
  return (unsigned short)(__builtin_bit_cast(unsigned int, r) & 0xffffu);
}
__device__ __forceinline__ float fdot2u(unsigned int a, unsigned int b, float c) {
#if __has_builtin(__builtin_amdgcn_fdot2)
  return __builtin_amdgcn_fdot2(__builtin_bit_cast(h2, a), __builtin_bit_cast(h2, b), c, false);
#else
  const h2 av = __builtin_bit_cast(h2, a), bv = __builtin_bit_cast(h2, b);
  return c + (float)av[0] * (float)bv[0] + (float)av[1] * (float)bv[1];
#endif
}
__device__ __forceinline__ void lds_async16(unsigned short* l, const unsigned short* g) {
  __builtin_amdgcn_global_load_lds(
      (const __attribute__((address_space(1))) unsigned int*)g,
      (__attribute__((address_space(3))) unsigned int*)l, 16, 0, 0);
}

// ====== 64x128-tile MFMA GEMM core — BK=64, 2-phase counted-vmcnt ======
// r0-r5 model: step time ~1 us regardless of bytes (per-CU staging-concurrency
// floor). r4 proved fewer-steps wins (K 3x -> 2.8x faster). This round: SAME
// bytes, HALF the steps (BK 32->64). r1's BK=64 failed via __syncthreads
// vmcnt(0) drain; here raw s_barrier + vmcnt(6) keeps tile t+1's 6 loads in
// flight while tile t computes. LDS 48KB dbuf -> 3 blocks/CU exact.
// Layout per buffer: 16-row groups, chunk-major (chunk=8 u16 of K): group g
// stride 1024 u16, within = chunk*128 + row*8. Staging j covers chunks
// j*4+kgrp -> LDS dest = base(g,j) + lane*16B (lane-contiguous, required).
template <bool F16>
__device__ __forceinline__ void gemm64_core(
    const unsigned short* __restrict__ A, const unsigned short* __restrict__ Bt,
    float* __restrict__ C, int K, int lda, int row0, int bcol0, int ccol0, int ldc,
    unsigned short* As, unsigned short* Bs) {
  const int tid = threadIdx.x;
  const int w = tid >> 6, lane = tid & 63;
  const int wr = w >> 1, wc = w & 1;
  const int mrow = lane & 15, kgrp = lane >> 4;

  const int sr = (w << 4) + mrow;          // staged row 0..63
  const int sc = kgrp;                     // staged chunk within 4-chunk half

  floatx4 zero = {0.f, 0.f, 0.f, 0.f};
  floatx4 acc[2][4];
#pragma unroll
  for (int i = 0; i < 2; i++)
#pragma unroll
    for (int j = 0; j < 4; j++) acc[i][j] = zero;

  const int nt = K >> 6;
  const unsigned short* Ap  = A  + (size_t)(row0 + sr) * lda + sc * 8;
  const unsigned short* Bp0 = Bt + (size_t)(bcol0 + sr) * K + sc * 8;
  const unsigned short* Bp1 = Bt + (size_t)(bcol0 + 64 + sr) * K + sc * 8;

  auto stage = [&](int t, int b) {
    const int ko = t << 6;
#pragma unroll
    for (int j = 0; j < 2; j++) {
      lds_async16(&As[b * 4096 + w * 1024 + j * 512], Ap + ko + j * 32);
      lds_async16(&Bs[b * 8192 + w * 1024 + j * 512], Bp0 + ko + j * 32);
      lds_async16(&Bs[b * 8192 + 4096 + w * 1024 + j * 512], Bp1 + ko + j * 32);
    }
  };

  stage(0, 0);
  int cur = 0;
  for (int t = 0; t < nt; t++) {
    if (t + 1 < nt) {
      stage(t + 1, cur ^ 1);                              // outstanding: 12
      asm volatile("s_waitcnt vmcnt(6)" ::: "memory");    // tile t landed; t+1 in flight
    } else {
      asm volatile("s_waitcnt vmcnt(0)" ::: "memory");    // final tile: drain
    }
    __builtin_amdgcn_s_barrier();
    const unsigned short* as = As + cur * 4096;
    const unsigned short* bs = Bs + cur * 8192;
#pragma unroll
    for (int ks = 0; ks < 2; ks++) {
      short8 af[2], bf4[4];
#pragma unroll
      for (int mi = 0; mi < 2; mi++)
        af[mi] = *(const short8*)&as[(wr * 2 + mi) * 1024 + (ks * 4 + kgrp) * 128 + mrow * 8];
#pragma unroll
      for (int ni = 0; ni < 4; ni++)
        bf4[ni] = *(const short8*)&bs[(wc * 4 + ni) * 1024 + (ks * 4 + kgrp) * 128 + mrow * 8];
#pragma unroll
      for (int mi = 0; mi < 2; mi++)
#pragma unroll
        for (int ni = 0; ni < 4; ni++) {
          if constexpr (F16)
            acc[mi][ni] = __builtin_amdgcn_mfma_f32_16x16x32_f16(
                __builtin_bit_cast(h8, af[mi]), __builtin_bit_cast(h8, bf4[ni]),
                acc[mi][ni], 0, 0, 0);
          else
            acc[mi][ni] = __builtin_amdgcn_mfma_f32_16x16x32_bf16(af[mi], bf4[ni],
                                                                  acc[mi][ni], 0, 0, 0);
        }
    }
    asm volatile("" ::: "memory");
    __builtin_amdgcn_s_barrier();       // all reads of buf[cur] done before overwrite
    cur ^= 1;
  }
#pragma unroll
  for (int mi = 0; mi < 2; mi++)
#pragma unroll
    for (int ni = 0; ni < 4; ni++) {
      float* Cp = C + (size_t)(row0 + wr * 32 + mi * 16 + kgrp * 4) * ldc
                    + ccol0 + wc * 64 + ni * 16 + mrow;
      Cp[0] = acc[mi][ni][0];
      Cp[(size_t)ldc] = acc[mi][ni][1];
      Cp[(size_t)2 * ldc] = acc[mi][ni][2];
      Cp[(size_t)3 * ldc] = acc[mi][ni][3];
    }
}

// merged q|k|v GEMM: grid (24, 32), f16 single pass K=1024 (r4 win).
__global__ __launch_bounds__(256) void qkv_gemm(const unsigned short* __restrict__ Axf,
                                                const unsigned short* __restrict__ Bqkv,
                                                float* __restrict__ C) {
  __shared__ __align__(16) unsigned short As[2 * 64 * 64];
  __shared__ __align__(16) unsigned short Bs[2 * 128 * 64];
  gemm64_core<true>(Axf, Bqkv, C, 1024, 1024, blockIdx.y * 64,
                    blockIdx.x * 128, blockIdx.x * 128, 3072, As, Bs);
}

// final output projection (bf16 inputs)
__global__ __launch_bounds__(256) void gemm_bt64(const unsigned short* __restrict__ A,
                                                 const unsigned short* __restrict__ Bt,
                                                 float* __restrict__ C,
                                                 int K, int lda, int ldc) {
  __shared__ __align__(16) unsigned short As[2 * 64 * 64];
  __shared__ __align__(16) unsigned short Bs[2 * 128 * 64];
  gemm64_core<false>(A, Bt, C, K, lda, blockIdx.y * 64,
                     blockIdx.x * 128, blockIdx.x * 128, ldc, As, Bs);
}

// ---------------- cast x -> f16 (2048 x 1024) ----------------
__global__ __launch_bounds__(256) void cast_x_k(const float* __restrict__ x,
                                                unsigned short* __restrict__ Axf) {
  const int gid = blockIdx.x * 256 + threadIdx.x;
  float4 xv = ((const float4*)x)[gid];
  const unsigned int p0 = pack_h2(xv.x, xv.y);
  const unsigned int p1 = pack_h2(xv.z, xv.w);
  *(uint2*)&Axf[(size_t)gid * 4] = make_uint2(p0, p1);
}

// ---- transpose-cast Wq/Wk/Wv (by blockIdx.z) into Bqkv f16 (3072n x 1024k) ----
__global__ void cast_wqkv(const float* __restrict__ Wq, const float* __restrict__ Wk,
                          const float* __restrict__ Wv, unsigned short* __restrict__ Bt) {
  __shared__ float tile[32][33];
  const float* W = (blockIdx.z == 0) ? Wq : (blockIdx.z == 1) ? Wk : Wv;
  const int n0 = blockIdx.z * 1024;
  const int kt0 = blockIdx.y * 32, nt0 = blockIdx.x * 32;
  const int tx = threadIdx.x, ty = threadIdx.y;
#pragma unroll
  for (int i = 0; i < 32; i += 8)
    tile[ty + i][tx] = W[(size_t)(kt0 + ty + i) * 1024 + nt0 + tx];
  __syncthreads();
#pragma unroll
  for (int i = 0; i < 32; i += 8) {
    const int n = nt0 + ty + i, kk = kt0 + tx;
    Bt[(size_t)(n0 + n) * 1024 + kk] = f32_to_f16u(tile[tx][ty + i]);
  }
}

// ---- transpose-cast 1024x1024 W -> Bt (1024n x 1024k) bf16 ----
__global__ void cast_wt1(const float* __restrict__ W, unsigned short* __restrict__ Bt) {
  __shared__ float tile[32][33];
  const int kt0 = blockIdx.y * 32, nt0 = blockIdx.x * 32;
  const int tx = threadIdx.x, ty = threadIdx.y;
#pragma unroll
  for (int i = 0; i < 32; i += 8)
    tile[ty + i][tx] = W[(size_t)(kt0 + ty + i) * 1024 + nt0 + tx];
  __syncthreads();
#pragma unroll
  for (int i = 0; i < 32; i += 8) {
    const int n = nt0 + ty + i, kk = kt0 + tx;
    Bt[(size_t)n * 1024 + kk] = f32_to_bf16(tile[tx][ty + i]);
  }
}

// ---- transpose-cast Wck/Wcv (1024x64) -> (64,1024) hi/lo bf16 ----
__global__ void cast_wct(const float* __restrict__ Wck, const float* __restrict__ Wcv,
                         unsigned short* __restrict__ KT_hi, unsigned short* __restrict__ KT_lo,
                         unsigned short* __restrict__ VT_hi, unsigned short* __restrict__ VT_lo) {
  __shared__ float tile[32][33];
  const float* W = blockIdx.z ? Wcv : Wck;
  unsigned short* Bh = blockIdx.z ? VT_hi : KT_hi;
  unsigned short* Bl = blockIdx.z ? VT_lo : KT_lo;
  const int kt0 = blockIdx.y * 32, nt0 = blockIdx.x * 32;
  const int tx = threadIdx.x, ty = threadIdx.y;
#pragma unroll
  for (int i = 0; i < 32; i += 8)
    tile[ty + i][tx] = W[(size_t)(kt0 + ty + i) * 64 + nt0 + tx];
  __syncthreads();
#pragma unroll
  for (int i = 0; i < 32; i += 8) {
    const int n = nt0 + ty + i, kk = kt0 + tx;
    const float f = tile[tx][ty + i];
    const unsigned short hb = f32_to_bf16(f);
    Bh[(size_t)n * 1024 + kk] = hb;
    Bl[(size_t)n * 1024 + kk] = f32_to_bf16(f - bf16_to_f32(hb));
  }
}

// ---------------- reorg: C(t,3072) -> qh f32, qhf f16 (T,1024),
//                  khfT f16 (H, 8, T, 8), vhf f16 (H, T, 64) ----------------
__global__ __launch_bounds__(256) void reorg_qkv(const float* __restrict__ C,
                                                 float* __restrict__ qh,
                                                 unsigned short* __restrict__ qhf,
                                                 unsigned short* __restrict__ khfT,
                                                 unsigned short* __restrict__ vhf) {
  const int gid = blockIdx.x * 256 + threadIdx.x;
  const int t = gid / 768;
  const int c = (gid - t * 768) * 4;
  float4 val = *(const float4*)&C[(size_t)t * 3072 + c];
  const unsigned int p0 = pack_h2(val.x, val.y);
  const unsigned int p1 = pack_h2(val.z, val.w);
  if (c < 1024) {
    *(float4*)&qh[(size_t)t * 1024 + c] = val;
    *(uint2*)&qhf[(size_t)t * 1024 + c] = make_uint2(p0, p1);
  } else if (c < 2048) {
    const int h = (c >> 6) & 15, d = c & 63;
    const int dc = d >> 3, j = d & 7;
    *(uint2*)&khfT[((size_t)(h * 8 + dc) * 2048 + t) * 8 + j] = make_uint2(p0, p1);
  } else {
    const int h = (c >> 6) & 15, d = c & 63;
    *(uint2*)&vhf[((size_t)h * 2048 + t) * 64 + d] = make_uint2(p0, p1);
  }
}

// ---- transpose vhf [h][t][64] -> vhfT [h][d][2048] f16 (for window PV MFMA) ----
__global__ void transp_v(const unsigned short* __restrict__ vhf,
                         unsigned short* __restrict__ vhfT) {
  __shared__ unsigned short tile[32][34];
  const int h = blockIdx.z;
  const int t0 = blockIdx.x * 32, d0 = blockIdx.y * 32;
  const int tx = threadIdx.x, ty = threadIdx.y;
#pragma unroll
  for (int i = 0; i < 32; i += 8)
    tile[ty + i][tx] = vhf[((size_t)h * 2048 + t0 + ty + i) * 64 + d0 + tx];
  __syncthreads();
#pragma unroll
  for (int i = 0; i < 32; i += 8)
    vhfT[((size_t)h * 64 + d0 + ty + i) * 2048 + t0 + tx] = tile[tx][ty + i];
}

// ---------------- compress via MFMA (reads k/v straight from C) ----------------
__global__ __launch_bounds__(512) void compress_mfma(
    const float* __restrict__ C,
    const unsigned short* __restrict__ KT_hi, const unsigned short* __restrict__ KT_lo,
    const unsigned short* __restrict__ VT_hi, const unsigned short* __restrict__ VT_lo,
    unsigned short* __restrict__ kc_hi, unsigned short* __restrict__ kc_lo,
    unsigned short* __restrict__ vcT) {
  __shared__ float red[8][64][17];
  const int isv = blockIdx.y;
  const unsigned short* Bh = isv ? VT_hi : KT_hi;
  const unsigned short* Bl = isv ? VT_lo : KT_lo;
  const int tid = threadIdx.x, w = tid >> 6, lane = tid & 63;
  const int mrow = lane & 15, kgrp = lane >> 4;
  const int m0 = blockIdx.x * 16;
  const int m = m0 + mrow;
  const int hh = m >> 7, nb = m & 127;
  const int cbase = 1024 + isv * 1024 + hh * 64;

  floatx4 zero = {0.f, 0.f, 0.f, 0.f};
  floatx4 acc[4] = {zero, zero, zero, zero};

  const int kbeg = w << 7;                  // per-wave K chunk of 128
  for (int k0 = kbeg; k0 < kbeg + 128; k0 += 32) {
    const int c = k0 + kgrp * 8;
    const float* ap = &C[(size_t)(nb * 16 + (c >> 6)) * 3072 + cbase + (c & 63)];
    float4 q0 = *(const float4*)ap;
    float4 q1 = *(const float4*)(ap + 4);
    float qq[8] = {q0.x, q0.y, q0.z, q0.w, q1.x, q1.y, q1.z, q1.w};
    short8 a_hi, a_lo;
#pragma unroll
    for (int j = 0; j < 8; j++) {
      unsigned short hb = f32_to_bf16(qq[j]);
      a_hi[j] = (short)hb;
      a_lo[j] = (short)f32_to_bf16(qq[j] - bf16_to_f32(hb));
    }
#pragma unroll
    for (int ni = 0; ni < 4; ni++) {
      const size_t boff = (size_t)(ni * 16 + mrow) * 1024 + k0 + kgrp * 8;
      short8 b_hi = *(const short8*)&Bh[boff];
      short8 b_lo = *(const short8*)&Bl[boff];
      acc[ni] = __builtin_amdgcn_mfma_f32_16x16x32_bf16(a_hi, b_hi, acc[ni], 0, 0, 0);
      acc[ni] = __builtin_amdgcn_mfma_f32_16x16x32_bf16(a_lo, b_hi, acc[ni], 0, 0, 0);
      acc[ni] = __builtin_amdgcn_mfma_f32_16x16x32_bf16(a_hi, b_lo, acc[ni], 0, 0, 0);
    }
  }

#pragma unroll
  for (int ni = 0; ni < 4; ni++)
#pragma unroll
    for (int r = 0; r < 4; r++) red[w][lane][ni * 4 + r] = acc[ni][r];
  __syncthreads();

  if (w < 4) {
#pragma unroll
    for (int r = 0; r < 4; r++) {
      const int j = w * 4 + r;
      float val = 0.f;
#pragma unroll
      for (int ww = 0; ww < 8; ww++) val += red[ww][lane][j];
      const int mo = m0 + kgrp * 4 + r;
      const int d = w * 16 + mrow;
      if (!isv) {
        const unsigned short hb = f32_to_bf16(val);
        kc_hi[(size_t)mo * 64 + d] = hb;
        kc_lo[(size_t)mo * 64 + d] = f32_to_bf16(val - bf16_to_f32(hb));
      } else {
        vcT[(size_t)(mo >> 7) * 8192 + (size_t)d * 128 + (mo & 127)] = f32_to_bf16(val);
      }
    }
  }
}

// ---------------- gates ----------------
__global__ __launch_bounds__(256) void gates_k(const float* __restrict__ C,
                                               const float* __restrict__ Wg,
                                               const float* __restrict__ bg,
                                               float* __restrict__ gates) {
  const int w = threadIdx.x >> 6, lane = threadIdx.x & 63;
  const int t = blockIdx.x * 4 + w;
  float m = 0.f;
#pragma unroll
  for (int h = 0; h < 16; h++) m += C[(size_t)t * 3072 + h * 64 + lane];
  m *= (1.f / 16.f);
  float g0 = wred_sum(m * Wg[lane * 3 + 0]);
  float g1 = wred_sum(m * Wg[lane * 3 + 1]);
  float g2 = wred_sum(m * Wg[lane * 3 + 2]);
  if (lane == 0) {
    g0 += bg[0]; g1 += bg[1]; g2 += bg[2];
    float mx = fmaxf(g0, fmaxf(g1, g2));
    float e0 = __expf(g0 - mx), e1 = __expf(g1 - mx), e2 = __expf(g2 - mx);
    float inv = 1.f / (e0 + e1 + e2);
    gates[t * 3 + 0] = e0 * inv;
    gates[t * 3 + 1] = e1 * inv;
    gates[t * 3 + 2] = e2 * inv;
  }
}

// ------- cscore: MFMA scores + softmax + top-4 + fused PV (r5 version) -------
__global__ __launch_bounds__(256) void cscore_k(
    const float* __restrict__ qh, const unsigned short* __restrict__ kc_hi,
    const unsigned short* __restrict__ kc_lo, const unsigned short* __restrict__ vcT,
    float* __restrict__ oc, int4* __restrict__ sel) {
  __shared__ float S_s[16][132];
  const int h = blockIdx.x >> 7, t0 = (blockIdx.x & 127) * 16;
  const int tid = threadIdx.x, w = tid >> 6, lane = tid & 63;
  const int mrow = lane & 15, kgrp = lane >> 4;

  short8 a_hi[2], a_lo[2];
#pragma unroll
  for (int ks = 0; ks < 2; ks++) {
    const float* qp = &qh[(size_t)(t0 + mrow) * 1024 + h * 64 + ks * 32 + kgrp * 8];
    float4 q0 = *(const float4*)qp;
    float4 q1 = *(const float4*)(qp + 4);
    float qq[8] = {q0.x, q0.y, q0.z, q0.w, q1.x, q1.y, q1.z, q1.w};
#pragma unroll
    for (int j = 0; j < 8; j++) {
      unsigned short hb = f32_to_bf16(qq[j]);
      a_hi[ks][j] = (short)hb;
      a_lo[ks][j] = (short)f32_to_bf16(qq[j] - bf16_to_f32(hb));
    }
  }
  floatx4 zero = {0.f, 0.f, 0.f, 0.f};
  floatx4 acc[2] = {zero, zero};
#pragma unroll
  for (int ni = 0; ni < 2; ni++) {
    const int nb = w * 32 + ni * 16 + mrow;
#pragma unroll
    for (int ks = 0; ks < 2; ks++) {
      const size_t off = ((size_t)h * 128 + nb) * 64 + ks * 32 + kgrp * 8;
      short8 b_hi = *(const short8*)&kc_hi[off];
      short8 b_lo = *(const short8*)&kc_lo[off];
      acc[ni] = __builtin_amdgcn_mfma_f32_16x16x32_bf16(a_hi[ks], b_hi, acc[ni], 0, 0, 0);
      acc[ni] = __builtin_amdgcn_mfma_f32_16x16x32_bf16(a_lo[ks], b_hi, acc[ni], 0, 0, 0);
      acc[ni] = __builtin_amdgcn_mfma_f32_16x16x32_bf16(a_hi[ks], b_lo, acc[ni], 0, 0, 0);
    }
  }
#pragma unroll
  for (int ni = 0; ni < 2; ni++) {
    const int n = w * 32 + ni * 16 + mrow;
#pragma unroll
    for (int r = 0; r < 4; r++) {
      const int row = kgrp * 4 + r;
      const int count = (t0 + row) >> 4;
      S_s[row][n] = (n < count) ? acc[ni][r] * 0.125f : NEGC;
    }
  }
  __syncthreads();

  for (int qq = 0; qq < 4; qq++) {
    const int row = w * 4 + qq, t = t0 + row, count = t >> 4;
    const float2 sv = *(const float2*)&S_s[row][2 * lane];
    const float s0 = sv.x, s1 = sv.y;
    const float M = wred_max(fmaxf(s0, s1));
    const float e0 = __expf(s0 - M), e1 = __expf(s1 - M);
    const float inv = 1.f / wred_sum(e0 + e1);
    S_s[row][2 * lane]     = (count == 0) ? 0.f : e0 * inv;
    S_s[row][2 * lane + 1] = (count == 0) ? 0.f : e1 * inv;

    float c0 = s0, c1 = s1;
    int sel0 = 0, sel1 = 0, sel2 = 0, sel3 = 0;
#pragma unroll
    for (int j = 0; j < 4; j++) {
      float bv; int bi;
      if (c0 >= c1) { bv = c0; bi = 2 * lane; } else { bv = c1; bi = 2 * lane + 1; }
#pragma unroll
      for (int o = 32; o > 0; o >>= 1) {
        const float ov = __shfl_xor(bv, o, 64);
        const int oi = __shfl_xor(bi, o, 64);
        if (ov > bv || (ov == bv && oi < bi)) { bv = ov; bi = oi; }
      }
      if (j == 0) sel0 = bi; else if (j == 1) sel1 = bi;
      else if (j == 2) sel2 = bi; else sel3 = bi;
      if (bi == 2 * lane) c0 = -FLT_MAX;
      if (bi == 2 * lane + 1) c1 = -FLT_MAX;
    }
    if (lane == 0) sel[((size_t)h << 11) + t] = make_int4(sel0, sel1, sel2, sel3);
  }
  __syncthreads();

  const int d = w * 16 + mrow;
  floatx4 accp = zero;
#pragma unroll
  for (int ks = 0; ks < 4; ks++) {
    const float4 p0 = *(const float4*)&S_s[mrow][ks * 32 + kgrp * 8];
    const float4 p1 = *(const float4*)&S_s[mrow][ks * 32 + kgrp * 8 + 4];
    short8 a;
    a[0] = (short)f32_to_bf16(p0.x); a[1] = (short)f32_to_bf16(p0.y);
    a[2] = (short)f32_to_bf16(p0.z); a[3] = (short)f32_to_bf16(p0.w);
    a[4] = (short)f32_to_bf16(p1.x); a[5] = (short)f32_to_bf16(p1.y);
    a[6] = (short)f32_to_bf16(p1.z); a[7] = (short)f32_to_bf16(p1.w);
    const short8 b = *(const short8*)&vcT[((size_t)h * 64 + d) * 128 + ks * 32 + kgrp * 8];
    accp = __builtin_amdgcn_mfma_f32_16x16x32_bf16(a, b, accp, 0, 0, 0);
  }
#pragma unroll
  for (int r = 0; r < 4; r++)
    oc[(size_t)(t0 + kgrp * 4 + r) * 1024 + h * 64 + d] = accp[r];
}

// ------------- selected branch only: per-wave per-(h,t), writes osel -------------
__global__ __launch_bounds__(256) void nsa_sel(
    const unsigned short* __restrict__ qhf, const unsigned short* __restrict__ khfT,
    const unsigned short* __restrict__ vhf, const int4* __restrict__ sel,
    float* __restrict__ osel) {
  __shared__ float ps[4][64];
  __shared__ int tks[4][64];
  const int bid = blockIdx.x;
  const int h = ((bid & 7) << 1) | ((bid >> 3) & 1);
  const int w = threadIdx.x >> 6, lane = threadIdx.x & 63;
  const int t = (bid >> 4) * 4 + w;

  const unsigned short* kT = khfT + (size_t)h * 131072;
  const unsigned short* vhh = vhf + (size_t)h * 131072;

  uint4 qr[8];
  {
    const uint4* qp = (const uint4*)(qhf + (size_t)t * 1024 + h * 64);
#pragma unroll
    for (int j = 0; j < 8; j++) qr[j] = qp[j];
  }
  const int4 s4 = sel[((size_t)h << 11) + t];

  const int g16 = lane >> 4;
  const int blk = (g16 == 0) ? s4.x : (g16 == 1) ? s4.y : (g16 == 2) ? s4.z : s4.w;
  const int tok = blk * 16 + (lane & 15);
  tks[w][lane] = tok;                        // cache token idx for PV (kills cndmask chain)
  {
    float a0 = 0.f, a1 = 0.f, a2 = 0.f, a3 = 0.f;
#pragma unroll
    for (int dc = 0; dc < 8; dc++) {
      const uint4 kk = *(const uint4*)(kT + ((size_t)dc * 2048 + tok) * 8);
      a0 = fdot2u(kk.x, qr[dc].x, a0);
      a1 = fdot2u(kk.y, qr[dc].y, a1);
      a2 = fdot2u(kk.z, qr[dc].z, a2);
      a3 = fdot2u(kk.w, qr[dc].w, a3);
    }
    const float sv_ = (tok <= t) ? ((a0 + a1) + (a2 + a3)) * 0.125f : NEGC;
    const float Ms = wred_max(sv_);
    const float es = __expf(sv_ - Ms);
    ps[w][lane] = es * (1.f / wred_sum(es));
  }

  const int dd = lane & 31, s = lane >> 5;
  const float4* ps4 = (const float4*)ps[w];
  const int4* tk4p = (const int4*)tks[w];

  float osx = 0.f, osy = 0.f;
#pragma unroll
  for (int jc = 0; jc < 8; jc++) {
    const float4 p4 = ps4[s * 8 + jc];
    const int4 t4 = tk4p[s * 8 + jc];
    const float pa[4] = {p4.x, p4.y, p4.z, p4.w};
    const int ta[4] = {t4.x, t4.y, t4.z, t4.w};
#pragma unroll
    for (int u = 0; u < 4; u++) {
      const unsigned int vv = *(const unsigned int*)(vhh + (size_t)ta[u] * 64 + 2 * dd);
      const h2 v2 = __builtin_bit_cast(h2, vv);
      osx += pa[u] * (float)v2[0];
      osy += pa[u] * (float)v2[1];
    }
  }
  osx += __shfl_xor(osx, 32, 64);
  osy += __shfl_xor(osy, 32, 64);

  if (lane < 32)
    *(float2*)&osel[(size_t)t * 1024 + h * 64 + 2 * dd] = make_float2(osx, osy);
}

// ------------- window branch via MFMA + gated combine -> outf -------------
// Block = (h, 64-query tile), 4 waves; wave w owns queries qt0..qt0+15.
// Keys: s = kb + n, n=0..47, kb = qt0-32 (union of all 16 windows).
// Scores 16x48 = 3 n-tiles x 2 k-steps MFMA f16; mask 0<=t-s<=32; row softmax
// across the 16 lanes sharing kgrp; P (f16) -> LDS [16][72] (pad vs stride-128B
// bank conflict, G4); PV 16x64 = 4 n-tiles x 2 k-steps with B = vhfT[d][t].
// Clamped V/K loads only touch P==0 slots (8-token ranges align, kb mult of 16).
__global__ __launch_bounds__(256) void nsa_win(
    const unsigned short* __restrict__ qhf, const unsigned short* __restrict__ khfT,
    const unsigned short* __restrict__ vhfT, const float* __restrict__ oc,
    const float* __restrict__ osel, const float* __restrict__ gates,
    unsigned short* __restrict__ outf) {
  __shared__ unsigned short P_lds[4][16][72];
  const int bid = blockIdx.x;
  const int h = bid & 15, tq0 = (bid >> 4) * 64;
  const int w = threadIdx.x >> 6, lane = threadIdx.x & 63;
  const int cc = lane & 15, kgrp = lane >> 4;
  const int qt0 = tq0 + w * 16;
  const int kb = qt0 - 32;

  const unsigned short* kT = khfT + (size_t)h * 131072;
  const unsigned short* vT = vhfT + (size_t)h * 131072;

  short8 aq[2];
#pragma unroll
  for (int ks = 0; ks < 2; ks++)
    aq[ks] = *(const short8*)&qhf[(size_t)(qt0 + cc) * 1024 + h * 64 + ks * 32 + kgrp * 8];

  floatx4 zero = {0.f, 0.f, 0.f, 0.f};
  floatx4 accs[3] = {zero, zero, zero};
#pragma unroll
  for (int ni = 0; ni < 3; ni++) {
    const int tokc = min(max(kb + ni * 16 + cc, 0), T_LEN - 1);
#pragma unroll
    for (int ks = 0; ks < 2; ks++) {
      const short8 bk = *(const short8*)&kT[((size_t)(ks * 4 + kgrp) * 2048 + tokc) * 8];
      accs[ni] = __builtin_amdgcn_mfma_f32_16x16x32_f16(
          __builtin_bit_cast(h8, aq[ks]), __builtin_bit_cast(h8, bk), accs[ni], 0, 0, 0);
    }
  }

  // mask + row softmax; D layout: row(query)=kgrp*4+r, col(key slot)=ni*16+cc
#pragma unroll
  for (int r = 0; r < 4; r++) {
    const int t = qt0 + kgrp * 4 + r;
    float sc[3];
#pragma unroll
    for (int ni = 0; ni < 3; ni++) {
      const int s = kb + ni * 16 + cc;
      const int ds = t - s;
      sc[ni] = (s >= 0 && ds >= 0 && ds <= 32) ? accs[ni][r] * 0.125f : NEGC;
    }
    float m3 = fmaxf(fmaxf(sc[0], sc[1]), sc[2]);
#pragma unroll
    for (int o = 1; o <= 8; o <<= 1) m3 = fmaxf(m3, __shfl_xor(m3, o, 64));
    float e0 = __expf(sc[0] - m3), e1 = __expf(sc[1] - m3), e2 = __expf(sc[2] - m3);
    float sum = e0 + e1 + e2;
#pragma unroll
    for (int o = 1; o <= 8; o <<= 1) sum += __shfl_xor(sum, o, 64);
    const float inv = 1.f / sum;
    const int row = kgrp * 4 + r;
    P_lds[w][row][cc]      = f32_to_f16u(e0 * inv);
    P_lds[w][row][16 + cc] = f32_to_f16u(e1 * inv);
    P_lds[w][row][32 + cc] = f32_to_f16u(e2 * inv);
  }
  {  // zero pad slots 48..63 (read by PV k-step 1)
    const int rr = lane >> 2, c0 = 48 + (lane & 3) * 4;
    *(ushort4*)&P_lds[w][rr][c0] = make_ushort4(0, 0, 0, 0);
  }
  __syncthreads();

  floatx4 accp[4] = {zero, zero, zero, zero};
#pragma unroll
  for (int ks2 = 0; ks2 < 2; ks2++) {
    const short8 ap = *(const short8*)&P_lds[w][cc][ks2 * 32 + kgrp * 8];
    const int tok0 = min(max(kb + ks2 * 32 + kgrp * 8, 0), T_LEN - 8);
#pragma unroll
    for (int ni = 0; ni < 4; ni++) {
      const short8 bv = *(const short8*)&vT[(size_t)(ni * 16 + cc) * 2048 + tok0];
      accp[ni] = __builtin_amdgcn_mfma_f32_16x16x32_f16(
          __builtin_bit_cast(h8, ap), __builtin_bit_cast(h8, bv), accp[ni], 0, 0, 0);
    }
  }

  // combine: out = g0*oc + g1*osel + g2*ol, write bf16
#pragma unroll
  for (int r = 0; r < 4; r++) {
    const int t = qt0 + kgrp * 4 + r;
    const float g0 = gates[t * 3 + 0], g1 = gates[t * 3 + 1], g2 = gates[t * 3 + 2];
#pragma unroll
    for (int ni = 0; ni < 4; ni++) {
      const int d = ni * 16 + cc;
      const float ocv = oc[(size_t)t * 1024 + h * 64 + d];
      const float osv = osel[(size_t)t * 1024 + h * 64 + d];
      outf[(size_t)t * 1024 + h * 64 + d] =
          f32_to_bf16(g0 * ocv + g1 * osv + g2 * accp[ni][r]);
    }
  }
}

// ---------------- launch ----------------
extern "C" void kernel_launch(void* const* d_in, const int* in_sizes, int n_in,
                              void* d_out, int out_size, void* d_ws, size_t ws_size,
                              hipStream_t stream) {
  const float* x   = (const float*)d_in[0];
  const float* Wq  = (const float*)d_in[1];
  const float* Wk  = (const float*)d_in[2];
  const float* Wv  = (const float*)d_in[3];
  const float* Wo  = (const float*)d_in[4];
  const float* Wck = (const float*)d_in[5];
  const float* Wcv = (const float*)d_in[6];
  const float* Wg  = (const float*)d_in[7];
  const float* bg  = (const float*)d_in[8];
  float* out = (float*)d_out;

  float* ws = (float*)d_ws;
  // region A [0,24 MB): C until compress; then osel [0,8), oc [8,16), outf [16,20)
  float*          C    = ws;
  float*          osel = ws;                                // [0,8 MB)
  float*          oc   = ws + 2097152;                      // [8,16 MB)
  unsigned short* outf = (unsigned short*)(ws + 4194304);   // [16,20 MB)
  // region B [24,36 MB): Axf (4 MB) until qkv GEMM; then qh + smalls
  unsigned short* Axf   = (unsigned short*)(ws + 6291456);
  float*          qh    = ws + 6291456;                     // [24,32 MB)
  unsigned short* Wot   = (unsigned short*)(ws + 8388608);  // [32,34 MB)
  unsigned short* kc_hi = (unsigned short*)(ws + 8912896);
  unsigned short* kc_lo = (unsigned short*)(ws + 8978432);
  unsigned short* vcT   = (unsigned short*)(ws + 9043968);
  int4*           sel   = (int4*)(ws + 9109504);
  unsigned short* WckT_hi = (unsigned short*)(ws + 9240576);
  unsigned short* WckT_lo = (unsigned short*)(ws + 9273344);
  unsigned short* WcvT_hi = (unsigned short*)(ws + 9306112);
  unsigned short* WcvT_lo = (unsigned short*)(ws + 9338880);
  float*          gates   = ws + 9371648;
  // region C [36,48 MB): Bqkv f16 (6 MB) until qkv GEMM; then qhf/khfT/vhf f16
  unsigned short* Bqkv = (unsigned short*)(ws + 9437184);   // 3072x1024 f16, 6 MB
  unsigned short* qhf  = (unsigned short*)(ws + 9437184);   // [36,40 MB)
  unsigned short* khfT = (unsigned short*)(ws + 10485760);  // [40,44 MB)
  unsigned short* vhf  = (unsigned short*)(ws + 11534336);  // [44,48 MB)
  // vhfT scratch lives in d_out (read by nsa_win, then gemm_bt64 overwrites out)
  unsigned short* vhfT = (unsigned short*)d_out;            // 16x64x2048 f16, 4 MB

  // 1. operand preparation (f16 single-pass QKV operands)
  cast_x_k<<<2048, 256, 0, stream>>>(x, Axf);
  cast_wqkv<<<dim3(32, 32, 3), dim3(32, 8), 0, stream>>>(Wq, Wk, Wv, Bqkv);

  // 2. merged q|k|v GEMM: K=1024 f16, BK=64 counted-vmcnt pipeline (16 steps)
  qkv_gemm<<<dim3(24, 32), 256, 0, stream>>>(Axf, Bqkv, C);

  // 3. reorg (+ V transpose for window MFMA) + gates; late weight casts
  reorg_qkv<<<6144, 256, 0, stream>>>(C, qh, qhf, khfT, vhf);
  transp_v<<<dim3(64, 2, 16), dim3(32, 8), 0, stream>>>(vhf, vhfT);
  gates_k<<<512, 256, 0, stream>>>(C, Wg, bg, gates);
  cast_wt1<<<dim3(32, 32), dim3(32, 8), 0, stream>>>(Wo, Wot);
  cast_wct<<<dim3(2, 32, 2), dim3(32, 8), 0, stream>>>(Wck, Wcv, WckT_hi, WckT_lo, WcvT_hi, WcvT_lo);

  // 4. compression (reads C; C dead after) + compressed branch (oc aliases C tail)
  compress_mfma<<<dim3(128, 2), 512, 0, stream>>>(C, WckT_hi, WckT_lo, WcvT_hi, WcvT_lo,
                                                  kc_hi, kc_lo, vcT);
  cscore_k<<<2048, 256, 0, stream>>>(qh, kc_hi, kc_lo, vcT, oc, sel);

  // 5. selected branch (scalar, per-query) -> osel; window branch (MFMA) + combine
  nsa_sel<<<8192, 256, 0, stream>>>(qhf, khfT, vhf, sel, osel);
  nsa_win<<<512, 256, 0, stream>>>(qhf, khfT, vhfT, oc, osel, gates, outf);

  // 6. output projection (BK=64 counted-vmcnt, 16 steps)
  gemm_bt64<<<dim3(8, 32), 256, 0, stream>>>(outf, Wot, out, 1024, 1024, 1024);
}

// Round 7
// 242.843 us; speedup vs baseline: 1.4297x; 1.0418x over previous
//
#include <hip/hip_runtime.h>
#include <hip/hip_bf16.h>
#include <float.h>

#define T_LEN 2048
#define DM    1024
#define NB    128
#define NEGC  (-1e9f)

typedef __attribute__((ext_vector_type(8))) short short8;
typedef __attribute__((ext_vector_type(4))) float floatx4;
typedef _Float16 h2 __attribute__((ext_vector_type(2)));
typedef _Float16 h8 __attribute__((ext_vector_type(8)));

// ---------------- helpers ----------------
__device__ __forceinline__ float wred_max(float v) {
#pragma unroll
  for (int o = 32; o > 0; o >>= 1) v = fmaxf(v, __shfl_xor(v, o, 64));
  return v;
}
__device__ __forceinline__ float wred_sum(float v) {
#pragma unroll
  for (int o = 32; o > 0; o >>= 1) v += __shfl_xor(v, o, 64);
  return v;
}
__device__ __forceinline__ unsigned short f32_to_bf16(float f) {
  unsigned int b = __float_as_uint(f);
  return (unsigned short)((b + 0x7fffu + ((b >> 16) & 1u)) >> 16);
}
__device__ __forceinline__ float bf16_to_f32(unsigned short u) {
  return __uint_as_float(((unsigned int)u) << 16);
}
__device__ __forceinline__ unsigned int pack_h2(float a, float b) {
  h2 r; r[0] = (_Float16)a; r[1] = (_Float16)b;
  return __builtin_bit_cast(unsigned int, r);
}
__device__ __forceinline__ unsigned short f32_to_f16u(float f) {
  h2 r; r[0] = (_Float16)f; r[1] = (_Float16)0.f;
  return (unsigned short)(__builtin_bit_cast(unsigned int, r) & 0xffffu);
}
__device__ __forceinline__ float fdot2u(unsigned int a, unsigned int b, float c) {
#if __has_builtin(__builtin_amdgcn_fdot2)
  return __builtin_amdgcn_fdot2(__builtin_bit_cast(h2, a), __builtin_bit_cast(h2, b), c, false);
#else
  const h2 av = __builtin_bit_cast(h2, a), bv = __builtin_bit_cast(h2, b);
  return c + (float)av[0] * (float)bv[0] + (float)av[1] * (float)bv[1];
#endif
}
__device__ __forceinline__ void lds_async16(unsigned short* l, const unsigned short* g) {
  __builtin_amdgcn_global_load_lds(
      (const __attribute__((address_space(1))) unsigned int*)g,
      (__attribute__((address_space(3))) unsigned int*)l, 16, 0, 0);
}

// ====== 64x128-tile MFMA GEMM core — BK=64, 2-phase counted-vmcnt ======
// (r6 structure kept: raw s_barrier + vmcnt(6), 16 steps at K=1024.)
template <bool F16>
__device__ __forceinline__ void gemm64_core(
    const unsigned short* __restrict__ A, const unsigned short* __restrict__ Bt,
    float* __restrict__ C, int K, int lda, int row0, int bcol0, int ccol0, int ldc,
    unsigned short* As, unsigned short* Bs) {
  const int tid = threadIdx.x;
  const int w = tid >> 6, lane = tid & 63;
  const int wr = w >> 1, wc = w & 1;
  const int mrow = lane & 15, kgrp = lane >> 4;

  const int sr = (w << 4) + mrow;          // staged row 0..63
  const int sc = kgrp;                     // staged chunk within 4-chunk half

  floatx4 zero = {0.f, 0.f, 0.f, 0.f};
  floatx4 acc[2][4];
#pragma unroll
  for (int i = 0; i < 2; i++)
#pragma unroll
    for (int j = 0; j < 4; j++) acc[i][j] = zero;

  const int nt = K >> 6;
  const unsigned short* Ap  = A  + (size_t)(row0 + sr) * lda + sc * 8;
  const unsigned short* Bp0 = Bt + (size_t)(bcol0 + sr) * K + sc * 8;
  const unsigned short* Bp1 = Bt + (size_t)(bcol0 + 64 + sr) * K + sc * 8;

  auto stage = [&](int t, int b) {
    const int ko = t << 6;
#pragma unroll
    for (int j = 0; j < 2; j++) {
      lds_async16(&As[b * 4096 + w * 1024 + j * 512], Ap + ko + j * 32);
      lds_async16(&Bs[b * 8192 + w * 1024 + j * 512], Bp0 + ko + j * 32);
      lds_async16(&Bs[b * 8192 + 4096 + w * 1024 + j * 512], Bp1 + ko + j * 32);
    }
  };

  stage(0, 0);
  int cur = 0;
  for (int t = 0; t < nt; t++) {
    if (t + 1 < nt) {
      stage(t + 1, cur ^ 1);                              // outstanding: 12
      asm volatile("s_waitcnt vmcnt(6)" ::: "memory");    // tile t landed; t+1 in flight
    } else {
      asm volatile("s_waitcnt vmcnt(0)" ::: "memory");    // final tile: drain
    }
    __builtin_amdgcn_s_barrier();
    const unsigned short* as = As + cur * 4096;
    const unsigned short* bs = Bs + cur * 8192;
#pragma unroll
    for (int ks = 0; ks < 2; ks++) {
      short8 af[2], bf4[4];
#pragma unroll
      for (int mi = 0; mi < 2; mi++)
        af[mi] = *(const short8*)&as[(wr * 2 + mi) * 1024 + (ks * 4 + kgrp) * 128 + mrow * 8];
#pragma unroll
      for (int ni = 0; ni < 4; ni++)
        bf4[ni] = *(const short8*)&bs[(wc * 4 + ni) * 1024 + (ks * 4 + kgrp) * 128 + mrow * 8];
#pragma unroll
      for (int mi = 0; mi < 2; mi++)
#pragma unroll
        for (int ni = 0; ni < 4; ni++) {
          if constexpr (F16)
            acc[mi][ni] = __builtin_amdgcn_mfma_f32_16x16x32_f16(
                __builtin_bit_cast(h8, af[mi]), __builtin_bit_cast(h8, bf4[ni]),
                acc[mi][ni], 0, 0, 0);
          else
            acc[mi][ni] = __builtin_amdgcn_mfma_f32_16x16x32_bf16(af[mi], bf4[ni],
                                                                  acc[mi][ni], 0, 0, 0);
        }
    }
    asm volatile("" ::: "memory");
    __builtin_amdgcn_s_barrier();       // all reads of buf[cur] done before overwrite
    cur ^= 1;
  }
#pragma unroll
  for (int mi = 0; mi < 2; mi++)
#pragma unroll
    for (int ni = 0; ni < 4; ni++) {
      float* Cp = C + (size_t)(row0 + wr * 32 + mi * 16 + kgrp * 4) * ldc
                    + ccol0 + wc * 64 + ni * 16 + mrow;
      Cp[0] = acc[mi][ni][0];
      Cp[(size_t)ldc] = acc[mi][ni][1];
      Cp[(size_t)2 * ldc] = acc[mi][ni][2];
      Cp[(size_t)3 * ldc] = acc[mi][ni][3];
    }
}

// merged q|k|v GEMM: grid (24, 32), f16 single pass K=1024 (r4 win).
__global__ __launch_bounds__(256) void qkv_gemm(const unsigned short* __restrict__ Axf,
                                                const unsigned short* __restrict__ Bqkv,
                                                float* __restrict__ C) {
  __shared__ __align__(16) unsigned short As[2 * 64 * 64];
  __shared__ __align__(16) unsigned short Bs[2 * 128 * 64];
  gemm64_core<true>(Axf, Bqkv, C, 1024, 1024, blockIdx.y * 64,
                    blockIdx.x * 128, blockIdx.x * 128, 3072, As, Bs);
}

// final output projection (bf16 inputs)
__global__ __launch_bounds__(256) void gemm_bt64(const unsigned short* __restrict__ A,
                                                 const unsigned short* __restrict__ Bt,
                                                 float* __restrict__ C,
                                                 int K, int lda, int ldc) {
  __shared__ __align__(16) unsigned short As[2 * 64 * 64];
  __shared__ __align__(16) unsigned short Bs[2 * 128 * 64];
  gemm64_core<false>(A, Bt, C, K, lda, blockIdx.y * 64,
                     blockIdx.x * 128, blockIdx.x * 128, ldc, As, Bs);
}

// ---------------- cast x -> f16 (2048 x 1024) ----------------
__global__ __launch_bounds__(256) void cast_x_k(const float* __restrict__ x,
                                                unsigned short* __restrict__ Axf) {
  const int gid = blockIdx.x * 256 + threadIdx.x;
  float4 xv = ((const float4*)x)[gid];
  const unsigned int p0 = pack_h2(xv.x, xv.y);
  const unsigned int p1 = pack_h2(xv.z, xv.w);
  *(uint2*)&Axf[(size_t)gid * 4] = make_uint2(p0, p1);
}

// ---- transpose-cast Wq/Wk/Wv (by blockIdx.z) into Bqkv f16 (3072n x 1024k) ----
__global__ void cast_wqkv(const float* __restrict__ Wq, const float* __restrict__ Wk,
                          const float* __restrict__ Wv, unsigned short* __restrict__ Bt) {
  __shared__ float tile[32][33];
  const float* W = (blockIdx.z == 0) ? Wq : (blockIdx.z == 1) ? Wk : Wv;
  const int n0 = blockIdx.z * 1024;
  const int kt0 = blockIdx.y * 32, nt0 = blockIdx.x * 32;
  const int tx = threadIdx.x, ty = threadIdx.y;
#pragma unroll
  for (int i = 0; i < 32; i += 8)
    tile[ty + i][tx] = W[(size_t)(kt0 + ty + i) * 1024 + nt0 + tx];
  __syncthreads();
#pragma unroll
  for (int i = 0; i < 32; i += 8) {
    const int n = nt0 + ty + i, kk = kt0 + tx;
    Bt[(size_t)(n0 + n) * 1024 + kk] = f32_to_f16u(tile[tx][ty + i]);
  }
}

// ---- transpose-cast 1024x1024 W -> Bt (1024n x 1024k) bf16 ----
__global__ void cast_wt1(const float* __restrict__ W, unsigned short* __restrict__ Bt) {
  __shared__ float tile[32][33];
  const int kt0 = blockIdx.y * 32, nt0 = blockIdx.x * 32;
  const int tx = threadIdx.x, ty = threadIdx.y;
#pragma unroll
  for (int i = 0; i < 32; i += 8)
    tile[ty + i][tx] = W[(size_t)(kt0 + ty + i) * 1024 + nt0 + tx];
  __syncthreads();
#pragma unroll
  for (int i = 0; i < 32; i += 8) {
    const int n = nt0 + ty + i, kk = kt0 + tx;
    Bt[(size_t)n * 1024 + kk] = f32_to_bf16(tile[tx][ty + i]);
  }
}

// ---- transpose-cast Wck/Wcv (1024x64) -> (64,1024) hi/lo bf16 ----
__global__ void cast_wct(const float* __restrict__ Wck, const float* __restrict__ Wcv,
                         unsigned short* __restrict__ KT_hi, unsigned short* __restrict__ KT_lo,
                         unsigned short* __restrict__ VT_hi, unsigned short* __restrict__ VT_lo) {
  __shared__ float tile[32][33];
  const float* W = blockIdx.z ? Wcv : Wck;
  unsigned short* Bh = blockIdx.z ? VT_hi : KT_hi;
  unsigned short* Bl = blockIdx.z ? VT_lo : KT_lo;
  const int kt0 = blockIdx.y * 32, nt0 = blockIdx.x * 32;
  const int tx = threadIdx.x, ty = threadIdx.y;
#pragma unroll
  for (int i = 0; i < 32; i += 8)
    tile[ty + i][tx] = W[(size_t)(kt0 + ty + i) * 64 + nt0 + tx];
  __syncthreads();
#pragma unroll
  for (int i = 0; i < 32; i += 8) {
    const int n = nt0 + ty + i, kk = kt0 + tx;
    const float f = tile[tx][ty + i];
    const unsigned short hb = f32_to_bf16(f);
    Bh[(size_t)n * 1024 + kk] = hb;
    Bl[(size_t)n * 1024 + kk] = f32_to_bf16(f - bf16_to_f32(hb));
  }
}

// ---------------- reorg: C(t,3072) -> qh f32, qhf f16 (T,1024),
//                  khfT f16 (H, 8, T, 8), vhf f16 (H, T, 64) ----------------
__global__ __launch_bounds__(256) void reorg_qkv(const float* __restrict__ C,
                                                 float* __restrict__ qh,
                                                 unsigned short* __restrict__ qhf,
                                                 unsigned short* __restrict__ khfT,
                                                 unsigned short* __restrict__ vhf) {
  const int gid = blockIdx.x * 256 + threadIdx.x;
  const int t = gid / 768;
  const int c = (gid - t * 768) * 4;
  float4 val = *(const float4*)&C[(size_t)t * 3072 + c];
  const unsigned int p0 = pack_h2(val.x, val.y);
  const unsigned int p1 = pack_h2(val.z, val.w);
  if (c < 1024) {
    *(float4*)&qh[(size_t)t * 1024 + c] = val;
    *(uint2*)&qhf[(size_t)t * 1024 + c] = make_uint2(p0, p1);
  } else if (c < 2048) {
    const int h = (c >> 6) & 15, d = c & 63;
    const int dc = d >> 3, j = d & 7;
    *(uint2*)&khfT[((size_t)(h * 8 + dc) * 2048 + t) * 8 + j] = make_uint2(p0, p1);
  } else {
    const int h = (c >> 6) & 15, d = c & 63;
    *(uint2*)&vhf[((size_t)h * 2048 + t) * 64 + d] = make_uint2(p0, p1);
  }
}

// ---- transpose vhf [h][t][64] -> vhfT [h][d][2048] f16 (for window PV MFMA) ----
__global__ void transp_v(const unsigned short* __restrict__ vhf,
                         unsigned short* __restrict__ vhfT) {
  __shared__ unsigned short tile[32][34];
  const int h = blockIdx.z;
  const int t0 = blockIdx.x * 32, d0 = blockIdx.y * 32;
  const int tx = threadIdx.x, ty = threadIdx.y;
#pragma unroll
  for (int i = 0; i < 32; i += 8)
    tile[ty + i][tx] = vhf[((size_t)h * 2048 + t0 + ty + i) * 64 + d0 + tx];
  __syncthreads();
#pragma unroll
  for (int i = 0; i < 32; i += 8)
    vhfT[((size_t)h * 64 + d0 + ty + i) * 2048 + t0 + tx] = tile[tx][ty + i];
}

// ---------------- compress via MFMA (reads k/v straight from C) ----------------
__global__ __launch_bounds__(512) void compress_mfma(
    const float* __restrict__ C,
    const unsigned short* __restrict__ KT_hi, const unsigned short* __restrict__ KT_lo,
    const unsigned short* __restrict__ VT_hi, const unsigned short* __restrict__ VT_lo,
    unsigned short* __restrict__ kc_hi, unsigned short* __restrict__ kc_lo,
    unsigned short* __restrict__ vcT) {
  __shared__ float red[8][64][17];
  const int isv = blockIdx.y;
  const unsigned short* Bh = isv ? VT_hi : KT_hi;
  const unsigned short* Bl = isv ? VT_lo : KT_lo;
  const int tid = threadIdx.x, w = tid >> 6, lane = tid & 63;
  const int mrow = lane & 15, kgrp = lane >> 4;
  const int m0 = blockIdx.x * 16;
  const int m = m0 + mrow;
  const int hh = m >> 7, nb = m & 127;
  const int cbase = 1024 + isv * 1024 + hh * 64;

  floatx4 zero = {0.f, 0.f, 0.f, 0.f};
  floatx4 acc[4] = {zero, zero, zero, zero};

  const int kbeg = w << 7;                  // per-wave K chunk of 128
  for (int k0 = kbeg; k0 < kbeg + 128; k0 += 32) {
    const int c = k0 + kgrp * 8;
    const float* ap = &C[(size_t)(nb * 16 + (c >> 6)) * 3072 + cbase + (c & 63)];
    float4 q0 = *(const float4*)ap;
    float4 q1 = *(const float4*)(ap + 4);
    float qq[8] = {q0.x, q0.y, q0.z, q0.w, q1.x, q1.y, q1.z, q1.w};
    short8 a_hi, a_lo;
#pragma unroll
    for (int j = 0; j < 8; j++) {
      unsigned short hb = f32_to_bf16(qq[j]);
      a_hi[j] = (short)hb;
      a_lo[j] = (short)f32_to_bf16(qq[j] - bf16_to_f32(hb));
    }
#pragma unroll
    for (int ni = 0; ni < 4; ni++) {
      const size_t boff = (size_t)(ni * 16 + mrow) * 1024 + k0 + kgrp * 8;
      short8 b_hi = *(const short8*)&Bh[boff];
      short8 b_lo = *(const short8*)&Bl[boff];
      acc[ni] = __builtin_amdgcn_mfma_f32_16x16x32_bf16(a_hi, b_hi, acc[ni], 0, 0, 0);
      acc[ni] = __builtin_amdgcn_mfma_f32_16x16x32_bf16(a_lo, b_hi, acc[ni], 0, 0, 0);
      acc[ni] = __builtin_amdgcn_mfma_f32_16x16x32_bf16(a_hi, b_lo, acc[ni], 0, 0, 0);
    }
  }

#pragma unroll
  for (int ni = 0; ni < 4; ni++)
#pragma unroll
    for (int r = 0; r < 4; r++) red[w][lane][ni * 4 + r] = acc[ni][r];
  __syncthreads();

  if (w < 4) {
#pragma unroll
    for (int r = 0; r < 4; r++) {
      const int j = w * 4 + r;
      float val = 0.f;
#pragma unroll
      for (int ww = 0; ww < 8; ww++) val += red[ww][lane][j];
      const int mo = m0 + kgrp * 4 + r;
      const int d = w * 16 + mrow;
      if (!isv) {
        const unsigned short hb = f32_to_bf16(val);
        kc_hi[(size_t)mo * 64 + d] = hb;
        kc_lo[(size_t)mo * 64 + d] = f32_to_bf16(val - bf16_to_f32(hb));
      } else {
        vcT[(size_t)(mo >> 7) * 8192 + (size_t)d * 128 + (mo & 127)] = f32_to_bf16(val);
      }
    }
  }
}

// ---------------- gates ----------------
__global__ __launch_bounds__(256) void gates_k(const float* __restrict__ C,
                                               const float* __restrict__ Wg,
                                               const float* __restrict__ bg,
                                               float* __restrict__ gates) {
  const int w = threadIdx.x >> 6, lane = threadIdx.x & 63;
  const int t = blockIdx.x * 4 + w;
  float m = 0.f;
#pragma unroll
  for (int h = 0; h < 16; h++) m += C[(size_t)t * 3072 + h * 64 + lane];
  m *= (1.f / 16.f);
  float g0 = wred_sum(m * Wg[lane * 3 + 0]);
  float g1 = wred_sum(m * Wg[lane * 3 + 1]);
  float g2 = wred_sum(m * Wg[lane * 3 + 2]);
  if (lane == 0) {
    g0 += bg[0]; g1 += bg[1]; g2 += bg[2];
    float mx = fmaxf(g0, fmaxf(g1, g2));
    float e0 = __expf(g0 - mx), e1 = __expf(g1 - mx), e2 = __expf(g2 - mx);
    float inv = 1.f / (e0 + e1 + e2);
    gates[t * 3 + 0] = e0 * inv;
    gates[t * 3 + 1] = e1 * inv;
    gates[t * 3 + 2] = e2 * inv;
  }
}

// ------- cscore: MFMA scores + softmax + top-4 + fused PV -------
// r7: the qq loop was the kernel's cost — a ~60-op dependent shfl chain per
// row, NOT unrolled (zero ILP). Now: #pragma unroll (4 independent chains
// interleave) + argmax via max-butterfly + ballot/ctz + 1 broadcast shfl
// (replaces the 12-shfl value+index butterfly); j=0 reuses softmax max M.
// Tie semantics preserved: lowest lane via ctz(ballot), c0 (even idx) before
// c1 — identical to the old lowest-index-wins rule (incl. count==0 rows).
__global__ __launch_bounds__(256) void cscore_k(
    const float* __restrict__ qh, const unsigned short* __restrict__ kc_hi,
    const unsigned short* __restrict__ kc_lo, const unsigned short* __restrict__ vcT,
    float* __restrict__ oc, int4* __restrict__ sel) {
  __shared__ float S_s[16][132];
  const int h = blockIdx.x >> 7, t0 = (blockIdx.x & 127) * 16;
  const int tid = threadIdx.x, w = tid >> 6, lane = tid & 63;
  const int mrow = lane & 15, kgrp = lane >> 4;

  short8 a_hi[2], a_lo[2];
#pragma unroll
  for (int ks = 0; ks < 2; ks++) {
    const float* qp = &qh[(size_t)(t0 + mrow) * 1024 + h * 64 + ks * 32 + kgrp * 8];
    float4 q0 = *(const float4*)qp;
    float4 q1 = *(const float4*)(qp + 4);
    float qq[8] = {q0.x, q0.y, q0.z, q0.w, q1.x, q1.y, q1.z, q1.w};
#pragma unroll
    for (int j = 0; j < 8; j++) {
      unsigned short hb = f32_to_bf16(qq[j]);
      a_hi[ks][j] = (short)hb;
      a_lo[ks][j] = (short)f32_to_bf16(qq[j] - bf16_to_f32(hb));
    }
  }
  floatx4 zero = {0.f, 0.f, 0.f, 0.f};
  floatx4 acc[2] = {zero, zero};
#pragma unroll
  for (int ni = 0; ni < 2; ni++) {
    const int nb = w * 32 + ni * 16 + mrow;
#pragma unroll
    for (int ks = 0; ks < 2; ks++) {
      const size_t off = ((size_t)h * 128 + nb) * 64 + ks * 32 + kgrp * 8;
      short8 b_hi = *(const short8*)&kc_hi[off];
      short8 b_lo = *(const short8*)&kc_lo[off];
      acc[ni] = __builtin_amdgcn_mfma_f32_16x16x32_bf16(a_hi[ks], b_hi, acc[ni], 0, 0, 0);
      acc[ni] = __builtin_amdgcn_mfma_f32_16x16x32_bf16(a_lo[ks], b_hi, acc[ni], 0, 0, 0);
      acc[ni] = __builtin_amdgcn_mfma_f32_16x16x32_bf16(a_hi[ks], b_lo, acc[ni], 0, 0, 0);
    }
  }
#pragma unroll
  for (int ni = 0; ni < 2; ni++) {
    const int n = w * 32 + ni * 16 + mrow;
#pragma unroll
    for (int r = 0; r < 4; r++) {
      const int row = kgrp * 4 + r;
      const int count = (t0 + row) >> 4;
      S_s[row][n] = (n < count) ? acc[ni][r] * 0.125f : NEGC;
    }
  }
  __syncthreads();

#pragma unroll
  for (int qq = 0; qq < 4; qq++) {
    const int row = w * 4 + qq, t = t0 + row, count = t >> 4;
    const float2 sv = *(const float2*)&S_s[row][2 * lane];
    const float s0 = sv.x, s1 = sv.y;
    const float M = wred_max(fmaxf(s0, s1));
    const float e0 = __expf(s0 - M), e1 = __expf(s1 - M);
    const float inv = 1.f / wred_sum(e0 + e1);
    S_s[row][2 * lane]     = (count == 0) ? 0.f : e0 * inv;
    S_s[row][2 * lane + 1] = (count == 0) ? 0.f : e1 * inv;

    float c0 = s0, c1 = s1;
    float curM = M;
    int se0 = 0, se1 = 0, se2 = 0, se3 = 0;
#pragma unroll
    for (int j = 0; j < 4; j++) {
      if (j) curM = wred_max(fmaxf(c0, c1));
      const unsigned long long b = __ballot((c0 == curM) || (c1 == curM));
      const int lidx = (int)__builtin_ctzll(b);
      const float c0l = __shfl(c0, lidx, 64);
      const int isc0 = (c0l == curM);
      const int idx = 2 * lidx + (isc0 ? 0 : 1);
      if (j == 0) se0 = idx; else if (j == 1) se1 = idx;
      else if (j == 2) se2 = idx; else se3 = idx;
      if (lane == lidx) { if (isc0) c0 = -FLT_MAX; else c1 = -FLT_MAX; }
    }
    if (lane == 0) sel[((size_t)h << 11) + t] = make_int4(se0, se1, se2, se3);
  }
  __syncthreads();

  const int d = w * 16 + mrow;
  floatx4 accp = zero;
#pragma unroll
  for (int ks = 0; ks < 4; ks++) {
    const float4 p0 = *(const float4*)&S_s[mrow][ks * 32 + kgrp * 8];
    const float4 p1 = *(const float4*)&S_s[mrow][ks * 32 + kgrp * 8 + 4];
    short8 a;
    a[0] = (short)f32_to_bf16(p0.x); a[1] = (short)f32_to_bf16(p0.y);
    a[2] = (short)f32_to_bf16(p0.z); a[3] = (short)f32_to_bf16(p0.w);
    a[4] = (short)f32_to_bf16(p1.x); a[5] = (short)f32_to_bf16(p1.y);
    a[6] = (short)f32_to_bf16(p1.z); a[7] = (short)f32_to_bf16(p1.w);
    const short8 b = *(const short8*)&vcT[((size_t)h * 64 + d) * 128 + ks * 32 + kgrp * 8];
    accp = __builtin_amdgcn_mfma_f32_16x16x32_bf16(a, b, accp, 0, 0, 0);
  }
#pragma unroll
  for (int r = 0; r < 4; r++)
    oc[(size_t)(t0 + kgrp * 4 + r) * 1024 + h * 64 + d] = accp[r];
}

// ------------- selected branch only: per-wave per-(h,t), writes osel -------------
__global__ __launch_bounds__(256) void nsa_sel(
    const unsigned short* __restrict__ qhf, const unsigned short* __restrict__ khfT,
    const unsigned short* __restrict__ vhf, const int4* __restrict__ sel,
    float* __restrict__ osel) {
  __shared__ float ps[4][64];
  __shared__ int tks[4][64];
  const int bid = blockIdx.x;
  const int h = ((bid & 7) << 1) | ((bid >> 3) & 1);
  const int w = threadIdx.x >> 6, lane = threadIdx.x & 63;
  const int t = (bid >> 4) * 4 + w;

  const unsigned short* kT = khfT + (size_t)h * 131072;
  const unsigned short* vhh = vhf + (size_t)h * 131072;

  uint4 qr[8];
  {
    const uint4* qp = (const uint4*)(qhf + (size_t)t * 1024 + h * 64);
#pragma unroll
    for (int j = 0; j < 8; j++) qr[j] = qp[j];
  }
  const int4 s4 = sel[((size_t)h << 11) + t];

  const int g16 = lane >> 4;
  const int blk = (g16 == 0) ? s4.x : (g16 == 1) ? s4.y : (g16 == 2) ? s4.z : s4.w;
  const int tok = blk * 16 + (lane & 15);
  tks[w][lane] = tok;
  {
    float a0 = 0.f, a1 = 0.f, a2 = 0.f, a3 = 0.f;
#pragma unroll
    for (int dc = 0; dc < 8; dc++) {
      const uint4 kk = *(const uint4*)(kT + ((size_t)dc * 2048 + tok) * 8);
      a0 = fdot2u(kk.x, qr[dc].x, a0);
      a1 = fdot2u(kk.y, qr[dc].y, a1);
      a2 = fdot2u(kk.z, qr[dc].z, a2);
      a3 = fdot2u(kk.w, qr[dc].w, a3);
    }
    const float sv_ = (tok <= t) ? ((a0 + a1) + (a2 + a3)) * 0.125f : NEGC;
    const float Ms = wred_max(sv_);
    const float es = __expf(sv_ - Ms);
    ps[w][lane] = es * (1.f / wred_sum(es));
  }

  const int dd = lane & 31, s = lane >> 5;
  const float4* ps4 = (const float4*)ps[w];
  const int4* tk4p = (const int4*)tks[w];

  float osx = 0.f, osy = 0.f;
#pragma unroll
  for (int jc = 0; jc < 8; jc++) {
    const float4 p4 = ps4[s * 8 + jc];
    const int4 t4 = tk4p[s * 8 + jc];
    const float pa[4] = {p4.x, p4.y, p4.z, p4.w};
    const int ta[4] = {t4.x, t4.y, t4.z, t4.w};
#pragma unroll
    for (int u = 0; u < 4; u++) {
      const unsigned int vv = *(const unsigned int*)(vhh + (size_t)ta[u] * 64 + 2 * dd);
      const h2 v2 = __builtin_bit_cast(h2, vv);
      osx += pa[u] * (float)v2[0];
      osy += pa[u] * (float)v2[1];
    }
  }
  osx += __shfl_xor(osx, 32, 64);
  osy += __shfl_xor(osy, 32, 64);

  if (lane < 32)
    *(float2*)&osel[(size_t)t * 1024 + h * 64 + 2 * dd] = make_float2(osx, osy);
}

// ------------- window branch via MFMA + gated combine -> outf -------------
__global__ __launch_bounds__(256) void nsa_win(
    const unsigned short* __restrict__ qhf, const unsigned short* __restrict__ khfT,
    const unsigned short* __restrict__ vhfT, const float* __restrict__ oc,
    const float* __restrict__ osel, const float* __restrict__ gates,
    unsigned short* __restrict__ outf) {
  __shared__ unsigned short P_lds[4][16][72];
  const int bid = blockIdx.x;
  const int h = bid & 15, tq0 = (bid >> 4) * 64;
  const int w = threadIdx.x >> 6, lane = threadIdx.x & 63;
  const int cc = lane & 15, kgrp = lane >> 4;
  const int qt0 = tq0 + w * 16;
  const int kb = qt0 - 32;

  const unsigned short* kT = khfT + (size_t)h * 131072;
  const unsigned short* vT = vhfT + (size_t)h * 131072;

  short8 aq[2];
#pragma unroll
  for (int ks = 0; ks < 2; ks++)
    aq[ks] = *(const short8*)&qhf[(size_t)(qt0 + cc) * 1024 + h * 64 + ks * 32 + kgrp * 8];

  floatx4 zero = {0.f, 0.f, 0.f, 0.f};
  floatx4 accs[3] = {zero, zero, zero};
#pragma unroll
  for (int ni = 0; ni < 3; ni++) {
    const int tokc = min(max(kb + ni * 16 + cc, 0), T_LEN - 1);
#pragma unroll
    for (int ks = 0; ks < 2; ks++) {
      const short8 bk = *(const short8*)&kT[((size_t)(ks * 4 + kgrp) * 2048 + tokc) * 8];
      accs[ni] = __builtin_amdgcn_mfma_f32_16x16x32_f16(
          __builtin_bit_cast(h8, aq[ks]), __builtin_bit_cast(h8, bk), accs[ni], 0, 0, 0);
    }
  }

#pragma unroll
  for (int r = 0; r < 4; r++) {
    const int t = qt0 + kgrp * 4 + r;
    float sc[3];
#pragma unroll
    for (int ni = 0; ni < 3; ni++) {
      const int s = kb + ni * 16 + cc;
      const int ds = t - s;
      sc[ni] = (s >= 0 && ds >= 0 && ds <= 32) ? accs[ni][r] * 0.125f : NEGC;
    }
    float m3 = fmaxf(fmaxf(sc[0], sc[1]), sc[2]);
#pragma unroll
    for (int o = 1; o <= 8; o <<= 1) m3 = fmaxf(m3, __shfl_xor(m3, o, 64));
    float e0 = __expf(sc[0] - m3), e1 = __expf(sc[1] - m3), e2 = __expf(sc[2] - m3);
    float sum = e0 + e1 + e2;
#pragma unroll
    for (int o = 1; o <= 8; o <<= 1) sum += __shfl_xor(sum, o, 64);
    const float inv = 1.f / sum;
    const int row = kgrp * 4 + r;
    P_lds[w][row][cc]      = f32_to_f16u(e0 * inv);
    P_lds[w][row][16 + cc] = f32_to_f16u(e1 * inv);
    P_lds[w][row][32 + cc] = f32_to_f16u(e2 * inv);
  }
  {  // zero pad slots 48..63 (read by PV k-step 1)
    const int rr = lane >> 2, c0 = 48 + (lane & 3) * 4;
    *(ushort4*)&P_lds[w][rr][c0] = make_ushort4(0, 0, 0, 0);
  }
  __syncthreads();

  floatx4 accp[4] = {zero, zero, zero, zero};
#pragma unroll
  for (int ks2 = 0; ks2 < 2; ks2++) {
    const short8 ap = *(const short8*)&P_lds[w][cc][ks2 * 32 + kgrp * 8];
    const int tok0 = min(max(kb + ks2 * 32 + kgrp * 8, 0), T_LEN - 8);
#pragma unroll
    for (int ni = 0; ni < 4; ni++) {
      const short8 bv = *(const short8*)&vT[(size_t)(ni * 16 + cc) * 2048 + tok0];
      accp[ni] = __builtin_amdgcn_mfma_f32_16x16x32_f16(
          __builtin_bit_cast(h8, ap), __builtin_bit_cast(h8, bv), accp[ni], 0, 0, 0);
    }
  }

#pragma unroll
  for (int r = 0; r < 4; r++) {
    const int t = qt0 + kgrp * 4 + r;
    const float g0 = gates[t * 3 + 0], g1 = gates[t * 3 + 1], g2 = gates[t * 3 + 2];
#pragma unroll
    for (int ni = 0; ni < 4; ni++) {
      const int d = ni * 16 + cc;
      const float ocv = oc[(size_t)t * 1024 + h * 64 + d];
      const float osv = osel[(size_t)t * 1024 + h * 64 + d];
      outf[(size_t)t * 1024 + h * 64 + d] =
          f32_to_bf16(g0 * ocv + g1 * osv + g2 * accp[ni][r]);
    }
  }
}

// ---------------- launch ----------------
extern "C" void kernel_launch(void* const* d_in, const int* in_sizes, int n_in,
                              void* d_out, int out_size, void* d_ws, size_t ws_size,
                              hipStream_t stream) {
  const float* x   = (const float*)d_in[0];
  const float* Wq  = (const float*)d_in[1];
  const float* Wk  = (const float*)d_in[2];
  const float* Wv  = (const float*)d_in[3];
  const float* Wo  = (const float*)d_in[4];
  const float* Wck = (const float*)d_in[5];
  const float* Wcv = (const float*)d_in[6];
  const float* Wg  = (const float*)d_in[7];
  const float* bg  = (const float*)d_in[8];
  float* out = (float*)d_out;

  float* ws = (float*)d_ws;
  // region A [0,24 MB): C until compress; then osel [0,8), oc [8,16), outf [16,20)
  float*          C    = ws;
  float*          osel = ws;                                // [0,8 MB)
  float*          oc   = ws + 2097152;                      // [8,16 MB)
  unsigned short* outf = (unsigned short*)(ws + 4194304);   // [16,20 MB)
  // region B [24,36 MB): Axf (4 MB) until qkv GEMM; then qh + smalls
  unsigned short* Axf   = (unsigned short*)(ws + 6291456);
  float*          qh    = ws + 6291456;                     // [24,32 MB)
  unsigned short* Wot   = (unsigned short*)(ws + 8388608);  // [32,34 MB)
  unsigned short* kc_hi = (unsigned short*)(ws + 8912896);
  unsigned short* kc_lo = (unsigned short*)(ws + 8978432);
  unsigned short* vcT   = (unsigned short*)(ws + 9043968);
  int4*           sel   = (int4*)(ws + 9109504);
  unsigned short* WckT_hi = (unsigned short*)(ws + 9240576);
  unsigned short* WckT_lo = (unsigned short*)(ws + 9273344);
  unsigned short* WcvT_hi = (unsigned short*)(ws + 9306112);
  unsigned short* WcvT_lo = (unsigned short*)(ws + 9338880);
  float*          gates   = ws + 9371648;
  // region C [36,48 MB): Bqkv f16 (6 MB) until qkv GEMM; then qhf/khfT/vhf f16
  unsigned short* Bqkv = (unsigned short*)(ws + 9437184);   // 3072x1024 f16, 6 MB
  unsigned short* qhf  = (unsigned short*)(ws + 9437184);   // [36,40 MB)
  unsigned short* khfT = (unsigned short*)(ws + 10485760);  // [40,44 MB)
  unsigned short* vhf  = (unsigned short*)(ws + 11534336);  // [44,48 MB)
  // vhfT scratch lives in d_out (read by nsa_win, then gemm_bt64 overwrites out)
  unsigned short* vhfT = (unsigned short*)d_out;            // 16x64x2048 f16, 4 MB

  // 1. operand preparation (f16 single-pass QKV operands)
  cast_x_k<<<2048, 256, 0, stream>>>(x, Axf);
  cast_wqkv<<<dim3(32, 32, 3), dim3(32, 8), 0, stream>>>(Wq, Wk, Wv, Bqkv);

  // 2. merged q|k|v GEMM: K=1024 f16, BK=64 counted-vmcnt pipeline (16 steps)
  qkv_gemm<<<dim3(24, 32), 256, 0, stream>>>(Axf, Bqkv, C);

  // 3. reorg (+ V transpose for window MFMA) + gates; late weight casts
  reorg_qkv<<<6144, 256, 0, stream>>>(C, qh, qhf, khfT, vhf);
  transp_v<<<dim3(64, 2, 16), dim3(32, 8), 0, stream>>>(vhf, vhfT);
  gates_k<<<512, 256, 0, stream>>>(C, Wg, bg, gates);
  cast_wt1<<<dim3(32, 32), dim3(32, 8), 0, stream>>>(Wo, Wot);
  cast_wct<<<dim3(2, 32, 2), dim3(32, 8), 0, stream>>>(Wck, Wcv, WckT_hi, WckT_lo, WcvT_hi, WcvT_lo);

  // 4. compression (reads C; C dead after) + compressed branch (oc aliases C tail)
  compress_mfma<<<dim3(128, 2), 512, 0, stream>>>(C, WckT_hi, WckT_lo, WcvT_hi, WcvT_lo,
                                                  kc_hi, kc_lo, vcT);
  cscore_k<<<2048, 256, 0, stream>>>(qh, kc_hi, kc_lo, vcT, oc, sel);

  // 5. selected branch (scalar, per-query) -> osel; window branch (MFMA) + combine
  nsa_sel<<<8192, 256, 0, stream>>>(qhf, khfT, vhf, sel, osel);
  nsa_win<<<512, 256, 0, stream>>>(qhf, khfT, vhfT, oc, osel, gates, outf);

  // 6. output projection (BK=64 counted-vmcnt, 16 steps)
  gemm_bt64<<<dim3(8, 32), 256, 0, stream>>>(outf, Wot, out, 1024, 1024, 1024);
}